// Round 1
// baseline (5171.069 us; speedup 1.0000x reference)
//
#include <hip/hip_runtime.h>
#include <hip/hip_bf16.h>
#include <math.h>

// GraphSAGE: 4 layers on N=100000 nodes, E=1600000 edges.
//   h1 = relu(mean(x)@W1l + x@W1r + b1)          (N,128)
//   h2 = relu(mean(h1)@W2l + h1@W2r + b2)        (N,128)  [never materialized]
//   h3 = mean(h2)@W3l + h2@W3r + b3              (N,1)
//      linearity: mean(h2)@W3l == segment_mean(h2@W3l)  -> only scalars p,q needed
//   out_scalar = h3[:,0]
//   h4 = mean(h3)@W4l + h3@W4r + b4              (N,8)
//   out_rock = log_softmax(h4)
//
// Workspace layout (floats), N = 100000:
//   cnt   : ws[0       .. N)
//   B     : ws[N       .. 65N)   agg0 (N x 64); later p=B, q=B+N, aggp=B+2N, agg3=B+3N, h3=B
//   h1    : ws[65N     .. 193N)  (N x 128)
//   agg1  : ws[193N    .. 321N)  (N x 128)
// total 321N floats = 128.4 MB

__device__ __forceinline__ void atomAdd(float* p, float v) {
  __hip_atomic_fetch_add(p, v, __ATOMIC_RELAXED, __HIP_MEMORY_SCOPE_AGENT);
}

// ---------------- edge scatter: agg[dst] += x[src], float4 chunks ----------------
template<int DQ>  // DQ = D/4 float4-chunks per row
__global__ __launch_bounds__(256) void scatter_vec(const float* __restrict__ xin,
                                                   const int* __restrict__ ei,
                                                   float* __restrict__ agg,
                                                   float* __restrict__ cnt, // null except pass 1
                                                   int E) {
  const int* src = ei;
  const int* dst = ei + E;
  const int total = E * DQ;
  const int stride = gridDim.x * blockDim.x;
  for (int w = blockIdx.x * blockDim.x + threadIdx.x; w < total; w += stride) {
    int e = w / DQ;        // DQ is power of two -> shift
    int c = w - e * DQ;
    int s = src[e], d = dst[e];
    const float4 v = *(const float4*)(xin + ((size_t)s * DQ + c) * 4);
    float* ap = agg + ((size_t)d * DQ + c) * 4;
    atomAdd(ap + 0, v.x); atomAdd(ap + 1, v.y);
    atomAdd(ap + 2, v.z); atomAdd(ap + 3, v.w);
    if (cnt != nullptr && c == 0) atomAdd(cnt + d, 1.0f);
  }
}

// ---------------- edge scatter: scalar ----------------
__global__ __launch_bounds__(256) void scatter_scalar(const float* __restrict__ val,
                                                      const int* __restrict__ ei,
                                                      float* __restrict__ agg, int E) {
  const int* src = ei;
  const int* dst = ei + E;
  const int stride = gridDim.x * blockDim.x;
  for (int e = blockIdx.x * blockDim.x + threadIdx.x; e < E; e += stride)
    atomAdd(agg + dst[e], val[src[e]]);
}

// ---------------- fused SAGE GEMM ----------------
// out[n][j] = act( sum_k a[n][k] * W[k][j] + bias[j] ),
//   a = [agg[n]/max(cnt,1), prev[n]] (K2 = 2*KHALF dims), W = [Wl; Wr] (K2 x 128)
// FINAL: instead of storing h, compute p[n]=h.W3l, q[n]=h.W3r (relu applied).
#define DOUT 128
template<int KHALF, bool FINAL>
__global__ __launch_bounds__(256) void sage_gemm(
    const float* __restrict__ agg, const float* __restrict__ cnt,
    const float* __restrict__ prev,
    const float* __restrict__ Wl, const float* __restrict__ Wr,
    const float* __restrict__ bias,
    const float* __restrict__ W3l, const float* __restrict__ W3r,
    float* __restrict__ out_h, float* __restrict__ out_p, float* __restrict__ out_q,
    int nNodes) {
  constexpr int K2 = 2 * KHALF;
  constexpr int NT = 8;  // nodes per block-iteration
  __shared__ float a_lds[NT][K2];
  __shared__ float Wt[64][DOUT];
  __shared__ float b_lds[DOUT];
  __shared__ float w3l_lds[DOUT], w3r_lds[DOUT];
  __shared__ float partp[4][4], partq[4][4];  // [wave][node-in-group]

  const int t = threadIdx.x;
  if (t < DOUT) {
    b_lds[t] = bias[t];
    if constexpr (FINAL) { w3l_lds[t] = W3l[t]; w3r_lds[t] = W3r[t]; }
  }
  const int j = t & (DOUT - 1);
  const int ng = t >> 7;       // node group 0/1 (4 nodes each)
  const int lane = t & 63;
  const int wid = t >> 6;

  for (int base = blockIdx.x * NT; base < nNodes; base += gridDim.x * NT) {
    __syncthreads();  // S0: previous iteration fully done before a_lds overwrite
    // stage a = [mean, prev] for NT nodes
    for (int f = t; f < NT * K2; f += 256) {
      int n = f / K2, k = f - n * K2;
      int node = base + n;
      float v = 0.f;
      if (node < nNodes) {
        if (k < KHALF) {
          float c = cnt[node]; c = c < 1.f ? 1.f : c;
          v = agg[(size_t)node * KHALF + k] * (1.f / c);
        } else {
          v = prev[(size_t)node * KHALF + (k - KHALF)];
        }
      }
      a_lds[n][k] = v;
    }
    float acc[4] = {0.f, 0.f, 0.f, 0.f};  // 4 nodes: base + ng*4 + i
    for (int kt = 0; kt < K2 / 64; ++kt) {
      __syncthreads();  // S1: a_lds ready / previous Wt readers done
      for (int f = t; f < 64 * DOUT; f += 256) {
        int r = f >> 7, c = f & (DOUT - 1);
        int krow = kt * 64 + r;
        Wt[r][c] = (krow < KHALF) ? Wl[krow * DOUT + c] : Wr[(krow - KHALF) * DOUT + c];
      }
      __syncthreads();  // S2: Wt ready
#pragma unroll
      for (int k = 0; k < 64; ++k) {
        float w = Wt[k][j];
#pragma unroll
        for (int i = 0; i < 4; ++i)
          acc[i] = fmaf(w, a_lds[ng * 4 + i][kt * 64 + k], acc[i]);
      }
    }
    if constexpr (!FINAL) {
#pragma unroll
      for (int i = 0; i < 4; ++i) {
        int node = base + ng * 4 + i;
        if (node < nNodes) {
          float v = acc[i] + b_lds[j];
          out_h[(size_t)node * DOUT + j] = v > 0.f ? v : 0.f;  // relu
        }
      }
    } else {
#pragma unroll
      for (int i = 0; i < 4; ++i) {
        float v = acc[i] + b_lds[j];
        v = v > 0.f ? v : 0.f;  // relu (layer 2)
        float pv = v * w3l_lds[j];
        float qv = v * w3r_lds[j];
#pragma unroll
        for (int off = 1; off < 64; off <<= 1) {
          pv += __shfl_xor(pv, off);
          qv += __shfl_xor(qv, off);
        }
        if (lane == 0) { partp[wid][i] = pv; partq[wid][i] = qv; }
      }
      __syncthreads();  // S3: partials visible
      if (t < 8) {
        int g = t >> 2, i = t & 3;
        int node = base + g * 4 + i;
        if (node < nNodes) {
          out_p[node] = partp[2 * g][i] + partp[2 * g + 1][i];
          out_q[node] = partq[2 * g][i] + partq[2 * g + 1][i];
        }
      }
    }
  }
}

// ---------------- h3 = aggp/cnt + q + b3 ; also emit out_scalar ----------------
__global__ __launch_bounds__(256) void h3_kernel(const float* __restrict__ aggp,
                                                 const float* __restrict__ cnt,
                                                 const float* __restrict__ q,
                                                 const float* __restrict__ b3,
                                                 float* __restrict__ h3,
                                                 float* __restrict__ out_scalar, int nNodes) {
  int n = blockIdx.x * blockDim.x + threadIdx.x;
  if (n >= nNodes) return;
  float c = cnt[n]; c = c < 1.f ? 1.f : c;
  float v = aggp[n] * (1.f / c) + q[n] + b3[0];
  h3[n] = v;
  out_scalar[n] = v;
}

// ---------------- layer 4 + log_softmax ----------------
__global__ __launch_bounds__(256) void finalize(const float* __restrict__ agg3,
                                                const float* __restrict__ cnt,
                                                const float* __restrict__ h3,
                                                const float* __restrict__ W4l,
                                                const float* __restrict__ W4r,
                                                const float* __restrict__ b4,
                                                float* __restrict__ out, int nNodes) {
  int n = blockIdx.x * blockDim.x + threadIdx.x;
  if (n >= nNodes) return;
  float c = cnt[n]; c = c < 1.f ? 1.f : c;
  float m = agg3[n] * (1.f / c);
  float hv = h3[n];
  float logits[8];
  float mx = -1e30f;
#pragma unroll
  for (int jj = 0; jj < 8; ++jj) {
    float v = m * W4l[jj] + hv * W4r[jj] + b4[jj];
    logits[jj] = v;
    mx = v > mx ? v : mx;
  }
  float s = 0.f;
#pragma unroll
  for (int jj = 0; jj < 8; ++jj) s += expf(logits[jj] - mx);
  float lse = mx + logf(s);
  float4 o0, o1;
  o0.x = logits[0] - lse; o0.y = logits[1] - lse; o0.z = logits[2] - lse; o0.w = logits[3] - lse;
  o1.x = logits[4] - lse; o1.y = logits[5] - lse; o1.z = logits[6] - lse; o1.w = logits[7] - lse;
  float4* o4 = (float4*)(out + (size_t)n * 8);
  o4[0] = o0; o4[1] = o1;
}

extern "C" void kernel_launch(void* const* d_in, const int* in_sizes, int n_in,
                              void* d_out, int out_size, void* d_ws, size_t ws_size,
                              hipStream_t stream) {
  const float* x   = (const float*)d_in[0];
  const int*   ei  = (const int*)d_in[1];
  const float* W1l = (const float*)d_in[2];
  const float* W1r = (const float*)d_in[3];
  const float* b1  = (const float*)d_in[4];
  const float* W2l = (const float*)d_in[5];
  const float* W2r = (const float*)d_in[6];
  const float* b2  = (const float*)d_in[7];
  const float* W3l = (const float*)d_in[8];
  const float* W3r = (const float*)d_in[9];
  const float* b3  = (const float*)d_in[10];
  const float* W4l = (const float*)d_in[11];
  const float* W4r = (const float*)d_in[12];
  const float* b4  = (const float*)d_in[13];

  const int N = in_sizes[0] / 64;   // 100000
  const int E = in_sizes[1] / 2;    // 1600000
  const size_t Ns = (size_t)N;

  float* ws   = (float*)d_ws;
  float* cnt  = ws;                 // N
  float* B    = ws + Ns;            // agg0: N x 64
  float* h1   = ws + 65 * Ns;       // N x 128
  float* agg1 = ws + 193 * Ns;      // N x 128
  float* p    = B;                  // N (after agg0 consumed)
  float* q    = B + Ns;             // N
  float* aggp = B + 2 * Ns;         // N
  float* agg3 = B + 3 * Ns;         // N
  float* h3   = B;                  // N (overwrites p after pass 3)

  float* out_rock   = (float*)d_out;            // N x 8
  float* out_scalar = (float*)d_out + 8 * Ns;   // N

  // zero: cnt + agg0 ; agg1
  hipMemsetAsync(ws, 0, 65 * Ns * sizeof(float), stream);
  hipMemsetAsync(agg1, 0, 128 * Ns * sizeof(float), stream);

  // pass 1: agg0[dst] += x[src] (64 dims), cnt[dst] += 1
  scatter_vec<16><<<32768, 256, 0, stream>>>(x, ei, B, cnt, E);

  // layer 1 GEMM -> h1
  sage_gemm<64, false><<<(N + 7) / 8, 256, 0, stream>>>(
      B, cnt, x, W1l, W1r, b1, nullptr, nullptr, h1, nullptr, nullptr, N);

  // aggp/agg3 live inside the (now consumed) agg0 region -> zero them
  hipMemsetAsync(aggp, 0, 2 * Ns * sizeof(float), stream);

  // pass 2: agg1[dst] += h1[src] (128 dims)
  scatter_vec<32><<<32768, 256, 0, stream>>>(h1, ei, agg1, nullptr, E);

  // layer 2 GEMM (fused layer-3 projection) -> p, q
  sage_gemm<128, true><<<(N + 7) / 8, 256, 0, stream>>>(
      agg1, cnt, h1, W2l, W2r, b2, W3l, W3r, nullptr, p, q, N);

  // pass 3: aggp[dst] += p[src]
  scatter_scalar<<<6250, 256, 0, stream>>>(p, ei, aggp, E);

  // h3 = aggp/cnt + q + b3 ; out_scalar = h3
  h3_kernel<<<(N + 255) / 256, 256, 0, stream>>>(aggp, cnt, q, b3, h3, out_scalar, N);

  // pass 4: agg3[dst] += h3[src]
  scatter_scalar<<<6250, 256, 0, stream>>>(h3, ei, agg3, E);

  // layer 4 + log_softmax -> out_rock
  finalize<<<(N + 255) / 256, 256, 0, stream>>>(agg3, cnt, h3, W4l, W4r, b4, out_rock, N);
}

// Round 2
// 1320.931 us; speedup vs baseline: 3.9147x; 3.9147x over previous
//
#include <hip/hip_runtime.h>
#include <hip/hip_bf16.h>
#include <math.h>

// GraphSAGE: 4 layers on N=100000 nodes, E=1600000 edges.
// Round 2: atomic scatter -> CSR build + wave-per-node gather (no float atomics).
//   h1 = relu(mean(x)@W1l + x@W1r + b1)          (N,128)
//   h2 = relu(mean(h1)@W2l + h1@W2r + b2)        (N,128)  [never materialized]
//   h3 = mean(h2)@W3l + h2@W3r + b3 = mean(p) + q + b3   (p=h2.W3l, q=h2.W3r)
//   out_scalar = h3[:,0]
//   out_rock = log_softmax(mean(h3)@W4l + h3@W4r + b4)

// ---------------- CSR build ----------------
__global__ __launch_bounds__(256) void hist_kernel(const int* __restrict__ ei,
                                                   int* __restrict__ deg, int E) {
  int e = blockIdx.x * 256 + threadIdx.x;
  if (e < E) atomicAdd(&deg[ei[E + e]], 1);
}

// per-block exclusive scan over 1024-element tiles (256 thr x 4)
__global__ __launch_bounds__(256) void scan1(const int* __restrict__ deg,
                                             int* __restrict__ excl,
                                             int* __restrict__ bsum, int N) {
  __shared__ int lds[256];
  int t = threadIdx.x;
  int base = blockIdx.x * 1024;
  int v[4]; int s = 0;
#pragma unroll
  for (int k = 0; k < 4; ++k) {
    int i = base + t * 4 + k;
    v[k] = (i < N) ? deg[i] : 0;
    s += v[k];
  }
  lds[t] = s;
  __syncthreads();
  for (int off = 1; off < 256; off <<= 1) {
    int add = (t >= off) ? lds[t - off] : 0;
    __syncthreads();
    lds[t] += add;
    __syncthreads();
  }
  int run = lds[t] - s;  // exclusive prefix of this thread's chunk
#pragma unroll
  for (int k = 0; k < 4; ++k) {
    int i = base + t * 4 + k;
    if (i < N) excl[i] = run;
    run += v[k];
  }
  if (t == 255) bsum[blockIdx.x] = lds[255];
}

__global__ __launch_bounds__(256) void scan2(int* __restrict__ bsum, int nb) {
  __shared__ int lds[256];
  int t = threadIdx.x;
  int v = (t < nb) ? bsum[t] : 0;
  lds[t] = v;
  __syncthreads();
  for (int off = 1; off < 256; off <<= 1) {
    int add = (t >= off) ? lds[t - off] : 0;
    __syncthreads();
    lds[t] += add;
    __syncthreads();
  }
  if (t < nb) bsum[t] = lds[t] - v;  // exclusive
}

__global__ __launch_bounds__(256) void scan3(const int* __restrict__ excl,
                                             const int* __restrict__ bsum,
                                             int* __restrict__ rowptr, int N, int E) {
  int i = blockIdx.x * 256 + threadIdx.x;
  if (i < N) rowptr[i] = excl[i] + bsum[i >> 10];
  if (i == N) rowptr[N] = E;
}

__global__ __launch_bounds__(256) void fill_csr(const int* __restrict__ ei,
                                                const int* __restrict__ rowptr,
                                                int* __restrict__ cursor,
                                                int* __restrict__ csr, int E) {
  int e = blockIdx.x * 256 + threadIdx.x;
  if (e >= E) return;
  int s = ei[e], d = ei[E + e];
  int pos = rowptr[d] + atomicAdd(&cursor[d], 1);
  csr[pos] = s;
}

// ---------------- gather means (wave per node) ----------------
__global__ __launch_bounds__(256) void gather_mean_64(const float* __restrict__ xin,
                                                      const int* __restrict__ rowptr,
                                                      const int* __restrict__ csr,
                                                      float* __restrict__ mean, int N) {
  int w = (blockIdx.x * 256 + threadIdx.x) >> 6;
  int lane = threadIdx.x & 63;
  if (w >= N) return;
  int s0 = rowptr[w], s1 = rowptr[w + 1];
  float a0 = 0.f, a1 = 0.f, a2 = 0.f, a3 = 0.f;
  int e = s0;
  for (; e + 4 <= s1; e += 4) {
    int i0 = csr[e], i1 = csr[e + 1], i2 = csr[e + 2], i3 = csr[e + 3];
    a0 += xin[(size_t)i0 * 64 + lane];
    a1 += xin[(size_t)i1 * 64 + lane];
    a2 += xin[(size_t)i2 * 64 + lane];
    a3 += xin[(size_t)i3 * 64 + lane];
  }
  for (; e < s1; ++e) a0 += xin[(size_t)csr[e] * 64 + lane];
  float tot = (a0 + a1) + (a2 + a3);
  int c = s1 - s0;
  float inv = c > 0 ? 1.f / (float)c : 0.f;
  mean[(size_t)w * 64 + lane] = tot * inv;
}

__global__ __launch_bounds__(256) void gather_mean_128(const float* __restrict__ hin,
                                                       const int* __restrict__ rowptr,
                                                       const int* __restrict__ csr,
                                                       float* __restrict__ mean, int N) {
  int w = (blockIdx.x * 256 + threadIdx.x) >> 6;
  int lane = threadIdx.x & 63;
  if (w >= N) return;
  int s0 = rowptr[w], s1 = rowptr[w + 1];
  float ax0 = 0.f, ay0 = 0.f, ax1 = 0.f, ay1 = 0.f;
  float ax2 = 0.f, ay2 = 0.f, ax3 = 0.f, ay3 = 0.f;
  int e = s0;
  for (; e + 4 <= s1; e += 4) {
    const float2 v0 = *((const float2*)(hin + (size_t)csr[e]     * 128) + lane);
    const float2 v1 = *((const float2*)(hin + (size_t)csr[e + 1] * 128) + lane);
    const float2 v2 = *((const float2*)(hin + (size_t)csr[e + 2] * 128) + lane);
    const float2 v3 = *((const float2*)(hin + (size_t)csr[e + 3] * 128) + lane);
    ax0 += v0.x; ay0 += v0.y;
    ax1 += v1.x; ay1 += v1.y;
    ax2 += v2.x; ay2 += v2.y;
    ax3 += v3.x; ay3 += v3.y;
  }
  for (; e < s1; ++e) {
    const float2 v = *((const float2*)(hin + (size_t)csr[e] * 128) + lane);
    ax0 += v.x; ay0 += v.y;
  }
  float tx = (ax0 + ax1) + (ax2 + ax3);
  float ty = (ay0 + ay1) + (ay2 + ay3);
  int c = s1 - s0;
  float inv = c > 0 ? 1.f / (float)c : 0.f;
  float2* mp = (float2*)(mean + (size_t)w * 128) + lane;
  float2 o; o.x = tx * inv; o.y = ty * inv;
  *mp = o;
}

__global__ __launch_bounds__(256) void gather_mean_s(const float* __restrict__ val,
                                                     const int* __restrict__ rowptr,
                                                     const int* __restrict__ csr,
                                                     float* __restrict__ mean, int N) {
  int n = blockIdx.x * 256 + threadIdx.x;
  if (n >= N) return;
  int s0 = rowptr[n], s1 = rowptr[n + 1];
  float a = 0.f;
  for (int e = s0; e < s1; ++e) a += val[csr[e]];
  int c = s1 - s0;
  float inv = c > 0 ? 1.f / (float)c : 0.f;
  mean[n] = a * inv;
}

// ---------------- fused SAGE GEMM ----------------
// out[n][j] = act( sum_k a[n][k] * W[k][j] + bias[j] ),
//   a = [mean[n], prev[n]] (K2 = 2*KHALF dims), W = [Wl; Wr] (K2 x 128)
// FINAL: compute p[n]=h.W3l, q[n]=h.W3r instead of storing h.
#define DOUT 128
template<int KHALF, bool FINAL>
__global__ __launch_bounds__(256) void sage_gemm(
    const float* __restrict__ mean, const float* __restrict__ prev,
    const float* __restrict__ Wl, const float* __restrict__ Wr,
    const float* __restrict__ bias,
    const float* __restrict__ W3l, const float* __restrict__ W3r,
    float* __restrict__ out_h, float* __restrict__ out_p, float* __restrict__ out_q,
    int nNodes) {
  constexpr int K2 = 2 * KHALF;
  constexpr int NT = 8;  // nodes per block-iteration
  __shared__ float a_lds[NT][K2];
  __shared__ float Wt[64][DOUT];
  __shared__ float b_lds[DOUT];
  __shared__ float w3l_lds[DOUT], w3r_lds[DOUT];
  __shared__ float partp[4][4], partq[4][4];

  const int t = threadIdx.x;
  if (t < DOUT) {
    b_lds[t] = bias[t];
    if constexpr (FINAL) { w3l_lds[t] = W3l[t]; w3r_lds[t] = W3r[t]; }
  }
  const int j = t & (DOUT - 1);
  const int ng = t >> 7;
  const int lane = t & 63;
  const int wid = t >> 6;

  for (int base = blockIdx.x * NT; base < nNodes; base += gridDim.x * NT) {
    __syncthreads();  // S0
    for (int f = t; f < NT * K2; f += 256) {
      int n = f / K2, k = f - n * K2;
      int node = base + n;
      float v = 0.f;
      if (node < nNodes) {
        if (k < KHALF) v = mean[(size_t)node * KHALF + k];
        else           v = prev[(size_t)node * KHALF + (k - KHALF)];
      }
      a_lds[n][k] = v;
    }
    float acc[4] = {0.f, 0.f, 0.f, 0.f};
    for (int kt = 0; kt < K2 / 64; ++kt) {
      __syncthreads();  // S1
      for (int f = t; f < 64 * DOUT; f += 256) {
        int r = f >> 7, c = f & (DOUT - 1);
        int krow = kt * 64 + r;
        Wt[r][c] = (krow < KHALF) ? Wl[krow * DOUT + c] : Wr[(krow - KHALF) * DOUT + c];
      }
      __syncthreads();  // S2
#pragma unroll
      for (int k = 0; k < 64; ++k) {
        float w = Wt[k][j];
#pragma unroll
        for (int i = 0; i < 4; ++i)
          acc[i] = fmaf(w, a_lds[ng * 4 + i][kt * 64 + k], acc[i]);
      }
    }
    if constexpr (!FINAL) {
#pragma unroll
      for (int i = 0; i < 4; ++i) {
        int node = base + ng * 4 + i;
        if (node < nNodes) {
          float v = acc[i] + b_lds[j];
          out_h[(size_t)node * DOUT + j] = v > 0.f ? v : 0.f;
        }
      }
    } else {
#pragma unroll
      for (int i = 0; i < 4; ++i) {
        float v = acc[i] + b_lds[j];
        v = v > 0.f ? v : 0.f;
        float pv = v * w3l_lds[j];
        float qv = v * w3r_lds[j];
#pragma unroll
        for (int off = 1; off < 64; off <<= 1) {
          pv += __shfl_xor(pv, off);
          qv += __shfl_xor(qv, off);
        }
        if (lane == 0) { partp[wid][i] = pv; partq[wid][i] = qv; }
      }
      __syncthreads();  // S3
      if (t < 8) {
        int g = t >> 2, i = t & 3;
        int node = base + g * 4 + i;
        if (node < nNodes) {
          out_p[node] = partp[2 * g][i] + partp[2 * g + 1][i];
          out_q[node] = partq[2 * g][i] + partq[2 * g + 1][i];
        }
      }
    }
  }
}

// ---------------- h3 = mean(p) + q + b3 ; emit out_scalar ----------------
__global__ __launch_bounds__(256) void h3_kernel(const float* __restrict__ meanp,
                                                 const float* __restrict__ q,
                                                 const float* __restrict__ b3,
                                                 float* __restrict__ h3,
                                                 float* __restrict__ out_scalar, int nNodes) {
  int n = blockIdx.x * 256 + threadIdx.x;
  if (n >= nNodes) return;
  float v = meanp[n] + q[n] + b3[0];
  h3[n] = v;
  out_scalar[n] = v;
}

// ---------------- layer 4 + log_softmax ----------------
__global__ __launch_bounds__(256) void finalize(const float* __restrict__ mean3,
                                                const float* __restrict__ h3,
                                                const float* __restrict__ W4l,
                                                const float* __restrict__ W4r,
                                                const float* __restrict__ b4,
                                                float* __restrict__ out, int nNodes) {
  int n = blockIdx.x * 256 + threadIdx.x;
  if (n >= nNodes) return;
  float m = mean3[n];
  float hv = h3[n];
  float logits[8];
  float mx = -1e30f;
#pragma unroll
  for (int jj = 0; jj < 8; ++jj) {
    float v = m * W4l[jj] + hv * W4r[jj] + b4[jj];
    logits[jj] = v;
    mx = v > mx ? v : mx;
  }
  float s = 0.f;
#pragma unroll
  for (int jj = 0; jj < 8; ++jj) s += expf(logits[jj] - mx);
  float lse = mx + logf(s);
  float4 o0, o1;
  o0.x = logits[0] - lse; o0.y = logits[1] - lse; o0.z = logits[2] - lse; o0.w = logits[3] - lse;
  o1.x = logits[4] - lse; o1.y = logits[5] - lse; o1.z = logits[6] - lse; o1.w = logits[7] - lse;
  float4* o4 = (float4*)(out + (size_t)n * 8);
  o4[0] = o0; o4[1] = o1;
}

extern "C" void kernel_launch(void* const* d_in, const int* in_sizes, int n_in,
                              void* d_out, int out_size, void* d_ws, size_t ws_size,
                              hipStream_t stream) {
  const float* x   = (const float*)d_in[0];
  const int*   ei  = (const int*)d_in[1];
  const float* W1l = (const float*)d_in[2];
  const float* W1r = (const float*)d_in[3];
  const float* b1  = (const float*)d_in[4];
  const float* W2l = (const float*)d_in[5];
  const float* W2r = (const float*)d_in[6];
  const float* b2  = (const float*)d_in[7];
  const float* W3l = (const float*)d_in[8];
  const float* W3r = (const float*)d_in[9];
  const float* b3  = (const float*)d_in[10];
  const float* W4l = (const float*)d_in[11];
  const float* W4r = (const float*)d_in[12];
  const float* b4  = (const float*)d_in[13];

  const int N = in_sizes[0] / 64;   // 100000
  const int E = in_sizes[1] / 2;    // 1600000
  const size_t Ns = (size_t)N;

  // ---- workspace layout ----
  float* ws    = (float*)d_ws;
  float* h1    = ws;                 // 128N
  float* meanB = ws + 128 * Ns;      // 128N (mean0 uses first 64N; then mean1)
  float* p     = ws + 256 * Ns;      // N
  float* q     = ws + 257 * Ns;      // N
  float* meanp = ws + 258 * Ns;      // N
  float* h3    = ws + 259 * Ns;      // N
  float* mean3 = ws + 260 * Ns;      // N
  int* ib      = (int*)(ws + 261 * Ns);
  int* rowptr  = ib;                       // N+1
  int* deg     = ib + (N + 1);             // N
  int* excl    = ib + (N + 1) + N;         // N
  int* cursor  = ib + (N + 1) + 2 * N;     // N
  int* bsum    = ib + (N + 1) + 3 * N;     // 256
  int* csr     = ib + (N + 1) + 3 * N + 256;  // E

  float* out_rock   = (float*)d_out;            // N x 8
  float* out_scalar = (float*)d_out + 8 * Ns;   // N

  const int EB = (E + 255) / 256;        // 6250
  const int NB1 = (N + 1023) / 1024;     // 98 scan blocks
  const int NBn = (N + 256) / 256;       // covers N+1 indices

  // ---- CSR build ----
  hipMemsetAsync(deg, 0, Ns * sizeof(int), stream);
  hipMemsetAsync(cursor, 0, Ns * sizeof(int), stream);
  hist_kernel<<<EB, 256, 0, stream>>>(ei, deg, E);
  scan1<<<NB1, 256, 0, stream>>>(deg, excl, bsum, N);
  scan2<<<1, 256, 0, stream>>>(bsum, NB1);
  scan3<<<NBn, 256, 0, stream>>>(excl, bsum, rowptr, N, E);
  fill_csr<<<EB, 256, 0, stream>>>(ei, rowptr, cursor, csr, E);

  // ---- layer 1 ----
  gather_mean_64<<<(N + 3) / 4, 256, 0, stream>>>(x, rowptr, csr, meanB, N);
  sage_gemm<64, false><<<(N + 7) / 8, 256, 0, stream>>>(
      meanB, x, W1l, W1r, b1, nullptr, nullptr, h1, nullptr, nullptr, N);

  // ---- layer 2 (+ fused layer-3 projections p,q) ----
  gather_mean_128<<<(N + 3) / 4, 256, 0, stream>>>(h1, rowptr, csr, meanB, N);
  sage_gemm<128, true><<<(N + 7) / 8, 256, 0, stream>>>(
      meanB, h1, W2l, W2r, b2, W3l, W3r, nullptr, p, q, N);

  // ---- layer 3 (scalar) ----
  gather_mean_s<<<(N + 255) / 256, 256, 0, stream>>>(p, rowptr, csr, meanp, N);
  h3_kernel<<<(N + 255) / 256, 256, 0, stream>>>(meanp, q, b3, h3, out_scalar, N);

  // ---- layer 4 (scalar in, 8 out) ----
  gather_mean_s<<<(N + 255) / 256, 256, 0, stream>>>(h3, rowptr, csr, mean3, N);
  finalize<<<(N + 255) / 256, 256, 0, stream>>>(mean3, h3, W4l, W4r, b4, out_rock, N);
}

// Round 3
// 809.111 us; speedup vs baseline: 6.3911x; 1.6326x over previous
//
#include <hip/hip_runtime.h>
#include <hip/hip_bf16.h>
#include <math.h>

// GraphSAGE: 4 layers on N=100000 nodes, E=1600000 edges.
// Round 3: persistent-weight LDS GEMM (64 nodes x 64 cols per block).
//   h1 = relu(mean(x)@W1l + x@W1r + b1)          (N,128)
//   h2 = relu(mean(h1)@W2l + h1@W2r + b2)        (N,128)  [never materialized]
//   h3 = mean(p) + q + b3,  p=h2.W3l, q=h2.W3r   (N,1)
//   out_scalar = h3 ; out_rock = log_softmax(mean(h3)@W4l + h3@W4r + b4)

// ---------------- CSR build ----------------
__global__ __launch_bounds__(256) void hist_kernel(const int* __restrict__ ei,
                                                   int* __restrict__ deg, int E) {
  int e = blockIdx.x * 256 + threadIdx.x;
  if (e < E) atomicAdd(&deg[ei[E + e]], 1);
}

__global__ __launch_bounds__(256) void scan1(const int* __restrict__ deg,
                                             int* __restrict__ excl,
                                             int* __restrict__ bsum, int N) {
  __shared__ int lds[256];
  int t = threadIdx.x;
  int base = blockIdx.x * 1024;
  int v[4]; int s = 0;
#pragma unroll
  for (int k = 0; k < 4; ++k) {
    int i = base + t * 4 + k;
    v[k] = (i < N) ? deg[i] : 0;
    s += v[k];
  }
  lds[t] = s;
  __syncthreads();
  for (int off = 1; off < 256; off <<= 1) {
    int add = (t >= off) ? lds[t - off] : 0;
    __syncthreads();
    lds[t] += add;
    __syncthreads();
  }
  int run = lds[t] - s;
#pragma unroll
  for (int k = 0; k < 4; ++k) {
    int i = base + t * 4 + k;
    if (i < N) excl[i] = run;
    run += v[k];
  }
  if (t == 255) bsum[blockIdx.x] = lds[255];
}

__global__ __launch_bounds__(256) void scan2(int* __restrict__ bsum, int nb) {
  __shared__ int lds[256];
  int t = threadIdx.x;
  int v = (t < nb) ? bsum[t] : 0;
  lds[t] = v;
  __syncthreads();
  for (int off = 1; off < 256; off <<= 1) {
    int add = (t >= off) ? lds[t - off] : 0;
    __syncthreads();
    lds[t] += add;
    __syncthreads();
  }
  if (t < nb) bsum[t] = lds[t] - v;
}

__global__ __launch_bounds__(256) void scan3(const int* __restrict__ excl,
                                             const int* __restrict__ bsum,
                                             int* __restrict__ rowptr, int N, int E) {
  int i = blockIdx.x * 256 + threadIdx.x;
  if (i < N) rowptr[i] = excl[i] + bsum[i >> 10];
  if (i == N) rowptr[N] = E;
}

__global__ __launch_bounds__(256) void fill_csr(const int* __restrict__ ei,
                                                const int* __restrict__ rowptr,
                                                int* __restrict__ cursor,
                                                int* __restrict__ csr, int E) {
  int e = blockIdx.x * 256 + threadIdx.x;
  if (e >= E) return;
  int s = ei[e], d = ei[E + e];
  int pos = rowptr[d] + atomicAdd(&cursor[d], 1);
  csr[pos] = s;
}

// ---------------- gather means (wave per node) ----------------
__global__ __launch_bounds__(256) void gather_mean_64(const float* __restrict__ xin,
                                                      const int* __restrict__ rowptr,
                                                      const int* __restrict__ csr,
                                                      float* __restrict__ mean, int N) {
  int w = (blockIdx.x * 256 + threadIdx.x) >> 6;
  int lane = threadIdx.x & 63;
  if (w >= N) return;
  int s0 = rowptr[w], s1 = rowptr[w + 1];
  float a0 = 0.f, a1 = 0.f, a2 = 0.f, a3 = 0.f;
  int e = s0;
  for (; e + 4 <= s1; e += 4) {
    int i0 = csr[e], i1 = csr[e + 1], i2 = csr[e + 2], i3 = csr[e + 3];
    a0 += xin[(size_t)i0 * 64 + lane];
    a1 += xin[(size_t)i1 * 64 + lane];
    a2 += xin[(size_t)i2 * 64 + lane];
    a3 += xin[(size_t)i3 * 64 + lane];
  }
  for (; e < s1; ++e) a0 += xin[(size_t)csr[e] * 64 + lane];
  float tot = (a0 + a1) + (a2 + a3);
  int c = s1 - s0;
  float inv = c > 0 ? 1.f / (float)c : 0.f;
  mean[(size_t)w * 64 + lane] = tot * inv;
}

__global__ __launch_bounds__(256) void gather_mean_128(const float* __restrict__ hin,
                                                       const int* __restrict__ rowptr,
                                                       const int* __restrict__ csr,
                                                       float* __restrict__ mean, int N) {
  int w = (blockIdx.x * 256 + threadIdx.x) >> 6;
  int lane = threadIdx.x & 63;
  if (w >= N) return;
  int s0 = rowptr[w], s1 = rowptr[w + 1];
  float ax0 = 0.f, ay0 = 0.f, ax1 = 0.f, ay1 = 0.f;
  float ax2 = 0.f, ay2 = 0.f, ax3 = 0.f, ay3 = 0.f;
  int e = s0;
  for (; e + 4 <= s1; e += 4) {
    const float2 v0 = *((const float2*)(hin + (size_t)csr[e]     * 128) + lane);
    const float2 v1 = *((const float2*)(hin + (size_t)csr[e + 1] * 128) + lane);
    const float2 v2 = *((const float2*)(hin + (size_t)csr[e + 2] * 128) + lane);
    const float2 v3 = *((const float2*)(hin + (size_t)csr[e + 3] * 128) + lane);
    ax0 += v0.x; ay0 += v0.y;
    ax1 += v1.x; ay1 += v1.y;
    ax2 += v2.x; ay2 += v2.y;
    ax3 += v3.x; ay3 += v3.y;
  }
  for (; e < s1; ++e) {
    const float2 v = *((const float2*)(hin + (size_t)csr[e] * 128) + lane);
    ax0 += v.x; ay0 += v.y;
  }
  float tx = (ax0 + ax1) + (ax2 + ax3);
  float ty = (ay0 + ay1) + (ay2 + ay3);
  int c = s1 - s0;
  float inv = c > 0 ? 1.f / (float)c : 0.f;
  float2* mp = (float2*)(mean + (size_t)w * 128) + lane;
  float2 o; o.x = tx * inv; o.y = ty * inv;
  *mp = o;
}

__global__ __launch_bounds__(256) void gather_mean_s(const float* __restrict__ val,
                                                     const int* __restrict__ rowptr,
                                                     const int* __restrict__ csr,
                                                     float* __restrict__ mean, int N) {
  int n = blockIdx.x * 256 + threadIdx.x;
  if (n >= N) return;
  int s0 = rowptr[n], s1 = rowptr[n + 1];
  float a = 0.f;
  for (int e = s0; e < s1; ++e) a += val[csr[e]];
  int c = s1 - s0;
  float inv = c > 0 ? 1.f / (float)c : 0.f;
  mean[n] = a * inv;
}

// ---------------- SAGE GEMM v2 ----------------
// Block = 64 nodes (tile) x 64 output cols (y half). 512 threads = 8 waves.
// Wave g owns nodes tile+g*8 .. +8; lane = output col within half.
// LDS: Wt[64 j][K2 k] transposed, 16B-chunk XOR-swizzled (c ^= j&7) -> conflict-free
//      b128 reads; A[64 n][K2] read as wave-broadcast b128 (conflict-free).
// FINAL: p,q j-half partials via wave shuffle reduce -> outp/outq[y*N + node].
template<int KHALF, bool FINAL>
__global__ __launch_bounds__(512) void sage_gemm_v2(
    const float* __restrict__ mean, const float* __restrict__ prev,
    const float* __restrict__ Wl, const float* __restrict__ Wr,
    const float* __restrict__ bias,
    const float* __restrict__ W3l, const float* __restrict__ W3r,
    float* __restrict__ out_h, float* __restrict__ outp, float* __restrict__ outq,
    int N) {
  constexpr int K2 = 2 * KHALF;
  constexpr int KC = K2 / 4;       // 16B chunks per row
  __shared__ __align__(16) float Wt[64 * K2];
  __shared__ __align__(16) float A[64 * K2];

  const int t = threadIdx.x;
  const int lane = t & 63;
  const int g = t >> 6;            // wave id = node group
  const int y = blockIdx.y;        // j-half
  const int jg = y * 64 + lane;    // global output col
  const int tile = blockIdx.x * 64;

  // stage W slice: global [k][j] (coalesced) -> LDS transposed [j][k], swizzled
  for (int i = t; i < 64 * K2; i += 512) {
    int k = i >> 6, j = i & 63;
    float v = (k < KHALF) ? Wl[k * 128 + y * 64 + j]
                          : Wr[(k - KHALF) * 128 + y * 64 + j];
    int c = k >> 2;
    Wt[j * K2 + (((c ^ (j & 7)) << 2) | (k & 3))] = v;
  }
  // stage A tile: rows = [mean | prev]
  for (int i = t; i < 64 * KC; i += 512) {
    int n = i / KC, c = i - n * KC;
    int node = tile + n;
    float4 v = make_float4(0.f, 0.f, 0.f, 0.f);
    if (node < N) {
      if (c < KC / 2) v = *(const float4*)(mean + (size_t)node * KHALF + c * 4);
      else            v = *(const float4*)(prev + (size_t)node * KHALF + (c - KC / 2) * 4);
    }
    *(float4*)(A + n * K2 + c * 4) = v;
  }
  __syncthreads();

  float acc[8] = {0.f, 0.f, 0.f, 0.f, 0.f, 0.f, 0.f, 0.f};
  const float* Arow = A + g * 8 * K2;
  const float* Wrow = Wt + lane * K2;
  const int sw = lane & 7;
#pragma unroll 8
  for (int c = 0; c < KC; ++c) {
    const float4 w = *(const float4*)(Wrow + ((c ^ sw) << 2));
#pragma unroll
    for (int n = 0; n < 8; ++n) {
      const float4 a = *(const float4*)(Arow + n * K2 + (c << 2));
      acc[n] = fmaf(w.x, a.x, acc[n]);
      acc[n] = fmaf(w.y, a.y, acc[n]);
      acc[n] = fmaf(w.z, a.z, acc[n]);
      acc[n] = fmaf(w.w, a.w, acc[n]);
    }
  }

  const float b = bias[jg];
  if constexpr (!FINAL) {
#pragma unroll
    for (int n = 0; n < 8; ++n) {
      int node = tile + g * 8 + n;
      if (node < N) {
        float v = acc[n] + b;
        out_h[(size_t)node * 128 + jg] = v > 0.f ? v : 0.f;
      }
    }
  } else {
    const float wl = W3l[jg], wr = W3r[jg];
#pragma unroll
    for (int n = 0; n < 8; ++n) {
      float v = acc[n] + b;
      v = v > 0.f ? v : 0.f;
      float pv = v * wl, qv = v * wr;
#pragma unroll
      for (int off = 1; off < 64; off <<= 1) {
        pv += __shfl_xor(pv, off);
        qv += __shfl_xor(qv, off);
      }
      int node = tile + g * 8 + n;
      if (lane == 0 && node < N) {
        outp[(size_t)y * N + node] = pv;
        outq[(size_t)y * N + node] = qv;
      }
    }
  }
}

// ---------------- combine p halves ----------------
__global__ __launch_bounds__(256) void combine_p(const float* __restrict__ pA,
                                                 const float* __restrict__ pB,
                                                 float* __restrict__ p, int N) {
  int n = blockIdx.x * 256 + threadIdx.x;
  if (n < N) p[n] = pA[n] + pB[n];
}

// ---------------- h3 = mean(p) + qA + qB + b3 ; emit out_scalar ----------------
__global__ __launch_bounds__(256) void h3_kernel(const float* __restrict__ meanp,
                                                 const float* __restrict__ qA,
                                                 const float* __restrict__ qB,
                                                 const float* __restrict__ b3,
                                                 float* __restrict__ h3,
                                                 float* __restrict__ out_scalar, int N) {
  int n = blockIdx.x * 256 + threadIdx.x;
  if (n >= N) return;
  float v = meanp[n] + qA[n] + qB[n] + b3[0];
  h3[n] = v;
  out_scalar[n] = v;
}

// ---------------- layer 4 + log_softmax ----------------
__global__ __launch_bounds__(256) void finalize(const float* __restrict__ mean3,
                                                const float* __restrict__ h3,
                                                const float* __restrict__ W4l,
                                                const float* __restrict__ W4r,
                                                const float* __restrict__ b4,
                                                float* __restrict__ out, int N) {
  int n = blockIdx.x * 256 + threadIdx.x;
  if (n >= N) return;
  float m = mean3[n];
  float hv = h3[n];
  float logits[8];
  float mx = -1e30f;
#pragma unroll
  for (int jj = 0; jj < 8; ++jj) {
    float v = m * W4l[jj] + hv * W4r[jj] + b4[jj];
    logits[jj] = v;
    mx = v > mx ? v : mx;
  }
  float s = 0.f;
#pragma unroll
  for (int jj = 0; jj < 8; ++jj) s += expf(logits[jj] - mx);
  float lse = mx + logf(s);
  float4 o0, o1;
  o0.x = logits[0] - lse; o0.y = logits[1] - lse; o0.z = logits[2] - lse; o0.w = logits[3] - lse;
  o1.x = logits[4] - lse; o1.y = logits[5] - lse; o1.z = logits[6] - lse; o1.w = logits[7] - lse;
  float4* o4 = (float4*)(out + (size_t)n * 8);
  o4[0] = o0; o4[1] = o1;
}

extern "C" void kernel_launch(void* const* d_in, const int* in_sizes, int n_in,
                              void* d_out, int out_size, void* d_ws, size_t ws_size,
                              hipStream_t stream) {
  const float* x   = (const float*)d_in[0];
  const int*   ei  = (const int*)d_in[1];
  const float* W1l = (const float*)d_in[2];
  const float* W1r = (const float*)d_in[3];
  const float* b1  = (const float*)d_in[4];
  const float* W2l = (const float*)d_in[5];
  const float* W2r = (const float*)d_in[6];
  const float* b2  = (const float*)d_in[7];
  const float* W3l = (const float*)d_in[8];
  const float* W3r = (const float*)d_in[9];
  const float* b3  = (const float*)d_in[10];
  const float* W4l = (const float*)d_in[11];
  const float* W4r = (const float*)d_in[12];
  const float* b4  = (const float*)d_in[13];

  const int N = in_sizes[0] / 64;   // 100000
  const int E = in_sizes[1] / 2;    // 1600000
  const size_t Ns = (size_t)N;

  // ---- workspace layout ----
  float* ws    = (float*)d_ws;
  float* h1    = ws;                 // 128N
  float* meanB = ws + 128 * Ns;      // 128N (mean0 uses first 64N; then mean1)
  float* pA    = ws + 256 * Ns;      // N
  float* pB    = ws + 257 * Ns;      // N
  float* qA    = ws + 258 * Ns;      // N
  float* qB    = ws + 259 * Ns;      // N
  float* p     = ws + 260 * Ns;      // N
  float* meanp = ws + 261 * Ns;      // N
  float* h3    = ws + 262 * Ns;      // N
  float* mean3 = ws + 263 * Ns;      // N
  int* ib      = (int*)(ws + 264 * Ns);
  int* rowptr  = ib;                       // N+1
  int* deg     = ib + (N + 1);             // N
  int* excl    = ib + (N + 1) + N;         // N
  int* cursor  = ib + (N + 1) + 2 * N;     // N
  int* bsum    = ib + (N + 1) + 3 * N;     // 256
  int* csr     = ib + (N + 1) + 3 * N + 256;  // E

  float* out_rock   = (float*)d_out;            // N x 8
  float* out_scalar = (float*)d_out + 8 * Ns;   // N

  const int EB = (E + 255) / 256;
  const int NB1 = (N + 1023) / 1024;
  const int NBn = (N + 256) / 256;
  const dim3 ggrid((N + 63) / 64, 2);

  // ---- CSR build ----
  hipMemsetAsync(deg, 0, Ns * sizeof(int), stream);
  hipMemsetAsync(cursor, 0, Ns * sizeof(int), stream);
  hist_kernel<<<EB, 256, 0, stream>>>(ei, deg, E);
  scan1<<<NB1, 256, 0, stream>>>(deg, excl, bsum, N);
  scan2<<<1, 256, 0, stream>>>(bsum, NB1);
  scan3<<<NBn, 256, 0, stream>>>(excl, bsum, rowptr, N, E);
  fill_csr<<<EB, 256, 0, stream>>>(ei, rowptr, cursor, csr, E);

  // ---- layer 1 ----
  gather_mean_64<<<(N + 3) / 4, 256, 0, stream>>>(x, rowptr, csr, meanB, N);
  sage_gemm_v2<64, false><<<ggrid, 512, 0, stream>>>(
      meanB, x, W1l, W1r, b1, nullptr, nullptr, h1, nullptr, nullptr, N);

  // ---- layer 2 (+ fused layer-3 projections p,q) ----
  gather_mean_128<<<(N + 3) / 4, 256, 0, stream>>>(h1, rowptr, csr, meanB, N);
  sage_gemm_v2<128, true><<<ggrid, 512, 0, stream>>>(
      meanB, h1, W2l, W2r, b2, W3l, W3r, nullptr, pA, qA, N);
  // note: outp/outq indexed [y*N+node] -> pA..pB and qA..qB are contiguous pairs
  // (pA at 256N, pB at 257N; qA at 258N, qB at 259N) -- pass base pointers:
  // outp = pA (y=0 -> pA, y=1 -> pA+N = pB), outq = qA likewise.

  // ---- layer 3 (scalar) ----
  combine_p<<<(N + 255) / 256, 256, 0, stream>>>(pA, pB, p, N);
  gather_mean_s<<<(N + 255) / 256, 256, 0, stream>>>(p, rowptr, csr, meanp, N);
  h3_kernel<<<(N + 255) / 256, 256, 0, stream>>>(meanp, qA, qB, b3, h3, out_scalar, N);

  // ---- layer 4 (scalar in, 8 out) ----
  gather_mean_s<<<(N + 255) / 256, 256, 0, stream>>>(h3, rowptr, csr, mean3, N);
  finalize<<<(N + 255) / 256, 256, 0, stream>>>(mean3, h3, W4l, W4r, b4, out_rock, N);
}

// Round 4
// 681.823 us; speedup vs baseline: 7.5842x; 1.1867x over previous
//
#include <hip/hip_runtime.h>
#include <hip/hip_bf16.h>
#include <math.h>

// GraphSAGE: 4 layers on N=100000 nodes, E=1600000 edges.
// Round 4: 4x4 register-tiled fp32 GEMM (64 nodes x 64 cols / block, 256 thr).
//   h1 = relu(mean(x)@W1l + x@W1r + b1)          (N,128)
//   h2 = relu(mean(h1)@W2l + h1@W2r + b2)        (N,128)  [never materialized]
//   h3 = mean(p) + q + b3,  p=h2.W3l, q=h2.W3r   (N,1)
//   out_scalar = h3 ; out_rock = log_softmax(mean(h3)@W4l + h3@W4r + b4)

// ---------------- CSR build ----------------
__global__ __launch_bounds__(256) void hist_kernel(const int* __restrict__ ei,
                                                   int* __restrict__ deg, int E) {
  int e = blockIdx.x * 256 + threadIdx.x;
  if (e < E) atomicAdd(&deg[ei[E + e]], 1);
}

__global__ __launch_bounds__(256) void scan1(const int* __restrict__ deg,
                                             int* __restrict__ excl,
                                             int* __restrict__ bsum, int N) {
  __shared__ int lds[256];
  int t = threadIdx.x;
  int base = blockIdx.x * 1024;
  int v[4]; int s = 0;
#pragma unroll
  for (int k = 0; k < 4; ++k) {
    int i = base + t * 4 + k;
    v[k] = (i < N) ? deg[i] : 0;
    s += v[k];
  }
  lds[t] = s;
  __syncthreads();
  for (int off = 1; off < 256; off <<= 1) {
    int add = (t >= off) ? lds[t - off] : 0;
    __syncthreads();
    lds[t] += add;
    __syncthreads();
  }
  int run = lds[t] - s;
#pragma unroll
  for (int k = 0; k < 4; ++k) {
    int i = base + t * 4 + k;
    if (i < N) excl[i] = run;
    run += v[k];
  }
  if (t == 255) bsum[blockIdx.x] = lds[255];
}

__global__ __launch_bounds__(256) void scan2(int* __restrict__ bsum, int nb) {
  __shared__ int lds[256];
  int t = threadIdx.x;
  int v = (t < nb) ? bsum[t] : 0;
  lds[t] = v;
  __syncthreads();
  for (int off = 1; off < 256; off <<= 1) {
    int add = (t >= off) ? lds[t - off] : 0;
    __syncthreads();
    lds[t] += add;
    __syncthreads();
  }
  if (t < nb) bsum[t] = lds[t] - v;
}

__global__ __launch_bounds__(256) void scan3(const int* __restrict__ excl,
                                             const int* __restrict__ bsum,
                                             int* __restrict__ rowptr, int N, int E) {
  int i = blockIdx.x * 256 + threadIdx.x;
  if (i < N) rowptr[i] = excl[i] + bsum[i >> 10];
  if (i == N) rowptr[N] = E;
}

__global__ __launch_bounds__(256) void fill_csr(const int* __restrict__ ei,
                                                const int* __restrict__ rowptr,
                                                int* __restrict__ cursor,
                                                int* __restrict__ csr, int E) {
  int e = blockIdx.x * 256 + threadIdx.x;
  if (e >= E) return;
  int s = ei[e], d = ei[E + e];
  int pos = rowptr[d] + atomicAdd(&cursor[d], 1);
  csr[pos] = s;
}

// ---------------- gather means (wave per node) ----------------
__global__ __launch_bounds__(256) void gather_mean_64(const float* __restrict__ xin,
                                                      const int* __restrict__ rowptr,
                                                      const int* __restrict__ csr,
                                                      float* __restrict__ mean, int N) {
  int w = (blockIdx.x * 256 + threadIdx.x) >> 6;
  int lane = threadIdx.x & 63;
  if (w >= N) return;
  int s0 = rowptr[w], s1 = rowptr[w + 1];
  float a0 = 0.f, a1 = 0.f, a2 = 0.f, a3 = 0.f;
  int e = s0;
  for (; e + 4 <= s1; e += 4) {
    int i0 = csr[e], i1 = csr[e + 1], i2 = csr[e + 2], i3 = csr[e + 3];
    a0 += xin[(size_t)i0 * 64 + lane];
    a1 += xin[(size_t)i1 * 64 + lane];
    a2 += xin[(size_t)i2 * 64 + lane];
    a3 += xin[(size_t)i3 * 64 + lane];
  }
  for (; e < s1; ++e) a0 += xin[(size_t)csr[e] * 64 + lane];
  float tot = (a0 + a1) + (a2 + a3);
  int c = s1 - s0;
  float inv = c > 0 ? 1.f / (float)c : 0.f;
  mean[(size_t)w * 64 + lane] = tot * inv;
}

__global__ __launch_bounds__(256) void gather_mean_128(const float* __restrict__ hin,
                                                       const int* __restrict__ rowptr,
                                                       const int* __restrict__ csr,
                                                       float* __restrict__ mean, int N) {
  int w = (blockIdx.x * 256 + threadIdx.x) >> 6;
  int lane = threadIdx.x & 63;
  if (w >= N) return;
  int s0 = rowptr[w], s1 = rowptr[w + 1];
  float ax0 = 0.f, ay0 = 0.f, ax1 = 0.f, ay1 = 0.f;
  float ax2 = 0.f, ay2 = 0.f, ax3 = 0.f, ay3 = 0.f;
  int e = s0;
  for (; e + 4 <= s1; e += 4) {
    const float2 v0 = *((const float2*)(hin + (size_t)csr[e]     * 128) + lane);
    const float2 v1 = *((const float2*)(hin + (size_t)csr[e + 1] * 128) + lane);
    const float2 v2 = *((const float2*)(hin + (size_t)csr[e + 2] * 128) + lane);
    const float2 v3 = *((const float2*)(hin + (size_t)csr[e + 3] * 128) + lane);
    ax0 += v0.x; ay0 += v0.y;
    ax1 += v1.x; ay1 += v1.y;
    ax2 += v2.x; ay2 += v2.y;
    ax3 += v3.x; ay3 += v3.y;
  }
  for (; e < s1; ++e) {
    const float2 v = *((const float2*)(hin + (size_t)csr[e] * 128) + lane);
    ax0 += v.x; ay0 += v.y;
  }
  float tx = (ax0 + ax1) + (ax2 + ax3);
  float ty = (ay0 + ay1) + (ay2 + ay3);
  int c = s1 - s0;
  float inv = c > 0 ? 1.f / (float)c : 0.f;
  float2* mp = (float2*)(mean + (size_t)w * 128) + lane;
  float2 o; o.x = tx * inv; o.y = ty * inv;
  *mp = o;
}

__global__ __launch_bounds__(256) void gather_mean_s(const float* __restrict__ val,
                                                     const int* __restrict__ rowptr,
                                                     const int* __restrict__ csr,
                                                     float* __restrict__ mean, int N) {
  int n = blockIdx.x * 256 + threadIdx.x;
  if (n >= N) return;
  int s0 = rowptr[n], s1 = rowptr[n + 1];
  float a = 0.f;
  for (int e = s0; e < s1; ++e) a += val[csr[e]];
  int c = s1 - s0;
  float inv = c > 0 ? 1.f / (float)c : 0.f;
  mean[n] = a * inv;
}

// ---------------- SAGE GEMM v3: 4x4 register tile ----------------
// Block = 64 nodes x 64 cols (y-half). 256 threads = 4 waves.
// lane = ty*16+tx (ty: node group, tx: col group); wave w owns nodes w*16..+16.
// Thread computes nodes nb..nb+3 x cols jg..jg+3.
// LDS: W k-major [K2][64] (natural; read = 16 distinct chunks -> 2-way, free)
//      A node-major [64][K2+4] (pad 4 floats keeps 16B align, read 2-way free).
// Per 4-k chunk: 4 A-reads + 4 W-reads (b128) feed 64 FMA instrs.
template<int KHALF, bool FINAL>
__global__ __launch_bounds__(256) void sage_gemm_v3(
    const float* __restrict__ mean, const float* __restrict__ prev,
    const float* __restrict__ Wl, const float* __restrict__ Wr,
    const float* __restrict__ bias,
    const float* __restrict__ W3l, const float* __restrict__ W3r,
    float* __restrict__ out_h, float* __restrict__ outp, float* __restrict__ outq,
    int N) {
  constexpr int K2 = 2 * KHALF;
  constexpr int KC = K2 / 4;        // 16B chunks per A row
  constexpr int AS = K2 + 4;        // padded A row stride (floats)
  __shared__ __align__(16) float Wlds[K2 * 64];
  __shared__ __align__(16) float Alds[64 * AS];

  const int t = threadIdx.x;
  const int lane = t & 63;
  const int tx = lane & 15;
  const int ty = lane >> 4;
  const int w = t >> 6;
  const int y = blockIdx.y;
  const int tile = blockIdx.x * 64;
  const int nb = w * 16 + ty * 4;   // first of this thread's 4 nodes (in-tile)
  const int jc = tx * 4;            // first of 4 cols within half
  const int jg = y * 64 + jc;       // global col base

  // stage W: [k][64] (coalesced float4 per 16-lane group)
  for (int i = t; i < K2 * 16; i += 256) {
    int k = i >> 4, c = i & 15;
    const float* srcw = (k < KHALF) ? (Wl + (size_t)k * 128 + y * 64 + c * 4)
                                    : (Wr + (size_t)(k - KHALF) * 128 + y * 64 + c * 4);
    *(float4*)(Wlds + k * 64 + c * 4) = *(const float4*)srcw;
  }
  // stage A: [n][K2] node-major, rows = [mean | prev]
  for (int i = t; i < 64 * KC; i += 256) {
    int n = i / KC, c = i - n * KC;
    int node = tile + n;
    float4 v = make_float4(0.f, 0.f, 0.f, 0.f);
    if (node < N) {
      if (c < KC / 2) v = *(const float4*)(mean + (size_t)node * KHALF + c * 4);
      else            v = *(const float4*)(prev + (size_t)node * KHALF + (c - KC / 2) * 4);
    }
    *(float4*)(Alds + n * AS + c * 4) = v;
  }
  __syncthreads();

  float acc[4][4];
#pragma unroll
  for (int q = 0; q < 4; ++q)
#pragma unroll
    for (int jj = 0; jj < 4; ++jj) acc[q][jj] = 0.f;

#pragma unroll 2
  for (int c = 0; c < KC; ++c) {
    float4 a[4], wv[4];
#pragma unroll
    for (int q = 0; q < 4; ++q)
      a[q] = *(const float4*)(Alds + (nb + q) * AS + (c << 2));
#pragma unroll
    for (int r = 0; r < 4; ++r)
      wv[r] = *(const float4*)(Wlds + ((c << 2) + r) * 64 + jc);
#pragma unroll
    for (int r = 0; r < 4; ++r) {
#pragma unroll
      for (int q = 0; q < 4; ++q) {
        float ar = (r == 0) ? a[q].x : (r == 1) ? a[q].y : (r == 2) ? a[q].z : a[q].w;
        acc[q][0] = fmaf(ar, wv[r].x, acc[q][0]);
        acc[q][1] = fmaf(ar, wv[r].y, acc[q][1]);
        acc[q][2] = fmaf(ar, wv[r].z, acc[q][2]);
        acc[q][3] = fmaf(ar, wv[r].w, acc[q][3]);
      }
    }
  }

  const float4 b4 = *(const float4*)(bias + jg);
  if constexpr (!FINAL) {
#pragma unroll
    for (int q = 0; q < 4; ++q) {
      int node = tile + nb + q;
      if (node < N) {
        float4 o;
        o.x = acc[q][0] + b4.x; o.y = acc[q][1] + b4.y;
        o.z = acc[q][2] + b4.z; o.w = acc[q][3] + b4.w;
        o.x = o.x > 0.f ? o.x : 0.f;
        o.y = o.y > 0.f ? o.y : 0.f;
        o.z = o.z > 0.f ? o.z : 0.f;
        o.w = o.w > 0.f ? o.w : 0.f;
        *(float4*)(out_h + (size_t)node * 128 + jg) = o;
      }
    }
  } else {
    const float4 wl4 = *(const float4*)(W3l + jg);
    const float4 wr4 = *(const float4*)(W3r + jg);
#pragma unroll
    for (int q = 0; q < 4; ++q) {
      float h0 = acc[q][0] + b4.x; h0 = h0 > 0.f ? h0 : 0.f;
      float h1 = acc[q][1] + b4.y; h1 = h1 > 0.f ? h1 : 0.f;
      float h2 = acc[q][2] + b4.z; h2 = h2 > 0.f ? h2 : 0.f;
      float h3v = acc[q][3] + b4.w; h3v = h3v > 0.f ? h3v : 0.f;
      float pv = h0 * wl4.x + h1 * wl4.y + h2 * wl4.z + h3v * wl4.w;
      float qv = h0 * wr4.x + h1 * wr4.y + h2 * wr4.z + h3v * wr4.w;
#pragma unroll
      for (int off = 1; off < 16; off <<= 1) {
        pv += __shfl_xor(pv, off);
        qv += __shfl_xor(qv, off);
      }
      int node = tile + nb + q;
      if (tx == 0 && node < N) {
        outp[(size_t)y * N + node] = pv;
        outq[(size_t)y * N + node] = qv;
      }
    }
  }
}

// ---------------- combine p halves ----------------
__global__ __launch_bounds__(256) void combine_p(const float* __restrict__ pA,
                                                 const float* __restrict__ pB,
                                                 float* __restrict__ p, int N) {
  int n = blockIdx.x * 256 + threadIdx.x;
  if (n < N) p[n] = pA[n] + pB[n];
}

// ---------------- h3 = mean(p) + qA + qB + b3 ; emit out_scalar ----------------
__global__ __launch_bounds__(256) void h3_kernel(const float* __restrict__ meanp,
                                                 const float* __restrict__ qA,
                                                 const float* __restrict__ qB,
                                                 const float* __restrict__ b3,
                                                 float* __restrict__ h3,
                                                 float* __restrict__ out_scalar, int N) {
  int n = blockIdx.x * 256 + threadIdx.x;
  if (n >= N) return;
  float v = meanp[n] + qA[n] + qB[n] + b3[0];
  h3[n] = v;
  out_scalar[n] = v;
}

// ---------------- layer 4 + log_softmax ----------------
__global__ __launch_bounds__(256) void finalize(const float* __restrict__ mean3,
                                                const float* __restrict__ h3,
                                                const float* __restrict__ W4l,
                                                const float* __restrict__ W4r,
                                                const float* __restrict__ b4,
                                                float* __restrict__ out, int N) {
  int n = blockIdx.x * 256 + threadIdx.x;
  if (n >= N) return;
  float m = mean3[n];
  float hv = h3[n];
  float logits[8];
  float mx = -1e30f;
#pragma unroll
  for (int jj = 0; jj < 8; ++jj) {
    float v = m * W4l[jj] + hv * W4r[jj] + b4[jj];
    logits[jj] = v;
    mx = v > mx ? v : mx;
  }
  float s = 0.f;
#pragma unroll
  for (int jj = 0; jj < 8; ++jj) s += expf(logits[jj] - mx);
  float lse = mx + logf(s);
  float4 o0, o1;
  o0.x = logits[0] - lse; o0.y = logits[1] - lse; o0.z = logits[2] - lse; o0.w = logits[3] - lse;
  o1.x = logits[4] - lse; o1.y = logits[5] - lse; o1.z = logits[6] - lse; o1.w = logits[7] - lse;
  float4* o4 = (float4*)(out + (size_t)n * 8);
  o4[0] = o0; o4[1] = o1;
}

extern "C" void kernel_launch(void* const* d_in, const int* in_sizes, int n_in,
                              void* d_out, int out_size, void* d_ws, size_t ws_size,
                              hipStream_t stream) {
  const float* x   = (const float*)d_in[0];
  const int*   ei  = (const int*)d_in[1];
  const float* W1l = (const float*)d_in[2];
  const float* W1r = (const float*)d_in[3];
  const float* b1  = (const float*)d_in[4];
  const float* W2l = (const float*)d_in[5];
  const float* W2r = (const float*)d_in[6];
  const float* b2  = (const float*)d_in[7];
  const float* W3l = (const float*)d_in[8];
  const float* W3r = (const float*)d_in[9];
  const float* b3  = (const float*)d_in[10];
  const float* W4l = (const float*)d_in[11];
  const float* W4r = (const float*)d_in[12];
  const float* b4  = (const float*)d_in[13];

  const int N = in_sizes[0] / 64;   // 100000
  const int E = in_sizes[1] / 2;    // 1600000
  const size_t Ns = (size_t)N;

  // ---- workspace layout ----
  float* ws    = (float*)d_ws;
  float* h1    = ws;                 // 128N
  float* meanB = ws + 128 * Ns;      // 128N (mean0 uses first 64N; then mean1)
  float* pA    = ws + 256 * Ns;      // N
  float* pB    = ws + 257 * Ns;      // N
  float* qA    = ws + 258 * Ns;      // N
  float* qB    = ws + 259 * Ns;      // N
  float* p     = ws + 260 * Ns;      // N
  float* meanp = ws + 261 * Ns;      // N
  float* h3    = ws + 262 * Ns;      // N
  float* mean3 = ws + 263 * Ns;      // N
  int* ib      = (int*)(ws + 264 * Ns);
  int* rowptr  = ib;                       // N+1
  int* deg     = ib + (N + 1);             // N
  int* excl    = ib + (N + 1) + N;         // N
  int* cursor  = ib + (N + 1) + 2 * N;     // N
  int* bsum    = ib + (N + 1) + 3 * N;     // 256
  int* csr     = ib + (N + 1) + 3 * N + 256;  // E

  float* out_rock   = (float*)d_out;            // N x 8
  float* out_scalar = (float*)d_out + 8 * Ns;   // N

  const int EB = (E + 255) / 256;
  const int NB1 = (N + 1023) / 1024;
  const int NBn = (N + 256) / 256;
  const dim3 ggrid((N + 63) / 64, 2);

  // ---- CSR build ----
  hipMemsetAsync(deg, 0, Ns * sizeof(int), stream);
  hipMemsetAsync(cursor, 0, Ns * sizeof(int), stream);
  hist_kernel<<<EB, 256, 0, stream>>>(ei, deg, E);
  scan1<<<NB1, 256, 0, stream>>>(deg, excl, bsum, N);
  scan2<<<1, 256, 0, stream>>>(bsum, NB1);
  scan3<<<NBn, 256, 0, stream>>>(excl, bsum, rowptr, N, E);
  fill_csr<<<EB, 256, 0, stream>>>(ei, rowptr, cursor, csr, E);

  // ---- layer 1 ----
  gather_mean_64<<<(N + 3) / 4, 256, 0, stream>>>(x, rowptr, csr, meanB, N);
  sage_gemm_v3<64, false><<<ggrid, 256, 0, stream>>>(
      meanB, x, W1l, W1r, b1, nullptr, nullptr, h1, nullptr, nullptr, N);

  // ---- layer 2 (+ fused layer-3 projections p,q) ----
  gather_mean_128<<<(N + 3) / 4, 256, 0, stream>>>(h1, rowptr, csr, meanB, N);
  sage_gemm_v3<128, true><<<ggrid, 256, 0, stream>>>(
      meanB, h1, W2l, W2r, b2, W3l, W3r, nullptr, pA, qA, N);
  // outp/outq indexed [y*N+node]: y=0 -> pA/qA, y=1 -> pB/qB (contiguous).

  // ---- layer 3 (scalar) ----
  combine_p<<<(N + 255) / 256, 256, 0, stream>>>(pA, pB, p, N);
  gather_mean_s<<<(N + 255) / 256, 256, 0, stream>>>(p, rowptr, csr, meanp, N);
  h3_kernel<<<(N + 255) / 256, 256, 0, stream>>>(meanp, qA, qB, b3, h3, out_scalar, N);

  // ---- layer 4 (scalar in, 8 out) ----
  gather_mean_s<<<(N + 255) / 256, 256, 0, stream>>>(h3, rowptr, csr, mean3, N);
  finalize<<<(N + 255) / 256, 256, 0, stream>>>(mean3, h3, W4l, W4r, b4, out_rock, N);
}

// Round 5
// 430.727 us; speedup vs baseline: 12.0054x; 1.5830x over previous
//
#include <hip/hip_runtime.h>
#include <hip/hip_bf16.h>
#include <math.h>

// GraphSAGE: 4 layers on N=100000 nodes, E=1600000 edges.
// Round 5: bf16 feature path + MFMA 16x16x32 GEMMs + bf16 gathers.
//   h1 = relu(mean(x)@W1l + x@W1r + b1)          (N,128) bf16
//   h2 = relu(mean(h1)@W2l + h1@W2r + b2)        (N,128) bf16
//   h3 = mean(p) + q + b3,  p=h2.W3l, q=h2.W3r   (N,1)   fp32
//   out_scalar = h3 ; out_rock = log_softmax(mean(h3)@W4l + h3@W4r + b4)

typedef unsigned short u16;
typedef unsigned int u32;
typedef __attribute__((ext_vector_type(4))) float f32x4;
typedef __attribute__((ext_vector_type(8))) short s16x8;

__device__ __forceinline__ float b2f(u16 u) {
  union { float f; u32 i; } v; v.i = ((u32)u) << 16; return v.f;
}
__device__ __forceinline__ u16 f2b(float f) {
  union { float f; u32 u; } v; v.f = f;
  u32 r = v.u + 0x7fffu + ((v.u >> 16) & 1u);   // RTN-even
  return (u16)(r >> 16);
}

// ---------------- CSR build ----------------
__global__ __launch_bounds__(256) void hist_kernel(const int* __restrict__ ei,
                                                   int* __restrict__ deg, int E) {
  int e = blockIdx.x * 256 + threadIdx.x;
  if (e < E) atomicAdd(&deg[ei[E + e]], 1);
}

__global__ __launch_bounds__(256) void scan1(const int* __restrict__ deg,
                                             int* __restrict__ excl,
                                             int* __restrict__ bsum, int N) {
  __shared__ int lds[256];
  int t = threadIdx.x;
  int base = blockIdx.x * 1024;
  int v[4]; int s = 0;
#pragma unroll
  for (int k = 0; k < 4; ++k) {
    int i = base + t * 4 + k;
    v[k] = (i < N) ? deg[i] : 0;
    s += v[k];
  }
  lds[t] = s;
  __syncthreads();
  for (int off = 1; off < 256; off <<= 1) {
    int add = (t >= off) ? lds[t - off] : 0;
    __syncthreads();
    lds[t] += add;
    __syncthreads();
  }
  int run = lds[t] - s;
#pragma unroll
  for (int k = 0; k < 4; ++k) {
    int i = base + t * 4 + k;
    if (i < N) excl[i] = run;
    run += v[k];
  }
  if (t == 255) bsum[blockIdx.x] = lds[255];
}

__global__ __launch_bounds__(256) void scan2(int* __restrict__ bsum, int nb) {
  __shared__ int lds[256];
  int t = threadIdx.x;
  int v = (t < nb) ? bsum[t] : 0;
  lds[t] = v;
  __syncthreads();
  for (int off = 1; off < 256; off <<= 1) {
    int add = (t >= off) ? lds[t - off] : 0;
    __syncthreads();
    lds[t] += add;
    __syncthreads();
  }
  if (t < nb) bsum[t] = lds[t] - v;
}

__global__ __launch_bounds__(256) void scan3(const int* __restrict__ excl,
                                             const int* __restrict__ bsum,
                                             int* __restrict__ rowptr, int N, int E) {
  int i = blockIdx.x * 256 + threadIdx.x;
  if (i < N) rowptr[i] = excl[i] + bsum[i >> 10];
  if (i == N) rowptr[N] = E;
}

__global__ __launch_bounds__(256) void fill_csr(const int* __restrict__ ei,
                                                const int* __restrict__ rowptr,
                                                int* __restrict__ cursor,
                                                int* __restrict__ csr, int E) {
  int e = blockIdx.x * 256 + threadIdx.x;
  if (e >= E) return;
  int s = ei[e], d = ei[E + e];
  int pos = rowptr[d] + atomicAdd(&cursor[d], 1);
  csr[pos] = s;
}

// ---------------- conversions ----------------
__global__ __launch_bounds__(256) void cvt_x(const float* __restrict__ x,
                                             u16* __restrict__ xb, int total4) {
  int i = blockIdx.x * 256 + threadIdx.x;
  if (i >= total4) return;
  float4 v = *(const float4*)(x + (size_t)i * 4);
  u32 lo = (u32)f2b(v.x) | ((u32)f2b(v.y) << 16);
  u32 hi = (u32)f2b(v.z) | ((u32)f2b(v.w) << 16);
  uint2 o; o.x = lo; o.y = hi;
  *(uint2*)(xb + (size_t)i * 4) = o;
}

// Wt1[j][k] k<64->W1l[k][j] else W1r ; Wt2[j][k] k<128->W2l[k][j] else W2r
__global__ __launch_bounds__(256) void cvt_w(const float* __restrict__ W1l,
                                             const float* __restrict__ W1r,
                                             const float* __restrict__ W2l,
                                             const float* __restrict__ W2r,
                                             u16* __restrict__ wt1,
                                             u16* __restrict__ wt2) {
  int i = blockIdx.x * 256 + threadIdx.x;
  if (i < 16384) {                 // Wt1: 128 x 128
    int j = i >> 7, k = i & 127;
    float v = (k < 64) ? W1l[k * 128 + j] : W1r[(k - 64) * 128 + j];
    wt1[j * 128 + k] = f2b(v);
  } else if (i < 16384 + 32768) {  // Wt2: 128 x 256
    int i2 = i - 16384;
    int j = i2 >> 8, k = i2 & 255;
    float v = (k < 128) ? W2l[k * 128 + j] : W2r[(k - 128) * 128 + j];
    wt2[j * 256 + k] = f2b(v);
  }
}

// ---------------- gather means (bf16) ----------------
// 64-dim: half-wave (32 lanes) per node, lane holds dims 2*ln, 2*ln+1
__global__ __launch_bounds__(256) void gather_mean_64b(const u16* __restrict__ xb,
                                                       const int* __restrict__ rowptr,
                                                       const int* __restrict__ csr,
                                                       u16* __restrict__ mean, int N) {
  int n = (blockIdx.x * 256 + threadIdx.x) >> 5;
  int ln = threadIdx.x & 31;
  if (n >= N) return;
  int s0 = rowptr[n], s1 = rowptr[n + 1];
  float ax0 = 0.f, ay0 = 0.f, ax1 = 0.f, ay1 = 0.f;
  float ax2 = 0.f, ay2 = 0.f, ax3 = 0.f, ay3 = 0.f;
  int e = s0;
  for (; e + 4 <= s1; e += 4) {
    u32 v0 = *(const u32*)(xb + (size_t)csr[e]     * 64 + ln * 2);
    u32 v1 = *(const u32*)(xb + (size_t)csr[e + 1] * 64 + ln * 2);
    u32 v2 = *(const u32*)(xb + (size_t)csr[e + 2] * 64 + ln * 2);
    u32 v3 = *(const u32*)(xb + (size_t)csr[e + 3] * 64 + ln * 2);
    ax0 += b2f((u16)v0); ay0 += b2f((u16)(v0 >> 16));
    ax1 += b2f((u16)v1); ay1 += b2f((u16)(v1 >> 16));
    ax2 += b2f((u16)v2); ay2 += b2f((u16)(v2 >> 16));
    ax3 += b2f((u16)v3); ay3 += b2f((u16)(v3 >> 16));
  }
  for (; e < s1; ++e) {
    u32 v = *(const u32*)(xb + (size_t)csr[e] * 64 + ln * 2);
    ax0 += b2f((u16)v); ay0 += b2f((u16)(v >> 16));
  }
  float tx = (ax0 + ax1) + (ax2 + ax3);
  float ty = (ay0 + ay1) + (ay2 + ay3);
  int c = s1 - s0;
  float inv = c > 0 ? 1.f / (float)c : 0.f;
  u32 o = (u32)f2b(tx * inv) | ((u32)f2b(ty * inv) << 16);
  *(u32*)(mean + (size_t)n * 64 + ln * 2) = o;
}

// 128-dim: full wave per node, lane holds dims 2*lane, 2*lane+1
__global__ __launch_bounds__(256) void gather_mean_128b(const u16* __restrict__ hb,
                                                        const int* __restrict__ rowptr,
                                                        const int* __restrict__ csr,
                                                        u16* __restrict__ mean, int N) {
  int n = (blockIdx.x * 256 + threadIdx.x) >> 6;
  int lane = threadIdx.x & 63;
  if (n >= N) return;
  int s0 = rowptr[n], s1 = rowptr[n + 1];
  float ax0 = 0.f, ay0 = 0.f, ax1 = 0.f, ay1 = 0.f;
  float ax2 = 0.f, ay2 = 0.f, ax3 = 0.f, ay3 = 0.f;
  int e = s0;
  for (; e + 4 <= s1; e += 4) {
    u32 v0 = *(const u32*)(hb + (size_t)csr[e]     * 128 + lane * 2);
    u32 v1 = *(const u32*)(hb + (size_t)csr[e + 1] * 128 + lane * 2);
    u32 v2 = *(const u32*)(hb + (size_t)csr[e + 2] * 128 + lane * 2);
    u32 v3 = *(const u32*)(hb + (size_t)csr[e + 3] * 128 + lane * 2);
    ax0 += b2f((u16)v0); ay0 += b2f((u16)(v0 >> 16));
    ax1 += b2f((u16)v1); ay1 += b2f((u16)(v1 >> 16));
    ax2 += b2f((u16)v2); ay2 += b2f((u16)(v2 >> 16));
    ax3 += b2f((u16)v3); ay3 += b2f((u16)(v3 >> 16));
  }
  for (; e < s1; ++e) {
    u32 v = *(const u32*)(hb + (size_t)csr[e] * 128 + lane * 2);
    ax0 += b2f((u16)v); ay0 += b2f((u16)(v >> 16));
  }
  float tx = (ax0 + ax1) + (ax2 + ax3);
  float ty = (ay0 + ay1) + (ay2 + ay3);
  int c = s1 - s0;
  float inv = c > 0 ? 1.f / (float)c : 0.f;
  u32 o = (u32)f2b(tx * inv) | ((u32)f2b(ty * inv) << 16);
  *(u32*)(mean + (size_t)n * 128 + lane * 2) = o;
}

__global__ __launch_bounds__(256) void gather_mean_s(const float* __restrict__ val,
                                                     const int* __restrict__ rowptr,
                                                     const int* __restrict__ csr,
                                                     float* __restrict__ mean, int N) {
  int n = blockIdx.x * 256 + threadIdx.x;
  if (n >= N) return;
  int s0 = rowptr[n], s1 = rowptr[n + 1];
  float a = 0.f;
  for (int e = s0; e < s1; ++e) a += val[csr[e]];
  int c = s1 - s0;
  float inv = c > 0 ? 1.f / (float)c : 0.f;
  mean[n] = a * inv;
}

// ---------------- MFMA GEMM ----------------
// out[n][j] = relu( [mean[n] | prev[n]] (K2) dot W[.][j] + bias[j] ), j=0..127
// Block: 512 thr = 8 waves, tile BM=128 nodes x BN=128 cols.
// Wave wid: wm=wid>>1 (32-node band), wn=wid&1 (64-col half); 2x4 16x16 frags.
// LDS: A[128][K2] bf16, Wt[128 cols][K2] bf16, both 16B-chunk XOR-swizzled
//      (chunk ^= row&7) -> a/b-frag ds_read_b128 is 2-way max (free).
template<int K2>
__global__ __launch_bounds__(512) void mfma_gemm(
    const u16* __restrict__ meanb, const u16* __restrict__ prevb,
    const u16* __restrict__ wt,    // [128][K2] bf16 (pre-transposed)
    const float* __restrict__ bias,
    u16* __restrict__ hout, int N) {
  constexpr int KH = K2 / 2;
  constexpr int NC = K2 / 8;       // 16B chunks per row
  __shared__ __align__(16) u16 Albs[128 * K2];
  __shared__ __align__(16) u16 Wlds[128 * K2];

  const int t = threadIdx.x;
  const int tile = blockIdx.x * 128;

  // stage Wt (from global, coalesced) -> swizzled LDS
  for (int i = t; i < 128 * NC; i += 512) {
    int j = i / NC, c = i - j * NC;
    uint4 v = *(const uint4*)(wt + (size_t)j * K2 + c * 8);
    *(uint4*)(Wlds + j * K2 + ((c ^ (j & 7)) << 3)) = v;
  }
  // stage A rows = [mean | prev]
  for (int i = t; i < 128 * NC; i += 512) {
    int r = i / NC, c = i - r * NC;
    int node = tile + r;
    uint4 v; v.x = 0; v.y = 0; v.z = 0; v.w = 0;
    if (node < N) {
      int k0 = c * 8;
      v = (k0 < KH) ? *(const uint4*)(meanb + (size_t)node * KH + k0)
                    : *(const uint4*)(prevb + (size_t)node * KH + (k0 - KH));
    }
    *(uint4*)(Albs + r * K2 + ((c ^ (r & 7)) << 3)) = v;
  }
  __syncthreads();

  const int lane = t & 63;
  const int wid = t >> 6;
  const int wm = wid >> 1, wn = wid & 1;
  const int er = lane & 15;
  const int kg = lane >> 4;

  f32x4 acc[2][4];
#pragma unroll
  for (int mi = 0; mi < 2; ++mi)
#pragma unroll
    for (int ni = 0; ni < 4; ++ni) acc[mi][ni] = (f32x4)(0.f);

#pragma unroll
  for (int ks = 0; ks < K2 / 32; ++ks) {
    int cidx = ks * 4 + kg;
    s16x8 a[2], b[4];
#pragma unroll
    for (int mi = 0; mi < 2; ++mi) {
      int row = wm * 32 + mi * 16 + er;
      a[mi] = *(const s16x8*)(Albs + row * K2 + ((cidx ^ (row & 7)) << 3));
    }
#pragma unroll
    for (int ni = 0; ni < 4; ++ni) {
      int col = wn * 64 + ni * 16 + er;
      b[ni] = *(const s16x8*)(Wlds + col * K2 + ((cidx ^ (col & 7)) << 3));
    }
#pragma unroll
    for (int mi = 0; mi < 2; ++mi)
#pragma unroll
      for (int ni = 0; ni < 4; ++ni)
        acc[mi][ni] = __builtin_amdgcn_mfma_f32_16x16x32_bf16(a[mi], b[ni], acc[mi][ni], 0, 0, 0);
  }

  // epilogue: D row = kg*4 + r (within frag), col = er
#pragma unroll
  for (int mi = 0; mi < 2; ++mi) {
#pragma unroll
    for (int ni = 0; ni < 4; ++ni) {
      int col = wn * 64 + ni * 16 + er;
      float bv = bias[col];
#pragma unroll
      for (int r = 0; r < 4; ++r) {
        int node = tile + wm * 32 + mi * 16 + kg * 4 + r;
        if (node < N) {
          float v = acc[mi][ni][r] + bv;
          v = v > 0.f ? v : 0.f;
          hout[(size_t)node * 128 + col] = f2b(v);
        }
      }
    }
  }
}

// ---------------- p,q projections of h2 ----------------
__global__ __launch_bounds__(256) void pq_kernel(const u16* __restrict__ h2b,
                                                 const float* __restrict__ W3l,
                                                 const float* __restrict__ W3r,
                                                 float* __restrict__ p,
                                                 float* __restrict__ q, int N) {
  int n = (blockIdx.x * 256 + threadIdx.x) >> 6;
  int lane = threadIdx.x & 63;
  if (n >= N) return;
  u32 v = *(const u32*)(h2b + (size_t)n * 128 + lane * 2);
  float h0 = b2f((u16)v), h1 = b2f((u16)(v >> 16));
  float pv = h0 * W3l[lane * 2] + h1 * W3l[lane * 2 + 1];
  float qv = h0 * W3r[lane * 2] + h1 * W3r[lane * 2 + 1];
#pragma unroll
  for (int off = 1; off < 64; off <<= 1) {
    pv += __shfl_xor(pv, off);
    qv += __shfl_xor(qv, off);
  }
  if (lane == 0) { p[n] = pv; q[n] = qv; }
}

// ---------------- h3 = mean(p) + q + b3 ; emit out_scalar ----------------
__global__ __launch_bounds__(256) void h3_kernel(const float* __restrict__ meanp,
                                                 const float* __restrict__ q,
                                                 const float* __restrict__ b3,
                                                 float* __restrict__ h3,
                                                 float* __restrict__ out_scalar, int N) {
  int n = blockIdx.x * 256 + threadIdx.x;
  if (n >= N) return;
  float v = meanp[n] + q[n] + b3[0];
  h3[n] = v;
  out_scalar[n] = v;
}

// ---------------- layer 4 + log_softmax ----------------
__global__ __launch_bounds__(256) void finalize(const float* __restrict__ mean3,
                                                const float* __restrict__ h3,
                                                const float* __restrict__ W4l,
                                                const float* __restrict__ W4r,
                                                const float* __restrict__ b4,
                                                float* __restrict__ out, int N) {
  int n = blockIdx.x * 256 + threadIdx.x;
  if (n >= N) return;
  float m = mean3[n];
  float hv = h3[n];
  float logits[8];
  float mx = -1e30f;
#pragma unroll
  for (int jj = 0; jj < 8; ++jj) {
    float v = m * W4l[jj] + hv * W4r[jj] + b4[jj];
    logits[jj] = v;
    mx = v > mx ? v : mx;
  }
  float s = 0.f;
#pragma unroll
  for (int jj = 0; jj < 8; ++jj) s += expf(logits[jj] - mx);
  float lse = mx + logf(s);
  float4 o0, o1;
  o0.x = logits[0] - lse; o0.y = logits[1] - lse; o0.z = logits[2] - lse; o0.w = logits[3] - lse;
  o1.x = logits[4] - lse; o1.y = logits[5] - lse; o1.z = logits[6] - lse; o1.w = logits[7] - lse;
  float4* o4 = (float4*)(out + (size_t)n * 8);
  o4[0] = o0; o4[1] = o1;
}

extern "C" void kernel_launch(void* const* d_in, const int* in_sizes, int n_in,
                              void* d_out, int out_size, void* d_ws, size_t ws_size,
                              hipStream_t stream) {
  const float* x   = (const float*)d_in[0];
  const int*   ei  = (const int*)d_in[1];
  const float* W1l = (const float*)d_in[2];
  const float* W1r = (const float*)d_in[3];
  const float* b1  = (const float*)d_in[4];
  const float* W2l = (const float*)d_in[5];
  const float* W2r = (const float*)d_in[6];
  const float* b2  = (const float*)d_in[7];
  const float* W3l = (const float*)d_in[8];
  const float* W3r = (const float*)d_in[9];
  const float* b3  = (const float*)d_in[10];
  const float* W4l = (const float*)d_in[11];
  const float* W4r = (const float*)d_in[12];
  const float* b4  = (const float*)d_in[13];

  const int N = in_sizes[0] / 64;   // 100000
  const int E = in_sizes[1] / 2;    // 1600000
  const size_t Ns = (size_t)N;

  // ---- workspace layout ----
  u16* ub      = (u16*)d_ws;
  u16* xb      = ub;                 // 64N
  u16* mean0b  = ub + 64 * Ns;       // 64N
  u16* h1b     = ub + 128 * Ns;      // 128N
  u16* mean1b  = ub + 256 * Ns;      // 128N
  u16* h2b     = ub + 384 * Ns;      // 128N
  u16* wt1     = ub + 512 * Ns;      // 16384
  u16* wt2     = wt1 + 16384;        // 32768
  float* fb    = (float*)(wt2 + 32768);
  float* p     = fb;                 // N
  float* q     = fb + Ns;            // N
  float* meanp = fb + 2 * Ns;        // N
  float* h3    = fb + 3 * Ns;        // N
  float* mean3 = fb + 4 * Ns;        // N
  int* ib      = (int*)(fb + 5 * Ns);
  int* rowptr  = ib;                       // N+1
  int* deg     = ib + (N + 1);             // N
  int* excl    = ib + (N + 1) + N;         // N
  int* cursor  = ib + (N + 1) + 2 * N;     // N
  int* bsum    = ib + (N + 1) + 3 * N;     // 256
  int* csr     = ib + (N + 1) + 3 * N + 256;  // E

  float* out_rock   = (float*)d_out;            // N x 8
  float* out_scalar = (float*)d_out + 8 * Ns;   // N

  const int EB = (E + 255) / 256;
  const int NB1 = (N + 1023) / 1024;
  const int NBn = (N + 256) / 256;
  const int GG = (N + 127) / 128;   // mfma grid

  // ---- CSR build ----
  hipMemsetAsync(deg, 0, Ns * sizeof(int), stream);
  hipMemsetAsync(cursor, 0, Ns * sizeof(int), stream);
  hist_kernel<<<EB, 256, 0, stream>>>(ei, deg, E);
  scan1<<<NB1, 256, 0, stream>>>(deg, excl, bsum, N);
  scan2<<<1, 256, 0, stream>>>(bsum, NB1);
  scan3<<<NBn, 256, 0, stream>>>(excl, bsum, rowptr, N, E);
  fill_csr<<<EB, 256, 0, stream>>>(ei, rowptr, cursor, csr, E);

  // ---- conversions (overlap with CSR build on same stream order) ----
  cvt_x<<<(N * 16 + 255) / 256, 256, 0, stream>>>(x, xb, N * 16);
  cvt_w<<<192, 256, 0, stream>>>(W1l, W1r, W2l, W2r, wt1, wt2);

  // ---- layer 1 ----
  gather_mean_64b<<<(N + 7) / 8, 256, 0, stream>>>(xb, rowptr, csr, mean0b, N);
  mfma_gemm<128><<<GG, 512, 0, stream>>>(mean0b, xb, wt1, b1, h1b, N);

  // ---- layer 2 ----
  gather_mean_128b<<<(N + 3) / 4, 256, 0, stream>>>(h1b, rowptr, csr, mean1b, N);
  mfma_gemm<256><<<GG, 512, 0, stream>>>(mean1b, h1b, wt2, b2, h2b, N);

  // ---- layer 3 (scalar) ----
  pq_kernel<<<(N + 3) / 4, 256, 0, stream>>>(h2b, W3l, W3r, p, q, N);
  gather_mean_s<<<(N + 255) / 256, 256, 0, stream>>>(p, rowptr, csr, meanp, N);
  h3_kernel<<<(N + 255) / 256, 256, 0, stream>>>(meanp, q, b3, h3, out_scalar, N);

  // ---- layer 4 (scalar in, 8 out) ----
  gather_mean_s<<<(N + 255) / 256, 256, 0, stream>>>(h3, rowptr, csr, mean3, N);
  finalize<<<(N + 255) / 256, 256, 0, stream>>>(mean3, h3, W4l, W4r, b4, out_rock, N);
}

// Round 6
// 338.042 us; speedup vs baseline: 15.2971x; 1.2742x over previous
//
#include <hip/hip_runtime.h>
#include <hip/hip_bf16.h>
#include <math.h>

// GraphSAGE: 4 layers on N=100000 nodes, E=1600000 edges.
// Round 6: bucketed two-pass CSR fill (kills fill_csr's 17x write amplification)
//          + fused layer-3/4 scalar kernels. bf16 MFMA path unchanged.

typedef unsigned short u16;
typedef unsigned int u32;
typedef __attribute__((ext_vector_type(4))) float f32x4;
typedef __attribute__((ext_vector_type(8))) short s16x8;

__device__ __forceinline__ float b2f(u16 u) {
  union { float f; u32 i; } v; v.i = ((u32)u) << 16; return v.f;
}
__device__ __forceinline__ u16 f2b(float f) {
  union { float f; u32 u; } v; v.f = f;
  u32 r = v.u + 0x7fffu + ((v.u >> 16) & 1u);   // RTN-even
  return (u16)(r >> 16);
}

// ---------------- CSR build: histogram + scan ----------------
__global__ __launch_bounds__(256) void hist_kernel(const int* __restrict__ ei,
                                                   int* __restrict__ deg, int E) {
  int e = blockIdx.x * 256 + threadIdx.x;
  if (e < E) atomicAdd(&deg[ei[E + e]], 1);
}

__global__ __launch_bounds__(256) void scan1(const int* __restrict__ deg,
                                             int* __restrict__ excl,
                                             int* __restrict__ bsum, int N) {
  __shared__ int lds[256];
  int t = threadIdx.x;
  int base = blockIdx.x * 1024;
  int v[4]; int s = 0;
#pragma unroll
  for (int k = 0; k < 4; ++k) {
    int i = base + t * 4 + k;
    v[k] = (i < N) ? deg[i] : 0;
    s += v[k];
  }
  lds[t] = s;
  __syncthreads();
  for (int off = 1; off < 256; off <<= 1) {
    int add = (t >= off) ? lds[t - off] : 0;
    __syncthreads();
    lds[t] += add;
    __syncthreads();
  }
  int run = lds[t] - s;
#pragma unroll
  for (int k = 0; k < 4; ++k) {
    int i = base + t * 4 + k;
    if (i < N) excl[i] = run;
    run += v[k];
  }
  if (t == 255) bsum[blockIdx.x] = lds[255];
}

__global__ __launch_bounds__(256) void scan2(int* __restrict__ bsum, int nb) {
  __shared__ int lds[256];
  int t = threadIdx.x;
  int v = (t < nb) ? bsum[t] : 0;
  lds[t] = v;
  __syncthreads();
  for (int off = 1; off < 256; off <<= 1) {
    int add = (t >= off) ? lds[t - off] : 0;
    __syncthreads();
    lds[t] += add;
    __syncthreads();
  }
  if (t < nb) bsum[t] = lds[t] - v;
}

__global__ __launch_bounds__(256) void scan3(const int* __restrict__ excl,
                                             const int* __restrict__ bsum,
                                             int* __restrict__ rowptr, int N, int E) {
  int i = blockIdx.x * 256 + threadIdx.x;
  if (i < N) rowptr[i] = excl[i] + bsum[i >> 10];
  if (i == N) rowptr[N] = E;
}

// gcur[b] = rowptr[min(b*128, N)]
__global__ __launch_bounds__(256) void init_gcur(const int* __restrict__ rowptr,
                                                 int* __restrict__ gcur, int B, int N) {
  int b = blockIdx.x * 256 + threadIdx.x;
  if (b < B) {
    int node = b << 7;
    gcur[b] = rowptr[node < N ? node : N];
  }
}

// ---------------- pass 1: bucketize edges by dst>>7, LDS-staged coalesced write ----
// T=8192 edges/block, 512 threads. staging[slot] = src | ((dst&127)<<17).
__global__ __launch_bounds__(512) void bucketize(const int* __restrict__ ei,
                                                 int* __restrict__ gcur,
                                                 u32* __restrict__ staging,
                                                 int E, int B) {
  __shared__ u32 vals[8192];
  __shared__ u16 bkt[8192];
  __shared__ int hist[1024], ofs[1024], curx[1024], gbase[1024];
  __shared__ int wsum[512];

  const int t = threadIdx.x;
  const int base = blockIdx.x * 8192;
  const int cnt = min(8192, E - base);

  for (int b = t; b < 1024; b += 512) hist[b] = 0;
  __syncthreads();

  // histogram
  for (int k = t; k < cnt; k += 512) {
    int d = ei[E + base + k];
    atomicAdd(&hist[d >> 7], 1);
  }
  __syncthreads();

  // exclusive scan over 1024 (2 per thread)
  int a0 = hist[2 * t], a1 = hist[2 * t + 1];
  int s = a0 + a1;
  wsum[t] = s;
  __syncthreads();
  for (int off = 1; off < 512; off <<= 1) {
    int add = (t >= off) ? wsum[t - off] : 0;
    __syncthreads();
    wsum[t] += add;
    __syncthreads();
  }
  int excl = wsum[t] - s;
  ofs[2 * t] = excl;
  ofs[2 * t + 1] = excl + a0;
  __syncthreads();

  // reserve global slices + init local cursors
  for (int b = t; b < B; b += 512) {
    int c = hist[b];
    gbase[b] = c ? atomicAdd(&gcur[b], c) : 0;
    curx[b] = ofs[b];
  }
  __syncthreads();

  // stage values bucket-sorted in LDS
  for (int k = t; k < cnt; k += 512) {
    int sv = ei[base + k];
    int d = ei[E + base + k];
    int b = d >> 7;
    u32 val = (u32)sv | ((u32)(d & 127) << 17);
    int lpos = atomicAdd(&curx[b], 1);
    vals[lpos] = val;
    bkt[lpos] = (u16)b;
  }
  __syncthreads();

  // coalesced-ish write-out (runs of same bucket are consecutive)
  for (int i = t; i < cnt; i += 512) {
    int b = bkt[i];
    staging[gbase[b] + (i - ofs[b])] = vals[i];
  }
}

// ---------------- pass 2: place within bucket (one block per bucket) ----------------
__global__ __launch_bounds__(256) void place(const u32* __restrict__ staging,
                                             const int* __restrict__ rowptr,
                                             int* __restrict__ csr, int N) {
  __shared__ int lrp[129];
  __shared__ int cur[128];
  const int t = threadIdx.x;
  const int node0 = blockIdx.x << 7;
  const int nn = min(128, N - node0);
  if (t <= nn) lrp[t] = rowptr[node0 + t];
  if (t < nn) cur[t] = 0;
  __syncthreads();
  const int rstart = lrp[0], rend = lrp[nn];
  for (int i = rstart + t; i < rend; i += 256) {
    u32 v = staging[i];
    int nl = v >> 17;
    int src = v & 0x1FFFF;
    int tk = atomicAdd(&cur[nl], 1);
    csr[lrp[nl] + tk] = src;
  }
}

// ---------------- conversions ----------------
__global__ __launch_bounds__(256) void cvt_x(const float* __restrict__ x,
                                             u16* __restrict__ xb, int total4) {
  int i = blockIdx.x * 256 + threadIdx.x;
  if (i >= total4) return;
  float4 v = *(const float4*)(x + (size_t)i * 4);
  u32 lo = (u32)f2b(v.x) | ((u32)f2b(v.y) << 16);
  u32 hi = (u32)f2b(v.z) | ((u32)f2b(v.w) << 16);
  uint2 o; o.x = lo; o.y = hi;
  *(uint2*)(xb + (size_t)i * 4) = o;
}

__global__ __launch_bounds__(256) void cvt_w(const float* __restrict__ W1l,
                                             const float* __restrict__ W1r,
                                             const float* __restrict__ W2l,
                                             const float* __restrict__ W2r,
                                             u16* __restrict__ wt1,
                                             u16* __restrict__ wt2) {
  int i = blockIdx.x * 256 + threadIdx.x;
  if (i < 16384) {                 // Wt1: 128 x 128
    int j = i >> 7, k = i & 127;
    float v = (k < 64) ? W1l[k * 128 + j] : W1r[(k - 64) * 128 + j];
    wt1[j * 128 + k] = f2b(v);
  } else if (i < 16384 + 32768) {  // Wt2: 128 x 256
    int i2 = i - 16384;
    int j = i2 >> 8, k = i2 & 255;
    float v = (k < 128) ? W2l[k * 128 + j] : W2r[(k - 128) * 128 + j];
    wt2[j * 256 + k] = f2b(v);
  }
}

// ---------------- gather means (bf16) ----------------
__global__ __launch_bounds__(256) void gather_mean_64b(const u16* __restrict__ xb,
                                                       const int* __restrict__ rowptr,
                                                       const int* __restrict__ csr,
                                                       u16* __restrict__ mean, int N) {
  int n = (blockIdx.x * 256 + threadIdx.x) >> 5;
  int ln = threadIdx.x & 31;
  if (n >= N) return;
  int s0 = rowptr[n], s1 = rowptr[n + 1];
  float ax0 = 0.f, ay0 = 0.f, ax1 = 0.f, ay1 = 0.f;
  float ax2 = 0.f, ay2 = 0.f, ax3 = 0.f, ay3 = 0.f;
  int e = s0;
  for (; e + 4 <= s1; e += 4) {
    u32 v0 = *(const u32*)(xb + (size_t)csr[e]     * 64 + ln * 2);
    u32 v1 = *(const u32*)(xb + (size_t)csr[e + 1] * 64 + ln * 2);
    u32 v2 = *(const u32*)(xb + (size_t)csr[e + 2] * 64 + ln * 2);
    u32 v3 = *(const u32*)(xb + (size_t)csr[e + 3] * 64 + ln * 2);
    ax0 += b2f((u16)v0); ay0 += b2f((u16)(v0 >> 16));
    ax1 += b2f((u16)v1); ay1 += b2f((u16)(v1 >> 16));
    ax2 += b2f((u16)v2); ay2 += b2f((u16)(v2 >> 16));
    ax3 += b2f((u16)v3); ay3 += b2f((u16)(v3 >> 16));
  }
  for (; e < s1; ++e) {
    u32 v = *(const u32*)(xb + (size_t)csr[e] * 64 + ln * 2);
    ax0 += b2f((u16)v); ay0 += b2f((u16)(v >> 16));
  }
  float tx = (ax0 + ax1) + (ax2 + ax3);
  float ty = (ay0 + ay1) + (ay2 + ay3);
  int c = s1 - s0;
  float inv = c > 0 ? 1.f / (float)c : 0.f;
  u32 o = (u32)f2b(tx * inv) | ((u32)f2b(ty * inv) << 16);
  *(u32*)(mean + (size_t)n * 64 + ln * 2) = o;
}

__global__ __launch_bounds__(256) void gather_mean_128b(const u16* __restrict__ hb,
                                                        const int* __restrict__ rowptr,
                                                        const int* __restrict__ csr,
                                                        u16* __restrict__ mean, int N) {
  int n = (blockIdx.x * 256 + threadIdx.x) >> 6;
  int lane = threadIdx.x & 63;
  if (n >= N) return;
  int s0 = rowptr[n], s1 = rowptr[n + 1];
  float ax0 = 0.f, ay0 = 0.f, ax1 = 0.f, ay1 = 0.f;
  float ax2 = 0.f, ay2 = 0.f, ax3 = 0.f, ay3 = 0.f;
  int e = s0;
  for (; e + 4 <= s1; e += 4) {
    u32 v0 = *(const u32*)(hb + (size_t)csr[e]     * 128 + lane * 2);
    u32 v1 = *(const u32*)(hb + (size_t)csr[e + 1] * 128 + lane * 2);
    u32 v2 = *(const u32*)(hb + (size_t)csr[e + 2] * 128 + lane * 2);
    u32 v3 = *(const u32*)(hb + (size_t)csr[e + 3] * 128 + lane * 2);
    ax0 += b2f((u16)v0); ay0 += b2f((u16)(v0 >> 16));
    ax1 += b2f((u16)v1); ay1 += b2f((u16)(v1 >> 16));
    ax2 += b2f((u16)v2); ay2 += b2f((u16)(v2 >> 16));
    ax3 += b2f((u16)v3); ay3 += b2f((u16)(v3 >> 16));
  }
  for (; e < s1; ++e) {
    u32 v = *(const u32*)(hb + (size_t)csr[e] * 128 + lane * 2);
    ax0 += b2f((u16)v); ay0 += b2f((u16)(v >> 16));
  }
  float tx = (ax0 + ax1) + (ax2 + ax3);
  float ty = (ay0 + ay1) + (ay2 + ay3);
  int c = s1 - s0;
  float inv = c > 0 ? 1.f / (float)c : 0.f;
  u32 o = (u32)f2b(tx * inv) | ((u32)f2b(ty * inv) << 16);
  *(u32*)(mean + (size_t)n * 128 + lane * 2) = o;
}

// ---------------- MFMA GEMM (unchanged from round 5) ----------------
template<int K2>
__global__ __launch_bounds__(512) void mfma_gemm(
    const u16* __restrict__ meanb, const u16* __restrict__ prevb,
    const u16* __restrict__ wt,    // [128][K2] bf16 (pre-transposed)
    const float* __restrict__ bias,
    u16* __restrict__ hout, int N) {
  constexpr int KH = K2 / 2;
  constexpr int NC = K2 / 8;
  __shared__ __align__(16) u16 Albs[128 * K2];
  __shared__ __align__(16) u16 Wlds[128 * K2];

  const int t = threadIdx.x;
  const int tile = blockIdx.x * 128;

  for (int i = t; i < 128 * NC; i += 512) {
    int j = i / NC, c = i - j * NC;
    uint4 v = *(const uint4*)(wt + (size_t)j * K2 + c * 8);
    *(uint4*)(Wlds + j * K2 + ((c ^ (j & 7)) << 3)) = v;
  }
  for (int i = t; i < 128 * NC; i += 512) {
    int r = i / NC, c = i - r * NC;
    int node = tile + r;
    uint4 v; v.x = 0; v.y = 0; v.z = 0; v.w = 0;
    if (node < N) {
      int k0 = c * 8;
      v = (k0 < KH) ? *(const uint4*)(meanb + (size_t)node * KH + k0)
                    : *(const uint4*)(prevb + (size_t)node * KH + (k0 - KH));
    }
    *(uint4*)(Albs + r * K2 + ((c ^ (r & 7)) << 3)) = v;
  }
  __syncthreads();

  const int lane = t & 63;
  const int wid = t >> 6;
  const int wm = wid >> 1, wn = wid & 1;
  const int er = lane & 15;
  const int kg = lane >> 4;

  f32x4 acc[2][4];
#pragma unroll
  for (int mi = 0; mi < 2; ++mi)
#pragma unroll
    for (int ni = 0; ni < 4; ++ni) acc[mi][ni] = (f32x4)(0.f);

#pragma unroll
  for (int ks = 0; ks < K2 / 32; ++ks) {
    int cidx = ks * 4 + kg;
    s16x8 a[2], b[4];
#pragma unroll
    for (int mi = 0; mi < 2; ++mi) {
      int row = wm * 32 + mi * 16 + er;
      a[mi] = *(const s16x8*)(Albs + row * K2 + ((cidx ^ (row & 7)) << 3));
    }
#pragma unroll
    for (int ni = 0; ni < 4; ++ni) {
      int col = wn * 64 + ni * 16 + er;
      b[ni] = *(const s16x8*)(Wlds + col * K2 + ((cidx ^ (col & 7)) << 3));
    }
#pragma unroll
    for (int mi = 0; mi < 2; ++mi)
#pragma unroll
      for (int ni = 0; ni < 4; ++ni)
        acc[mi][ni] = __builtin_amdgcn_mfma_f32_16x16x32_bf16(a[mi], b[ni], acc[mi][ni], 0, 0, 0);
  }

#pragma unroll
  for (int mi = 0; mi < 2; ++mi) {
#pragma unroll
    for (int ni = 0; ni < 4; ++ni) {
      int col = wn * 64 + ni * 16 + er;
      float bv = bias[col];
#pragma unroll
      for (int r = 0; r < 4; ++r) {
        int node = tile + wm * 32 + mi * 16 + kg * 4 + r;
        if (node < N) {
          float v = acc[mi][ni][r] + bv;
          v = v > 0.f ? v : 0.f;
          hout[(size_t)node * 128 + col] = f2b(v);
        }
      }
    }
  }
}

// ---------------- p,q projections of h2 ----------------
__global__ __launch_bounds__(256) void pq_kernel(const u16* __restrict__ h2b,
                                                 const float* __restrict__ W3l,
                                                 const float* __restrict__ W3r,
                                                 float* __restrict__ p,
                                                 float* __restrict__ q, int N) {
  int n = (blockIdx.x * 256 + threadIdx.x) >> 6;
  int lane = threadIdx.x & 63;
  if (n >= N) return;
  u32 v = *(const u32*)(h2b + (size_t)n * 128 + lane * 2);
  float h0 = b2f((u16)v), h1 = b2f((u16)(v >> 16));
  float pv = h0 * W3l[lane * 2] + h1 * W3l[lane * 2 + 1];
  float qv = h0 * W3r[lane * 2] + h1 * W3r[lane * 2 + 1];
#pragma unroll
  for (int off = 1; off < 64; off <<= 1) {
    pv += __shfl_xor(pv, off);
    qv += __shfl_xor(qv, off);
  }
  if (lane == 0) { p[n] = pv; q[n] = qv; }
}

// ---------------- layer 3 fused: h3 = mean_e(p) + q + b3 ; out_scalar ----------------
__global__ __launch_bounds__(256) void gather3_fused(const float* __restrict__ p,
                                                     const int* __restrict__ rowptr,
                                                     const int* __restrict__ csr,
                                                     const float* __restrict__ q,
                                                     const float* __restrict__ b3,
                                                     float* __restrict__ h3,
                                                     float* __restrict__ out_scalar, int N) {
  int n = blockIdx.x * 256 + threadIdx.x;
  if (n >= N) return;
  int s0 = rowptr[n], s1 = rowptr[n + 1];
  float a = 0.f;
  for (int e = s0; e < s1; ++e) a += p[csr[e]];
  int c = s1 - s0;
  float inv = c > 0 ? 1.f / (float)c : 0.f;
  float v = a * inv + q[n] + b3[0];
  h3[n] = v;
  out_scalar[n] = v;
}

// ---------------- layer 4 fused: mean_e(h3) -> logits -> log_softmax ----------------
__global__ __launch_bounds__(256) void gather4_fused(const float* __restrict__ h3,
                                                     const int* __restrict__ rowptr,
                                                     const int* __restrict__ csr,
                                                     const float* __restrict__ W4l,
                                                     const float* __restrict__ W4r,
                                                     const float* __restrict__ b4,
                                                     float* __restrict__ out, int N) {
  int n = blockIdx.x * 256 + threadIdx.x;
  if (n >= N) return;
  int s0 = rowptr[n], s1 = rowptr[n + 1];
  float a = 0.f;
  for (int e = s0; e < s1; ++e) a += h3[csr[e]];
  int c = s1 - s0;
  float inv = c > 0 ? 1.f / (float)c : 0.f;
  float m = a * inv;
  float hv = h3[n];
  float logits[8];
  float mx = -1e30f;
#pragma unroll
  for (int jj = 0; jj < 8; ++jj) {
    float v = m * W4l[jj] + hv * W4r[jj] + b4[jj];
    logits[jj] = v;
    mx = v > mx ? v : mx;
  }
  float s = 0.f;
#pragma unroll
  for (int jj = 0; jj < 8; ++jj) s += expf(logits[jj] - mx);
  float lse = mx + logf(s);
  float4 o0, o1;
  o0.x = logits[0] - lse; o0.y = logits[1] - lse; o0.z = logits[2] - lse; o0.w = logits[3] - lse;
  o1.x = logits[4] - lse; o1.y = logits[5] - lse; o1.z = logits[6] - lse; o1.w = logits[7] - lse;
  float4* o4 = (float4*)(out + (size_t)n * 8);
  o4[0] = o0; o4[1] = o1;
}

extern "C" void kernel_launch(void* const* d_in, const int* in_sizes, int n_in,
                              void* d_out, int out_size, void* d_ws, size_t ws_size,
                              hipStream_t stream) {
  const float* x   = (const float*)d_in[0];
  const int*   ei  = (const int*)d_in[1];
  const float* W1l = (const float*)d_in[2];
  const float* W1r = (const float*)d_in[3];
  const float* b1  = (const float*)d_in[4];
  const float* W2l = (const float*)d_in[5];
  const float* W2r = (const float*)d_in[6];
  const float* b2  = (const float*)d_in[7];
  const float* W3l = (const float*)d_in[8];
  const float* W3r = (const float*)d_in[9];
  const float* b3  = (const float*)d_in[10];
  const float* W4l = (const float*)d_in[11];
  const float* W4r = (const float*)d_in[12];
  const float* b4  = (const float*)d_in[13];

  const int N = in_sizes[0] / 64;   // 100000
  const int E = in_sizes[1] / 2;    // 1600000
  const size_t Ns = (size_t)N;
  const int B = (N + 127) >> 7;     // 782 buckets (must be <= 1024)

  // ---- workspace layout ----
  u16* ub      = (u16*)d_ws;
  u16* xb      = ub;                 // 64N
  u16* mean0b  = ub + 64 * Ns;       // 64N
  u16* h1b     = ub + 128 * Ns;      // 128N
  u16* mean1b  = ub + 256 * Ns;      // 128N
  u16* h2b     = ub + 384 * Ns;      // 128N
  u16* wt1     = ub + 512 * Ns;      // 16384
  u16* wt2     = wt1 + 16384;        // 32768
  float* fb    = (float*)(wt2 + 32768);
  float* p     = fb;                 // N
  float* q     = fb + Ns;            // N
  float* h3    = fb + 2 * Ns;        // N
  int* ib      = (int*)(fb + 3 * Ns);
  int* rowptr  = ib;                          // N+1
  int* deg     = ib + (N + 1);                // N
  int* excl    = ib + (N + 1) + N;            // N
  int* bsum    = ib + (N + 1) + 2 * N;        // 256
  int* gcur    = ib + (N + 1) + 2 * N + 256;  // 1024
  int* csr     = gcur + 1024;                 // E
  u32* staging = (u32*)(csr + E);             // E

  float* out_rock   = (float*)d_out;            // N x 8
  float* out_scalar = (float*)d_out + 8 * Ns;   // N

  const int EB = (E + 255) / 256;
  const int NB1 = (N + 1023) / 1024;
  const int NBn = (N + 256) / 256;
  const int GG = (N + 127) / 128;

  // ---- CSR build ----
  hipMemsetAsync(deg, 0, Ns * sizeof(int), stream);
  hist_kernel<<<EB, 256, 0, stream>>>(ei, deg, E);
  scan1<<<NB1, 256, 0, stream>>>(deg, excl, bsum, N);
  scan2<<<1, 256, 0, stream>>>(bsum, NB1);
  scan3<<<NBn, 256, 0, stream>>>(excl, bsum, rowptr, N, E);
  init_gcur<<<(B + 255) / 256, 256, 0, stream>>>(rowptr, gcur, B, N);
  bucketize<<<(E + 8191) / 8192, 512, 0, stream>>>(ei, gcur, staging, E, B);
  place<<<B, 256, 0, stream>>>(staging, rowptr, csr, N);

  // ---- conversions ----
  cvt_x<<<(N * 16 + 255) / 256, 256, 0, stream>>>(x, xb, N * 16);
  cvt_w<<<192, 256, 0, stream>>>(W1l, W1r, W2l, W2r, wt1, wt2);

  // ---- layer 1 ----
  gather_mean_64b<<<(N + 7) / 8, 256, 0, stream>>>(xb, rowptr, csr, mean0b, N);
  mfma_gemm<128><<<GG, 512, 0, stream>>>(mean0b, xb, wt1, b1, h1b, N);

  // ---- layer 2 ----
  gather_mean_128b<<<(N + 3) / 4, 256, 0, stream>>>(h1b, rowptr, csr, mean1b, N);
  mfma_gemm<256><<<GG, 512, 0, stream>>>(mean1b, h1b, wt2, b2, h2b, N);

  // ---- layer 3 (scalar) ----
  pq_kernel<<<(N + 3) / 4, 256, 0, stream>>>(h2b, W3l, W3r, p, q, N);
  gather3_fused<<<(N + 255) / 256, 256, 0, stream>>>(p, rowptr, csr, q, b3, h3, out_scalar, N);

  // ---- layer 4 (scalar in, 8 out) ----
  gather4_fused<<<(N + 255) / 256, 256, 0, stream>>>(h3, rowptr, csr, W4l, W4r, b4, out_rock, N);
}

// Round 7
// 304.145 us; speedup vs baseline: 17.0020x; 1.1114x over previous
//
#include <hip/hip_runtime.h>
#include <hip/hip_bf16.h>
#include <math.h>

// GraphSAGE: 4 layers on N=100000 nodes, E=1600000 edges.
// Round 7: high-MLP gathers (4-8 rows per wave-load) + pq fused into GEMM-2 epilogue.

typedef unsigned short u16;
typedef unsigned int u32;
typedef __attribute__((ext_vector_type(4))) float f32x4;
typedef __attribute__((ext_vector_type(8))) short s16x8;

__device__ __forceinline__ float b2f(u16 u) {
  union { float f; u32 i; } v; v.i = ((u32)u) << 16; return v.f;
}
__device__ __forceinline__ u16 f2b(float f) {
  union { float f; u32 u; } v; v.f = f;
  u32 r = v.u + 0x7fffu + ((v.u >> 16) & 1u);   // RTN-even
  return (u16)(r >> 16);
}

// ---------------- CSR build: histogram + scan ----------------
__global__ __launch_bounds__(256) void hist_kernel(const int* __restrict__ ei,
                                                   int* __restrict__ deg, int E) {
  int e = blockIdx.x * 256 + threadIdx.x;
  if (e < E) atomicAdd(&deg[ei[E + e]], 1);
}

__global__ __launch_bounds__(256) void scan1(const int* __restrict__ deg,
                                             int* __restrict__ excl,
                                             int* __restrict__ bsum, int N) {
  __shared__ int lds[256];
  int t = threadIdx.x;
  int base = blockIdx.x * 1024;
  int v[4]; int s = 0;
#pragma unroll
  for (int k = 0; k < 4; ++k) {
    int i = base + t * 4 + k;
    v[k] = (i < N) ? deg[i] : 0;
    s += v[k];
  }
  lds[t] = s;
  __syncthreads();
  for (int off = 1; off < 256; off <<= 1) {
    int add = (t >= off) ? lds[t - off] : 0;
    __syncthreads();
    lds[t] += add;
    __syncthreads();
  }
  int run = lds[t] - s;
#pragma unroll
  for (int k = 0; k < 4; ++k) {
    int i = base + t * 4 + k;
    if (i < N) excl[i] = run;
    run += v[k];
  }
  if (t == 255) bsum[blockIdx.x] = lds[255];
}

__global__ __launch_bounds__(256) void scan2(int* __restrict__ bsum, int nb) {
  __shared__ int lds[256];
  int t = threadIdx.x;
  int v = (t < nb) ? bsum[t] : 0;
  lds[t] = v;
  __syncthreads();
  for (int off = 1; off < 256; off <<= 1) {
    int add = (t >= off) ? lds[t - off] : 0;
    __syncthreads();
    lds[t] += add;
    __syncthreads();
  }
  if (t < nb) bsum[t] = lds[t] - v;
}

__global__ __launch_bounds__(256) void scan3(const int* __restrict__ excl,
                                             const int* __restrict__ bsum,
                                             int* __restrict__ rowptr, int N, int E) {
  int i = blockIdx.x * 256 + threadIdx.x;
  if (i < N) rowptr[i] = excl[i] + bsum[i >> 10];
  if (i == N) rowptr[N] = E;
}

__global__ __launch_bounds__(256) void init_gcur(const int* __restrict__ rowptr,
                                                 int* __restrict__ gcur, int B, int N) {
  int b = blockIdx.x * 256 + threadIdx.x;
  if (b < B) {
    int node = b << 7;
    gcur[b] = rowptr[node < N ? node : N];
  }
}

// ---------------- pass 1: bucketize edges by dst>>7 ----------------
__global__ __launch_bounds__(512) void bucketize(const int* __restrict__ ei,
                                                 int* __restrict__ gcur,
                                                 u32* __restrict__ staging,
                                                 int E, int B) {
  __shared__ u32 vals[8192];
  __shared__ u16 bkt[8192];
  __shared__ int hist[1024], ofs[1024], curx[1024], gbase[1024];
  __shared__ int wsum[512];

  const int t = threadIdx.x;
  const int base = blockIdx.x * 8192;
  const int cnt = min(8192, E - base);

  for (int b = t; b < 1024; b += 512) hist[b] = 0;
  __syncthreads();

  for (int k = t; k < cnt; k += 512) {
    int d = ei[E + base + k];
    atomicAdd(&hist[d >> 7], 1);
  }
  __syncthreads();

  int a0 = hist[2 * t], a1 = hist[2 * t + 1];
  int s = a0 + a1;
  wsum[t] = s;
  __syncthreads();
  for (int off = 1; off < 512; off <<= 1) {
    int add = (t >= off) ? wsum[t - off] : 0;
    __syncthreads();
    wsum[t] += add;
    __syncthreads();
  }
  int excl = wsum[t] - s;
  ofs[2 * t] = excl;
  ofs[2 * t + 1] = excl + a0;
  __syncthreads();

  for (int b = t; b < B; b += 512) {
    int c = hist[b];
    gbase[b] = c ? atomicAdd(&gcur[b], c) : 0;
    curx[b] = ofs[b];
  }
  __syncthreads();

  for (int k = t; k < cnt; k += 512) {
    int sv = ei[base + k];
    int d = ei[E + base + k];
    int b = d >> 7;
    u32 val = (u32)sv | ((u32)(d & 127) << 17);
    int lpos = atomicAdd(&curx[b], 1);
    vals[lpos] = val;
    bkt[lpos] = (u16)b;
  }
  __syncthreads();

  for (int i = t; i < cnt; i += 512) {
    int b = bkt[i];
    staging[gbase[b] + (i - ofs[b])] = vals[i];
  }
}

// ---------------- pass 2: place within bucket ----------------
__global__ __launch_bounds__(256) void place(const u32* __restrict__ staging,
                                             const int* __restrict__ rowptr,
                                             int* __restrict__ csr, int N) {
  __shared__ int lrp[129];
  __shared__ int cur[128];
  const int t = threadIdx.x;
  const int node0 = blockIdx.x << 7;
  const int nn = min(128, N - node0);
  if (t <= nn) lrp[t] = rowptr[node0 + t];
  if (t < nn) cur[t] = 0;
  __syncthreads();
  const int rstart = lrp[0], rend = lrp[nn];
  for (int i = rstart + t; i < rend; i += 256) {
    u32 v = staging[i];
    int nl = v >> 17;
    int src = v & 0x1FFFF;
    int tk = atomicAdd(&cur[nl], 1);
    csr[lrp[nl] + tk] = src;
  }
}

// ---------------- conversions ----------------
__global__ __launch_bounds__(256) void cvt_x(const float* __restrict__ x,
                                             u16* __restrict__ xb, int total4) {
  int i = blockIdx.x * 256 + threadIdx.x;
  if (i >= total4) return;
  float4 v = *(const float4*)(x + (size_t)i * 4);
  u32 lo = (u32)f2b(v.x) | ((u32)f2b(v.y) << 16);
  u32 hi = (u32)f2b(v.z) | ((u32)f2b(v.w) << 16);
  uint2 o; o.x = lo; o.y = hi;
  *(uint2*)(xb + (size_t)i * 4) = o;
}

__global__ __launch_bounds__(256) void cvt_w(const float* __restrict__ W1l,
                                             const float* __restrict__ W1r,
                                             const float* __restrict__ W2l,
                                             const float* __restrict__ W2r,
                                             u16* __restrict__ wt1,
                                             u16* __restrict__ wt2) {
  int i = blockIdx.x * 256 + threadIdx.x;
  if (i < 16384) {                 // Wt1: 128 x 128
    int j = i >> 7, k = i & 127;
    float v = (k < 64) ? W1l[k * 128 + j] : W1r[(k - 64) * 128 + j];
    wt1[j * 128 + k] = f2b(v);
  } else if (i < 16384 + 32768) {  // Wt2: 128 x 256
    int i2 = i - 16384;
    int j = i2 >> 8, k = i2 & 255;
    float v = (k < 128) ? W2l[k * 128 + j] : W2r[(k - 128) * 128 + j];
    wt2[j * 256 + k] = f2b(v);
  }
}

// ---------------- gather means (bf16, high-MLP) ----------------
#define ACC8(v)                                                        \
  a0 += b2f((u16)(v).x); a1 += b2f((u16)((v).x >> 16));                \
  a2 += b2f((u16)(v).y); a3 += b2f((u16)((v).y >> 16));                \
  a4 += b2f((u16)(v).z); a5 += b2f((u16)((v).z >> 16));                \
  a6 += b2f((u16)(v).w); a7 += b2f((u16)((v).w >> 16));

// 64-dim: wave per node; 8 lanes x uint4 per row -> 8 rows per wave-load.
__global__ __launch_bounds__(256) void gather_mean_64b(const u16* __restrict__ xb,
                                                       const int* __restrict__ rowptr,
                                                       const int* __restrict__ csr,
                                                       u16* __restrict__ mean, int N) {
  int n = (blockIdx.x * 256 + threadIdx.x) >> 6;
  int lane = threadIdx.x & 63;
  int sub = lane >> 3;      // edge slot 0..7
  int ln = lane & 7;        // 8-dim chunk
  if (n >= N) return;
  int s0 = rowptr[n], s1 = rowptr[n + 1];
  float a0 = 0.f, a1 = 0.f, a2 = 0.f, a3 = 0.f, a4 = 0.f, a5 = 0.f, a6 = 0.f, a7 = 0.f;
  int e = s0;
  for (; e + 16 <= s1; e += 16) {
    int i0 = csr[e + sub], i1 = csr[e + 8 + sub];
    uint4 v0 = *(const uint4*)(xb + (size_t)i0 * 64 + ln * 8);
    uint4 v1 = *(const uint4*)(xb + (size_t)i1 * 64 + ln * 8);
    ACC8(v0); ACC8(v1);
  }
  for (; e + 8 <= s1; e += 8) {
    int i0 = csr[e + sub];
    uint4 v0 = *(const uint4*)(xb + (size_t)i0 * 64 + ln * 8);
    ACC8(v0);
  }
  int rem = s1 - e;
  if (sub < rem) {
    int i0 = csr[e + sub];
    uint4 v0 = *(const uint4*)(xb + (size_t)i0 * 64 + ln * 8);
    ACC8(v0);
  }
#pragma unroll
  for (int off = 8; off < 64; off <<= 1) {
    a0 += __shfl_xor(a0, off); a1 += __shfl_xor(a1, off);
    a2 += __shfl_xor(a2, off); a3 += __shfl_xor(a3, off);
    a4 += __shfl_xor(a4, off); a5 += __shfl_xor(a5, off);
    a6 += __shfl_xor(a6, off); a7 += __shfl_xor(a7, off);
  }
  if (sub == 0) {
    int c = s1 - s0;
    float inv = c > 0 ? 1.f / (float)c : 0.f;
    uint4 o;
    o.x = (u32)f2b(a0 * inv) | ((u32)f2b(a1 * inv) << 16);
    o.y = (u32)f2b(a2 * inv) | ((u32)f2b(a3 * inv) << 16);
    o.z = (u32)f2b(a4 * inv) | ((u32)f2b(a5 * inv) << 16);
    o.w = (u32)f2b(a6 * inv) | ((u32)f2b(a7 * inv) << 16);
    *(uint4*)(mean + (size_t)n * 64 + ln * 8) = o;
  }
}

// 128-dim: wave per node; 16 lanes x uint4 per row -> 4 rows per wave-load.
__global__ __launch_bounds__(256) void gather_mean_128b(const u16* __restrict__ hb,
                                                        const int* __restrict__ rowptr,
                                                        const int* __restrict__ csr,
                                                        u16* __restrict__ mean, int N) {
  int n = (blockIdx.x * 256 + threadIdx.x) >> 6;
  int lane = threadIdx.x & 63;
  int sub = lane >> 4;      // edge slot 0..3
  int ln = lane & 15;       // 8-dim chunk
  if (n >= N) return;
  int s0 = rowptr[n], s1 = rowptr[n + 1];
  float a0 = 0.f, a1 = 0.f, a2 = 0.f, a3 = 0.f, a4 = 0.f, a5 = 0.f, a6 = 0.f, a7 = 0.f;
  int e = s0;
  for (; e + 8 <= s1; e += 8) {
    int i0 = csr[e + sub], i1 = csr[e + 4 + sub];
    uint4 v0 = *(const uint4*)(hb + (size_t)i0 * 128 + ln * 8);
    uint4 v1 = *(const uint4*)(hb + (size_t)i1 * 128 + ln * 8);
    ACC8(v0); ACC8(v1);
  }
  for (; e + 4 <= s1; e += 4) {
    int i0 = csr[e + sub];
    uint4 v0 = *(const uint4*)(hb + (size_t)i0 * 128 + ln * 8);
    ACC8(v0);
  }
  int rem = s1 - e;
  if (sub < rem) {
    int i0 = csr[e + sub];
    uint4 v0 = *(const uint4*)(hb + (size_t)i0 * 128 + ln * 8);
    ACC8(v0);
  }
#pragma unroll
  for (int off = 16; off < 64; off <<= 1) {
    a0 += __shfl_xor(a0, off); a1 += __shfl_xor(a1, off);
    a2 += __shfl_xor(a2, off); a3 += __shfl_xor(a3, off);
    a4 += __shfl_xor(a4, off); a5 += __shfl_xor(a5, off);
    a6 += __shfl_xor(a6, off); a7 += __shfl_xor(a7, off);
  }
  if (sub == 0) {
    int c = s1 - s0;
    float inv = c > 0 ? 1.f / (float)c : 0.f;
    uint4 o;
    o.x = (u32)f2b(a0 * inv) | ((u32)f2b(a1 * inv) << 16);
    o.y = (u32)f2b(a2 * inv) | ((u32)f2b(a3 * inv) << 16);
    o.z = (u32)f2b(a4 * inv) | ((u32)f2b(a5 * inv) << 16);
    o.w = (u32)f2b(a6 * inv) | ((u32)f2b(a7 * inv) << 16);
    *(uint4*)(mean + (size_t)n * 128 + ln * 8) = o;
  }
}

// ---------------- MFMA GEMM (FINAL fuses p,q projection; h2 never stored) ------
template<int K2, bool FINAL>
__global__ __launch_bounds__(512) void mfma_gemm(
    const u16* __restrict__ meanb, const u16* __restrict__ prevb,
    const u16* __restrict__ wt,    // [128][K2] bf16 (pre-transposed)
    const float* __restrict__ bias,
    u16* __restrict__ hout,
    const float* __restrict__ W3l, const float* __restrict__ W3r,
    float* __restrict__ outp, float* __restrict__ outq, int N) {
  constexpr int KH = K2 / 2;
  constexpr int NC = K2 / 8;
  __shared__ __align__(16) u16 Albs[128 * K2];
  __shared__ __align__(16) u16 Wlds[128 * K2];

  const int t = threadIdx.x;
  const int tile = blockIdx.x * 128;

  for (int i = t; i < 128 * NC; i += 512) {
    int j = i / NC, c = i - j * NC;
    uint4 v = *(const uint4*)(wt + (size_t)j * K2 + c * 8);
    *(uint4*)(Wlds + j * K2 + ((c ^ (j & 7)) << 3)) = v;
  }
  for (int i = t; i < 128 * NC; i += 512) {
    int r = i / NC, c = i - r * NC;
    int node = tile + r;
    uint4 v; v.x = 0; v.y = 0; v.z = 0; v.w = 0;
    if (node < N) {
      int k0 = c * 8;
      v = (k0 < KH) ? *(const uint4*)(meanb + (size_t)node * KH + k0)
                    : *(const uint4*)(prevb + (size_t)node * KH + (k0 - KH));
    }
    *(uint4*)(Albs + r * K2 + ((c ^ (r & 7)) << 3)) = v;
  }
  __syncthreads();

  const int lane = t & 63;
  const int wid = t >> 6;
  const int wm = wid >> 1, wn = wid & 1;
  const int er = lane & 15;
  const int kg = lane >> 4;

  f32x4 acc[2][4];
#pragma unroll
  for (int mi = 0; mi < 2; ++mi)
#pragma unroll
    for (int ni = 0; ni < 4; ++ni) acc[mi][ni] = (f32x4)(0.f);

#pragma unroll
  for (int ks = 0; ks < K2 / 32; ++ks) {
    int cidx = ks * 4 + kg;
    s16x8 a[2], b[4];
#pragma unroll
    for (int mi = 0; mi < 2; ++mi) {
      int row = wm * 32 + mi * 16 + er;
      a[mi] = *(const s16x8*)(Albs + row * K2 + ((cidx ^ (row & 7)) << 3));
    }
#pragma unroll
    for (int ni = 0; ni < 4; ++ni) {
      int col = wn * 64 + ni * 16 + er;
      b[ni] = *(const s16x8*)(Wlds + col * K2 + ((cidx ^ (col & 7)) << 3));
    }
#pragma unroll
    for (int mi = 0; mi < 2; ++mi)
#pragma unroll
      for (int ni = 0; ni < 4; ++ni)
        acc[mi][ni] = __builtin_amdgcn_mfma_f32_16x16x32_bf16(a[mi], b[ni], acc[mi][ni], 0, 0, 0);
  }

  if constexpr (!FINAL) {
#pragma unroll
    for (int mi = 0; mi < 2; ++mi) {
#pragma unroll
      for (int ni = 0; ni < 4; ++ni) {
        int col = wn * 64 + ni * 16 + er;
        float bv = bias[col];
#pragma unroll
        for (int r = 0; r < 4; ++r) {
          int node = tile + wm * 32 + mi * 16 + kg * 4 + r;
          if (node < N) {
            float v = acc[mi][ni][r] + bv;
            v = v > 0.f ? v : 0.f;
            hout[(size_t)node * 128 + col] = f2b(v);
          }
        }
      }
    }
  } else {
    __shared__ float p_lds[128][2], q_lds[128][2];
    float wl[4], wr[4], bv[4];
#pragma unroll
    for (int ni = 0; ni < 4; ++ni) {
      int col = wn * 64 + ni * 16 + er;
      wl[ni] = W3l[col]; wr[ni] = W3r[col]; bv[ni] = bias[col];
    }
#pragma unroll
    for (int mi = 0; mi < 2; ++mi) {
#pragma unroll
      for (int r = 0; r < 4; ++r) {
        float pv = 0.f, qv = 0.f;
#pragma unroll
        for (int ni = 0; ni < 4; ++ni) {
          float v = acc[mi][ni][r] + bv[ni];
          v = v > 0.f ? v : 0.f;
          pv = fmaf(v, wl[ni], pv);
          qv = fmaf(v, wr[ni], qv);
        }
#pragma unroll
        for (int off = 1; off < 16; off <<= 1) {
          pv += __shfl_xor(pv, off);
          qv += __shfl_xor(qv, off);
        }
        if (er == 0) {
          int nl = wm * 32 + mi * 16 + kg * 4 + r;
          p_lds[nl][wn] = pv;
          q_lds[nl][wn] = qv;
        }
      }
    }
    __syncthreads();
    if (t < 128) {
      int node = tile + t;
      if (node < N) {
        outp[node] = p_lds[t][0] + p_lds[t][1];
        outq[node] = q_lds[t][0] + q_lds[t][1];
      }
    }
  }
}

// ---------------- layer 3 fused: h3 = mean_e(p) + q + b3 ; out_scalar ----------------
__global__ __launch_bounds__(256) void gather3_fused(const float* __restrict__ p,
                                                     const int* __restrict__ rowptr,
                                                     const int* __restrict__ csr,
                                                     const float* __restrict__ q,
                                                     const float* __restrict__ b3,
                                                     float* __restrict__ h3,
                                                     float* __restrict__ out_scalar, int N) {
  int n = blockIdx.x * 256 + threadIdx.x;
  if (n >= N) return;
  int s0 = rowptr[n], s1 = rowptr[n + 1];
  float a = 0.f;
  for (int e = s0; e < s1; ++e) a += p[csr[e]];
  int c = s1 - s0;
  float inv = c > 0 ? 1.f / (float)c : 0.f;
  float v = a * inv + q[n] + b3[0];
  h3[n] = v;
  out_scalar[n] = v;
}

// ---------------- layer 4 fused: mean_e(h3) -> logits -> log_softmax ----------------
__global__ __launch_bounds__(256) void gather4_fused(const float* __restrict__ h3,
                                                     const int* __restrict__ rowptr,
                                                     const int* __restrict__ csr,
                                                     const float* __restrict__ W4l,
                                                     const float* __restrict__ W4r,
                                                     const float* __restrict__ b4,
                                                     float* __restrict__ out, int N) {
  int n = blockIdx.x * 256 + threadIdx.x;
  if (n >= N) return;
  int s0 = rowptr[n], s1 = rowptr[n + 1];
  float a = 0.f;
  for (int e = s0; e < s1; ++e) a += h3[csr[e]];
  int c = s1 - s0;
  float inv = c > 0 ? 1.f / (float)c : 0.f;
  float m = a * inv;
  float hv = h3[n];
  float logits[8];
  float mx = -1e30f;
#pragma unroll
  for (int jj = 0; jj < 8; ++jj) {
    float v = m * W4l[jj] + hv * W4r[jj] + b4[jj];
    logits[jj] = v;
    mx = v > mx ? v : mx;
  }
  float s = 0.f;
#pragma unroll
  for (int jj = 0; jj < 8; ++jj) s += expf(logits[jj] - mx);
  float lse = mx + logf(s);
  float4 o0, o1;
  o0.x = logits[0] - lse; o0.y = logits[1] - lse; o0.z = logits[2] - lse; o0.w = logits[3] - lse;
  o1.x = logits[4] - lse; o1.y = logits[5] - lse; o1.z = logits[6] - lse; o1.w = logits[7] - lse;
  float4* o4 = (float4*)(out + (size_t)n * 8);
  o4[0] = o0; o4[1] = o1;
}

extern "C" void kernel_launch(void* const* d_in, const int* in_sizes, int n_in,
                              void* d_out, int out_size, void* d_ws, size_t ws_size,
                              hipStream_t stream) {
  const float* x   = (const float*)d_in[0];
  const int*   ei  = (const int*)d_in[1];
  const float* W1l = (const float*)d_in[2];
  const float* W1r = (const float*)d_in[3];
  const float* b1  = (const float*)d_in[4];
  const float* W2l = (const float*)d_in[5];
  const float* W2r = (const float*)d_in[6];
  const float* b2  = (const float*)d_in[7];
  const float* W3l = (const float*)d_in[8];
  const float* W3r = (const float*)d_in[9];
  const float* b3  = (const float*)d_in[10];
  const float* W4l = (const float*)d_in[11];
  const float* W4r = (const float*)d_in[12];
  const float* b4  = (const float*)d_in[13];

  const int N = in_sizes[0] / 64;   // 100000
  const int E = in_sizes[1] / 2;    // 1600000
  const size_t Ns = (size_t)N;
  const int B = (N + 127) >> 7;     // 782 buckets

  // ---- workspace layout ----
  u16* ub      = (u16*)d_ws;
  u16* xb      = ub;                 // 64N
  u16* mean0b  = ub + 64 * Ns;       // 64N
  u16* h1b     = ub + 128 * Ns;      // 128N
  u16* mean1b  = ub + 256 * Ns;      // 128N
  u16* wt1     = ub + 384 * Ns;      // 16384
  u16* wt2     = wt1 + 16384;        // 32768
  float* fb    = (float*)(wt2 + 32768);
  float* p     = fb;                 // N
  float* q     = fb + Ns;            // N
  float* h3    = fb + 2 * Ns;        // N
  int* ib      = (int*)(fb + 3 * Ns);
  int* rowptr  = ib;                          // N+1
  int* deg     = ib + (N + 1);                // N
  int* excl    = ib + (N + 1) + N;            // N
  int* bsum    = ib + (N + 1) + 2 * N;        // 256
  int* gcur    = ib + (N + 1) + 2 * N + 256;  // 1024
  int* csr     = gcur + 1024;                 // E
  u32* staging = (u32*)(csr + E);             // E

  float* out_rock   = (float*)d_out;            // N x 8
  float* out_scalar = (float*)d_out + 8 * Ns;   // N

  const int EB = (E + 255) / 256;
  const int NB1 = (N + 1023) / 1024;
  const int NBn = (N + 256) / 256;
  const int GG = (N + 127) / 128;

  // ---- CSR build ----
  hipMemsetAsync(deg, 0, Ns * sizeof(int), stream);
  hist_kernel<<<EB, 256, 0, stream>>>(ei, deg, E);
  scan1<<<NB1, 256, 0, stream>>>(deg, excl, bsum, N);
  scan2<<<1, 256, 0, stream>>>(bsum, NB1);
  scan3<<<NBn, 256, 0, stream>>>(excl, bsum, rowptr, N, E);
  init_gcur<<<(B + 255) / 256, 256, 0, stream>>>(rowptr, gcur, B, N);
  bucketize<<<(E + 8191) / 8192, 512, 0, stream>>>(ei, gcur, staging, E, B);
  place<<<B, 256, 0, stream>>>(staging, rowptr, csr, N);

  // ---- conversions ----
  cvt_x<<<(N * 16 + 255) / 256, 256, 0, stream>>>(x, xb, N * 16);
  cvt_w<<<192, 256, 0, stream>>>(W1l, W1r, W2l, W2r, wt1, wt2);

  // ---- layer 1 ----
  gather_mean_64b<<<(N + 3) / 4, 256, 0, stream>>>(xb, rowptr, csr, mean0b, N);
  mfma_gemm<128, false><<<GG, 512, 0, stream>>>(
      mean0b, xb, wt1, b1, h1b, nullptr, nullptr, nullptr, nullptr, N);

  // ---- layer 2 (+ fused p,q) ----
  gather_mean_128b<<<(N + 3) / 4, 256, 0, stream>>>(h1b, rowptr, csr, mean1b, N);
  mfma_gemm<256, true><<<GG, 512, 0, stream>>>(
      mean1b, h1b, wt2, b2, nullptr, W3l, W3r, p, q, N);

  // ---- layer 3 (scalar) ----
  gather3_fused<<<(N + 255) / 256, 256, 0, stream>>>(p, rowptr, csr, q, b3, h3, out_scalar, N);

  // ---- layer 4 (scalar in, 8 out) ----
  gather4_fused<<<(N + 255) / 256, 256, 0, stream>>>(h3, rowptr, csr, W4l, W4r, b4, out_rock, N);
}

// Round 8
// 260.814 us; speedup vs baseline: 19.8267x; 1.1661x over previous
//
#include <hip/hip_runtime.h>
#include <hip/hip_bf16.h>
#include <math.h>

// GraphSAGE: 4 layers on N=100000 nodes, E=1600000 edges.
// Round 8: CSR build without N-wide atomics — bucket histograms (private rows,
// no atomics) + rowptr derived inside place(). Rest unchanged from round 7.

typedef unsigned short u16;
typedef unsigned int u32;
typedef __attribute__((ext_vector_type(4))) float f32x4;
typedef __attribute__((ext_vector_type(8))) short s16x8;

__device__ __forceinline__ float b2f(u16 u) {
  union { float f; u32 i; } v; v.i = ((u32)u) << 16; return v.f;
}
__device__ __forceinline__ u16 f2b(float f) {
  union { float f; u32 u; } v; v.f = f;
  u32 r = v.u + 0x7fffu + ((v.u >> 16) & 1u);   // RTN-even
  return (u16)(r >> 16);
}

// ---------------- CSR build ----------------
// pass 0: per-block bucket histograms (dst>>7), private global rows, no atomics
__global__ __launch_bounds__(512) void bucket_hist(const int* __restrict__ ei,
                                                   int* __restrict__ gbh, int E) {
  __shared__ int hist[1024];
  const int t = threadIdx.x;
  const int base = blockIdx.x * 8192;
  const int cnt = min(8192, E - base);
  for (int b = t; b < 1024; b += 512) hist[b] = 0;
  __syncthreads();
  for (int k = t; k < cnt; k += 512)
    atomicAdd(&hist[ei[E + base + k] >> 7], 1);
  __syncthreads();
  for (int b = t; b < 1024; b += 512)
    gbh[blockIdx.x * 1024 + b] = hist[b];
}

// pass 0b: sum rows + exclusive scan over 1024 buckets -> bucket_base, gcur
__global__ __launch_bounds__(512) void scan_buckets(const int* __restrict__ gbh,
                                                    int nblk,
                                                    int* __restrict__ bucket_base,
                                                    int* __restrict__ gcur,
                                                    int* __restrict__ rowptr,
                                                    int N, int E) {
  __shared__ int wsum[512];
  const int t = threadIdx.x;
  int c0 = 0, c1 = 0;
  for (int blk = 0; blk < nblk; ++blk) {
    c0 += gbh[blk * 1024 + 2 * t];
    c1 += gbh[blk * 1024 + 2 * t + 1];
  }
  int s = c0 + c1;
  wsum[t] = s;
  __syncthreads();
  for (int off = 1; off < 512; off <<= 1) {
    int add = (t >= off) ? wsum[t - off] : 0;
    __syncthreads();
    wsum[t] += add;
    __syncthreads();
  }
  int excl = wsum[t] - s;
  bucket_base[2 * t] = excl;
  bucket_base[2 * t + 1] = excl + c0;
  gcur[2 * t] = excl;
  gcur[2 * t + 1] = excl + c0;
  if (t == 511) bucket_base[1024] = wsum[511];
  if (t == 0) rowptr[N] = E;
}

// pass 1: bucketize edges by dst>>7, LDS-staged coalesced write
__global__ __launch_bounds__(512) void bucketize(const int* __restrict__ ei,
                                                 int* __restrict__ gcur,
                                                 u32* __restrict__ staging,
                                                 int E, int B) {
  __shared__ u32 vals[8192];
  __shared__ u16 bkt[8192];
  __shared__ int hist[1024], ofs[1024], curx[1024], gbase[1024];
  __shared__ int wsum[512];

  const int t = threadIdx.x;
  const int base = blockIdx.x * 8192;
  const int cnt = min(8192, E - base);

  for (int b = t; b < 1024; b += 512) hist[b] = 0;
  __syncthreads();

  for (int k = t; k < cnt; k += 512) {
    int d = ei[E + base + k];
    atomicAdd(&hist[d >> 7], 1);
  }
  __syncthreads();

  int a0 = hist[2 * t], a1 = hist[2 * t + 1];
  int s = a0 + a1;
  wsum[t] = s;
  __syncthreads();
  for (int off = 1; off < 512; off <<= 1) {
    int add = (t >= off) ? wsum[t - off] : 0;
    __syncthreads();
    wsum[t] += add;
    __syncthreads();
  }
  int excl = wsum[t] - s;
  ofs[2 * t] = excl;
  ofs[2 * t + 1] = excl + a0;
  __syncthreads();

  for (int b = t; b < B; b += 512) {
    int c = hist[b];
    gbase[b] = c ? atomicAdd(&gcur[b], c) : 0;
    curx[b] = ofs[b];
  }
  __syncthreads();

  for (int k = t; k < cnt; k += 512) {
    int sv = ei[base + k];
    int d = ei[E + base + k];
    int b = d >> 7;
    u32 val = (u32)sv | ((u32)(d & 127) << 17);
    int lpos = atomicAdd(&curx[b], 1);
    vals[lpos] = val;
    bkt[lpos] = (u16)b;
  }
  __syncthreads();

  for (int i = t; i < cnt; i += 512) {
    int b = bkt[i];
    staging[gbase[b] + (i - ofs[b])] = vals[i];
  }
}

// pass 2: per bucket — derive rowptr (LDS count+scan) and place edges
__global__ __launch_bounds__(256) void place(const u32* __restrict__ staging,
                                             const int* __restrict__ bucket_base,
                                             int* __restrict__ rowptr,
                                             int* __restrict__ csr, int N) {
  __shared__ int cnt[128], excl[128], cur[128], sc[128];
  const int t = threadIdx.x;
  const int node0 = blockIdx.x << 7;
  const int nn = min(128, N - node0);
  if (t < 128) { cnt[t] = 0; cur[t] = 0; }
  __syncthreads();
  const int rstart = bucket_base[blockIdx.x];
  const int rend = bucket_base[blockIdx.x + 1];
  for (int i = rstart + t; i < rend; i += 256)
    atomicAdd(&cnt[staging[i] >> 17], 1);
  __syncthreads();
  if (t < 128) sc[t] = cnt[t];
  __syncthreads();
  for (int off = 1; off < 128; off <<= 1) {
    int add = (t < 128 && t >= off) ? sc[t - off] : 0;
    __syncthreads();
    if (t < 128) sc[t] += add;
    __syncthreads();
  }
  if (t < 128) excl[t] = sc[t] - cnt[t];
  if (t < nn) rowptr[node0 + t] = rstart + excl[t];
  __syncthreads();
  for (int i = rstart + t; i < rend; i += 256) {
    u32 v = staging[i];
    int nl = v >> 17;
    int src = v & 0x1FFFF;
    int tk = atomicAdd(&cur[nl], 1);
    csr[rstart + excl[nl] + tk] = src;
  }
}

// ---------------- conversions ----------------
__global__ __launch_bounds__(256) void cvt_x(const float* __restrict__ x,
                                             u16* __restrict__ xb, int total4) {
  int i = blockIdx.x * 256 + threadIdx.x;
  if (i >= total4) return;
  float4 v = *(const float4*)(x + (size_t)i * 4);
  u32 lo = (u32)f2b(v.x) | ((u32)f2b(v.y) << 16);
  u32 hi = (u32)f2b(v.z) | ((u32)f2b(v.w) << 16);
  uint2 o; o.x = lo; o.y = hi;
  *(uint2*)(xb + (size_t)i * 4) = o;
}

__global__ __launch_bounds__(256) void cvt_w(const float* __restrict__ W1l,
                                             const float* __restrict__ W1r,
                                             const float* __restrict__ W2l,
                                             const float* __restrict__ W2r,
                                             u16* __restrict__ wt1,
                                             u16* __restrict__ wt2) {
  int i = blockIdx.x * 256 + threadIdx.x;
  if (i < 16384) {                 // Wt1: 128 x 128
    int j = i >> 7, k = i & 127;
    float v = (k < 64) ? W1l[k * 128 + j] : W1r[(k - 64) * 128 + j];
    wt1[j * 128 + k] = f2b(v);
  } else if (i < 16384 + 32768) {  // Wt2: 128 x 256
    int i2 = i - 16384;
    int j = i2 >> 8, k = i2 & 255;
    float v = (k < 128) ? W2l[k * 128 + j] : W2r[(k - 128) * 128 + j];
    wt2[j * 256 + k] = f2b(v);
  }
}

// ---------------- gather means (bf16, high-MLP) ----------------
#define ACC8(v)                                                        \
  a0 += b2f((u16)(v).x); a1 += b2f((u16)((v).x >> 16));                \
  a2 += b2f((u16)(v).y); a3 += b2f((u16)((v).y >> 16));                \
  a4 += b2f((u16)(v).z); a5 += b2f((u16)((v).z >> 16));                \
  a6 += b2f((u16)(v).w); a7 += b2f((u16)((v).w >> 16));

__global__ __launch_bounds__(256) void gather_mean_64b(const u16* __restrict__ xb,
                                                       const int* __restrict__ rowptr,
                                                       const int* __restrict__ csr,
                                                       u16* __restrict__ mean, int N) {
  int n = (blockIdx.x * 256 + threadIdx.x) >> 6;
  int lane = threadIdx.x & 63;
  int sub = lane >> 3;
  int ln = lane & 7;
  if (n >= N) return;
  int s0 = rowptr[n], s1 = rowptr[n + 1];
  float a0 = 0.f, a1 = 0.f, a2 = 0.f, a3 = 0.f, a4 = 0.f, a5 = 0.f, a6 = 0.f, a7 = 0.f;
  int e = s0;
  for (; e + 16 <= s1; e += 16) {
    int i0 = csr[e + sub], i1 = csr[e + 8 + sub];
    uint4 v0 = *(const uint4*)(xb + (size_t)i0 * 64 + ln * 8);
    uint4 v1 = *(const uint4*)(xb + (size_t)i1 * 64 + ln * 8);
    ACC8(v0); ACC8(v1);
  }
  for (; e + 8 <= s1; e += 8) {
    int i0 = csr[e + sub];
    uint4 v0 = *(const uint4*)(xb + (size_t)i0 * 64 + ln * 8);
    ACC8(v0);
  }
  int rem = s1 - e;
  if (sub < rem) {
    int i0 = csr[e + sub];
    uint4 v0 = *(const uint4*)(xb + (size_t)i0 * 64 + ln * 8);
    ACC8(v0);
  }
#pragma unroll
  for (int off = 8; off < 64; off <<= 1) {
    a0 += __shfl_xor(a0, off); a1 += __shfl_xor(a1, off);
    a2 += __shfl_xor(a2, off); a3 += __shfl_xor(a3, off);
    a4 += __shfl_xor(a4, off); a5 += __shfl_xor(a5, off);
    a6 += __shfl_xor(a6, off); a7 += __shfl_xor(a7, off);
  }
  if (sub == 0) {
    int c = s1 - s0;
    float inv = c > 0 ? 1.f / (float)c : 0.f;
    uint4 o;
    o.x = (u32)f2b(a0 * inv) | ((u32)f2b(a1 * inv) << 16);
    o.y = (u32)f2b(a2 * inv) | ((u32)f2b(a3 * inv) << 16);
    o.z = (u32)f2b(a4 * inv) | ((u32)f2b(a5 * inv) << 16);
    o.w = (u32)f2b(a6 * inv) | ((u32)f2b(a7 * inv) << 16);
    *(uint4*)(mean + (size_t)n * 64 + ln * 8) = o;
  }
}

__global__ __launch_bounds__(256) void gather_mean_128b(const u16* __restrict__ hb,
                                                        const int* __restrict__ rowptr,
                                                        const int* __restrict__ csr,
                                                        u16* __restrict__ mean, int N) {
  int n = (blockIdx.x * 256 + threadIdx.x) >> 6;
  int lane = threadIdx.x & 63;
  int sub = lane >> 4;
  int ln = lane & 15;
  if (n >= N) return;
  int s0 = rowptr[n], s1 = rowptr[n + 1];
  float a0 = 0.f, a1 = 0.f, a2 = 0.f, a3 = 0.f, a4 = 0.f, a5 = 0.f, a6 = 0.f, a7 = 0.f;
  int e = s0;
  for (; e + 8 <= s1; e += 8) {
    int i0 = csr[e + sub], i1 = csr[e + 4 + sub];
    uint4 v0 = *(const uint4*)(hb + (size_t)i0 * 128 + ln * 8);
    uint4 v1 = *(const uint4*)(hb + (size_t)i1 * 128 + ln * 8);
    ACC8(v0); ACC8(v1);
  }
  for (; e + 4 <= s1; e += 4) {
    int i0 = csr[e + sub];
    uint4 v0 = *(const uint4*)(hb + (size_t)i0 * 128 + ln * 8);
    ACC8(v0);
  }
  int rem = s1 - e;
  if (sub < rem) {
    int i0 = csr[e + sub];
    uint4 v0 = *(const uint4*)(hb + (size_t)i0 * 128 + ln * 8);
    ACC8(v0);
  }
#pragma unroll
  for (int off = 16; off < 64; off <<= 1) {
    a0 += __shfl_xor(a0, off); a1 += __shfl_xor(a1, off);
    a2 += __shfl_xor(a2, off); a3 += __shfl_xor(a3, off);
    a4 += __shfl_xor(a4, off); a5 += __shfl_xor(a5, off);
    a6 += __shfl_xor(a6, off); a7 += __shfl_xor(a7, off);
  }
  if (sub == 0) {
    int c = s1 - s0;
    float inv = c > 0 ? 1.f / (float)c : 0.f;
    uint4 o;
    o.x = (u32)f2b(a0 * inv) | ((u32)f2b(a1 * inv) << 16);
    o.y = (u32)f2b(a2 * inv) | ((u32)f2b(a3 * inv) << 16);
    o.z = (u32)f2b(a4 * inv) | ((u32)f2b(a5 * inv) << 16);
    o.w = (u32)f2b(a6 * inv) | ((u32)f2b(a7 * inv) << 16);
    *(uint4*)(mean + (size_t)n * 128 + ln * 8) = o;
  }
}

// ---------------- MFMA GEMM (FINAL fuses p,q projection; h2 never stored) ------
template<int K2, bool FINAL>
__global__ __launch_bounds__(512) void mfma_gemm(
    const u16* __restrict__ meanb, const u16* __restrict__ prevb,
    const u16* __restrict__ wt,    // [128][K2] bf16 (pre-transposed)
    const float* __restrict__ bias,
    u16* __restrict__ hout,
    const float* __restrict__ W3l, const float* __restrict__ W3r,
    float* __restrict__ outp, float* __restrict__ outq, int N) {
  constexpr int KH = K2 / 2;
  constexpr int NC = K2 / 8;
  __shared__ __align__(16) u16 Albs[128 * K2];
  __shared__ __align__(16) u16 Wlds[128 * K2];

  const int t = threadIdx.x;
  const int tile = blockIdx.x * 128;

  for (int i = t; i < 128 * NC; i += 512) {
    int j = i / NC, c = i - j * NC;
    uint4 v = *(const uint4*)(wt + (size_t)j * K2 + c * 8);
    *(uint4*)(Wlds + j * K2 + ((c ^ (j & 7)) << 3)) = v;
  }
  for (int i = t; i < 128 * NC; i += 512) {
    int r = i / NC, c = i - r * NC;
    int node = tile + r;
    uint4 v; v.x = 0; v.y = 0; v.z = 0; v.w = 0;
    if (node < N) {
      int k0 = c * 8;
      v = (k0 < KH) ? *(const uint4*)(meanb + (size_t)node * KH + k0)
                    : *(const uint4*)(prevb + (size_t)node * KH + (k0 - KH));
    }
    *(uint4*)(Albs + r * K2 + ((c ^ (r & 7)) << 3)) = v;
  }
  __syncthreads();

  const int lane = t & 63;
  const int wid = t >> 6;
  const int wm = wid >> 1, wn = wid & 1;
  const int er = lane & 15;
  const int kg = lane >> 4;

  f32x4 acc[2][4];
#pragma unroll
  for (int mi = 0; mi < 2; ++mi)
#pragma unroll
    for (int ni = 0; ni < 4; ++ni) acc[mi][ni] = (f32x4)(0.f);

#pragma unroll
  for (int ks = 0; ks < K2 / 32; ++ks) {
    int cidx = ks * 4 + kg;
    s16x8 a[2], b[4];
#pragma unroll
    for (int mi = 0; mi < 2; ++mi) {
      int row = wm * 32 + mi * 16 + er;
      a[mi] = *(const s16x8*)(Albs + row * K2 + ((cidx ^ (row & 7)) << 3));
    }
#pragma unroll
    for (int ni = 0; ni < 4; ++ni) {
      int col = wn * 64 + ni * 16 + er;
      b[ni] = *(const s16x8*)(Wlds + col * K2 + ((cidx ^ (col & 7)) << 3));
    }
#pragma unroll
    for (int mi = 0; mi < 2; ++mi)
#pragma unroll
      for (int ni = 0; ni < 4; ++ni)
        acc[mi][ni] = __builtin_amdgcn_mfma_f32_16x16x32_bf16(a[mi], b[ni], acc[mi][ni], 0, 0, 0);
  }

  if constexpr (!FINAL) {
#pragma unroll
    for (int mi = 0; mi < 2; ++mi) {
#pragma unroll
      for (int ni = 0; ni < 4; ++ni) {
        int col = wn * 64 + ni * 16 + er;
        float bv = bias[col];
#pragma unroll
        for (int r = 0; r < 4; ++r) {
          int node = tile + wm * 32 + mi * 16 + kg * 4 + r;
          if (node < N) {
            float v = acc[mi][ni][r] + bv;
            v = v > 0.f ? v : 0.f;
            hout[(size_t)node * 128 + col] = f2b(v);
          }
        }
      }
    }
  } else {
    __shared__ float p_lds[128][2], q_lds[128][2];
    float wl[4], wr[4], bv[4];
#pragma unroll
    for (int ni = 0; ni < 4; ++ni) {
      int col = wn * 64 + ni * 16 + er;
      wl[ni] = W3l[col]; wr[ni] = W3r[col]; bv[ni] = bias[col];
    }
#pragma unroll
    for (int mi = 0; mi < 2; ++mi) {
#pragma unroll
      for (int r = 0; r < 4; ++r) {
        float pv = 0.f, qv = 0.f;
#pragma unroll
        for (int ni = 0; ni < 4; ++ni) {
          float v = acc[mi][ni][r] + bv[ni];
          v = v > 0.f ? v : 0.f;
          pv = fmaf(v, wl[ni], pv);
          qv = fmaf(v, wr[ni], qv);
        }
#pragma unroll
        for (int off = 1; off < 16; off <<= 1) {
          pv += __shfl_xor(pv, off);
          qv += __shfl_xor(qv, off);
        }
        if (er == 0) {
          int nl = wm * 32 + mi * 16 + kg * 4 + r;
          p_lds[nl][wn] = pv;
          q_lds[nl][wn] = qv;
        }
      }
    }
    __syncthreads();
    if (t < 128) {
      int node = tile + t;
      if (node < N) {
        outp[node] = p_lds[t][0] + p_lds[t][1];
        outq[node] = q_lds[t][0] + q_lds[t][1];
      }
    }
  }
}

// ---------------- layer 3 fused: h3 = mean_e(p) + q + b3 ; out_scalar ----------------
__global__ __launch_bounds__(256) void gather3_fused(const float* __restrict__ p,
                                                     const int* __restrict__ rowptr,
                                                     const int* __restrict__ csr,
                                                     const float* __restrict__ q,
                                                     const float* __restrict__ b3,
                                                     float* __restrict__ h3,
                                                     float* __restrict__ out_scalar, int N) {
  int n = blockIdx.x * 256 + threadIdx.x;
  if (n >= N) return;
  int s0 = rowptr[n], s1 = rowptr[n + 1];
  float a = 0.f;
  for (int e = s0; e < s1; ++e) a += p[csr[e]];
  int c = s1 - s0;
  float inv = c > 0 ? 1.f / (float)c : 0.f;
  float v = a * inv + q[n] + b3[0];
  h3[n] = v;
  out_scalar[n] = v;
}

// ---------------- layer 4 fused: mean_e(h3) -> logits -> log_softmax ----------------
__global__ __launch_bounds__(256) void gather4_fused(const float* __restrict__ h3,
                                                     const int* __restrict__ rowptr,
                                                     const int* __restrict__ csr,
                                                     const float* __restrict__ W4l,
                                                     const float* __restrict__ W4r,
                                                     const float* __restrict__ b4,
                                                     float* __restrict__ out, int N) {
  int n = blockIdx.x * 256 + threadIdx.x;
  if (n >= N) return;
  int s0 = rowptr[n], s1 = rowptr[n + 1];
  float a = 0.f;
  for (int e = s0; e < s1; ++e) a += h3[csr[e]];
  int c = s1 - s0;
  float inv = c > 0 ? 1.f / (float)c : 0.f;
  float m = a * inv;
  float hv = h3[n];
  float logits[8];
  float mx = -1e30f;
#pragma unroll
  for (int jj = 0; jj < 8; ++jj) {
    float v = m * W4l[jj] + hv * W4r[jj] + b4[jj];
    logits[jj] = v;
    mx = v > mx ? v : mx;
  }
  float s = 0.f;
#pragma unroll
  for (int jj = 0; jj < 8; ++jj) s += expf(logits[jj] - mx);
  float lse = mx + logf(s);
  float4 o0, o1;
  o0.x = logits[0] - lse; o0.y = logits[1] - lse; o0.z = logits[2] - lse; o0.w = logits[3] - lse;
  o1.x = logits[4] - lse; o1.y = logits[5] - lse; o1.z = logits[6] - lse; o1.w = logits[7] - lse;
  float4* o4 = (float4*)(out + (size_t)n * 8);
  o4[0] = o0; o4[1] = o1;
}

extern "C" void kernel_launch(void* const* d_in, const int* in_sizes, int n_in,
                              void* d_out, int out_size, void* d_ws, size_t ws_size,
                              hipStream_t stream) {
  const float* x   = (const float*)d_in[0];
  const int*   ei  = (const int*)d_in[1];
  const float* W1l = (const float*)d_in[2];
  const float* W1r = (const float*)d_in[3];
  const float* b1  = (const float*)d_in[4];
  const float* W2l = (const float*)d_in[5];
  const float* W2r = (const float*)d_in[6];
  const float* b2  = (const float*)d_in[7];
  const float* W3l = (const float*)d_in[8];
  const float* W3r = (const float*)d_in[9];
  const float* b3  = (const float*)d_in[10];
  const float* W4l = (const float*)d_in[11];
  const float* W4r = (const float*)d_in[12];
  const float* b4  = (const float*)d_in[13];

  const int N = in_sizes[0] / 64;   // 100000
  const int E = in_sizes[1] / 2;    // 1600000
  const size_t Ns = (size_t)N;
  const int B = (N + 127) >> 7;     // 782 buckets
  const int NBLK = (E + 8191) / 8192;  // 196

  // ---- workspace layout ----
  u16* ub      = (u16*)d_ws;
  u16* xb      = ub;                 // 64N
  u16* mean0b  = ub + 64 * Ns;       // 64N
  u16* h1b     = ub + 128 * Ns;      // 128N
  u16* mean1b  = ub + 256 * Ns;      // 128N
  u16* wt1     = ub + 384 * Ns;      // 16384
  u16* wt2     = wt1 + 16384;        // 32768
  float* fb    = (float*)(wt2 + 32768);
  float* p     = fb;                 // N
  float* q     = fb + Ns;            // N
  float* h3    = fb + 2 * Ns;        // N
  int* ib      = (int*)(fb + 3 * Ns);
  int* rowptr      = ib;                      // N+1
  int* gcur        = ib + (N + 1);            // 1024
  int* bucket_base = gcur + 1024;             // 1025
  int* gbh         = bucket_base + 1025;      // NBLK*1024
  int* csr         = gbh + NBLK * 1024;       // E
  u32* staging     = (u32*)(csr + E);         // E

  float* out_rock   = (float*)d_out;            // N x 8
  float* out_scalar = (float*)d_out + 8 * Ns;   // N

  const int GG = (N + 127) / 128;

  // ---- CSR build (no N-wide atomics) ----
  bucket_hist<<<NBLK, 512, 0, stream>>>(ei, gbh, E);
  scan_buckets<<<1, 512, 0, stream>>>(gbh, NBLK, bucket_base, gcur, rowptr, N, E);
  bucketize<<<NBLK, 512, 0, stream>>>(ei, gcur, staging, E, B);
  place<<<B, 256, 0, stream>>>(staging, bucket_base, rowptr, csr, N);

  // ---- conversions ----
  cvt_x<<<(N * 16 + 255) / 256, 256, 0, stream>>>(x, xb, N * 16);
  cvt_w<<<192, 256, 0, stream>>>(W1l, W1r, W2l, W2r, wt1, wt2);

  // ---- layer 1 ----
  gather_mean_64b<<<(N + 3) / 4, 256, 0, stream>>>(xb, rowptr, csr, mean0b, N);
  mfma_gemm<128, false><<<GG, 512, 0, stream>>>(
      mean0b, xb, wt1, b1, h1b, nullptr, nullptr, nullptr, nullptr, N);

  // ---- layer 2 (+ fused p,q) ----
  gather_mean_128b<<<(N + 3) / 4, 256, 0, stream>>>(h1b, rowptr, csr, mean1b, N);
  mfma_gemm<256, true><<<GG, 512, 0, stream>>>(
      mean1b, h1b, wt2, b2, nullptr, W3l, W3r, p, q, N);

  // ---- layer 3 (scalar) ----
  gather3_fused<<<(N + 255) / 256, 256, 0, stream>>>(p, rowptr, csr, q, b3, h3, out_scalar, N);

  // ---- layer 4 (scalar in, 8 out) ----
  gather4_fused<<<(N + 255) / 256, 256, 0, stream>>>(h3, rowptr, csr, W4l, W4r, b4, out_rock, N);
}

// Round 9
// 240.029 us; speedup vs baseline: 21.5435x; 1.0866x over previous
//
#include <hip/hip_runtime.h>
#include <hip/hip_bf16.h>
#include <math.h>

// GraphSAGE: 4 layers on N=100000 nodes, E=1600000 edges.
// Round 9: packed f32x2 gather accumulation (v_pk_add_f32), global bucket_count
// (kills scan_buckets' 800KB serial read), bucketize reuses gbh histogram,
// fused cvt kernel. Structure otherwise as round 8.

typedef unsigned short u16;
typedef unsigned int u32;
typedef __attribute__((ext_vector_type(2))) float f32x2;
typedef __attribute__((ext_vector_type(4))) float f32x4;
typedef __attribute__((ext_vector_type(8))) short s16x8;

__device__ __forceinline__ float b2f(u16 u) {
  union { float f; u32 i; } v; v.i = ((u32)u) << 16; return v.f;
}
__device__ __forceinline__ u16 f2b(float f) {
  union { float f; u32 u; } v; v.f = f;
  u32 r = v.u + 0x7fffu + ((v.u >> 16) & 1u);   // RTN-even
  return (u16)(r >> 16);
}
// unpack two bf16 (packed in u32) -> float2 {low elem, high elem}
__device__ __forceinline__ f32x2 up2(u32 v) {
  union { float f; u32 u; } lo, hi;
  lo.u = v << 16;
  hi.u = v & 0xFFFF0000u;
  f32x2 r; r.x = lo.f; r.y = hi.f; return r;
}

// ---------------- CSR build ----------------
// pass 0: per-block bucket histograms (dst>>7) -> gbh row + global bucket_count
__global__ __launch_bounds__(512) void bucket_hist(const int* __restrict__ ei,
                                                   int* __restrict__ gbh,
                                                   int* __restrict__ bucket_count,
                                                   int E) {
  __shared__ int hist[1024];
  const int t = threadIdx.x;
  const int base = blockIdx.x * 8192;
  const int cnt = min(8192, E - base);
  for (int b = t; b < 1024; b += 512) hist[b] = 0;
  __syncthreads();
  for (int k = t; k < cnt; k += 512)
    atomicAdd(&hist[ei[E + base + k] >> 7], 1);
  __syncthreads();
  for (int b = t; b < 1024; b += 512) {
    int c = hist[b];
    gbh[blockIdx.x * 1024 + b] = c;
    if (c) atomicAdd(&bucket_count[b], c);
  }
}

// pass 0b: exclusive scan over 1024 bucket counts -> bucket_base, gcur
__global__ __launch_bounds__(512) void scan_tiny(const int* __restrict__ bucket_count,
                                                 int* __restrict__ bucket_base,
                                                 int* __restrict__ gcur,
                                                 int* __restrict__ rowptr,
                                                 int N, int E) {
  __shared__ int wsum[512];
  const int t = threadIdx.x;
  int c0 = bucket_count[2 * t];
  int c1 = bucket_count[2 * t + 1];
  int s = c0 + c1;
  wsum[t] = s;
  __syncthreads();
  for (int off = 1; off < 512; off <<= 1) {
    int add = (t >= off) ? wsum[t - off] : 0;
    __syncthreads();
    wsum[t] += add;
    __syncthreads();
  }
  int excl = wsum[t] - s;
  bucket_base[2 * t] = excl;
  bucket_base[2 * t + 1] = excl + c0;
  gcur[2 * t] = excl;
  gcur[2 * t + 1] = excl + c0;
  if (t == 511) bucket_base[1024] = wsum[511];
  if (t == 0) rowptr[N] = E;
}

// pass 1: bucketize edges by dst>>7 (histogram loaded from gbh)
__global__ __launch_bounds__(512) void bucketize(const int* __restrict__ ei,
                                                 const int* __restrict__ gbh,
                                                 int* __restrict__ gcur,
                                                 u32* __restrict__ staging,
                                                 int E, int B) {
  __shared__ u32 vals[8192];
  __shared__ u16 bkt[8192];
  __shared__ int hist[1024], ofs[1024], curx[1024], gbase[1024];
  __shared__ int wsum[512];

  const int t = threadIdx.x;
  const int base = blockIdx.x * 8192;
  const int cnt = min(8192, E - base);

  for (int b = t; b < 1024; b += 512) hist[b] = gbh[blockIdx.x * 1024 + b];
  __syncthreads();

  int a0 = hist[2 * t], a1 = hist[2 * t + 1];
  int s = a0 + a1;
  wsum[t] = s;
  __syncthreads();
  for (int off = 1; off < 512; off <<= 1) {
    int add = (t >= off) ? wsum[t - off] : 0;
    __syncthreads();
    wsum[t] += add;
    __syncthreads();
  }
  int excl = wsum[t] - s;
  ofs[2 * t] = excl;
  ofs[2 * t + 1] = excl + a0;
  __syncthreads();

  for (int b = t; b < B; b += 512) {
    int c = hist[b];
    gbase[b] = c ? atomicAdd(&gcur[b], c) : 0;
    curx[b] = ofs[b];
  }
  __syncthreads();

  for (int k = t; k < cnt; k += 512) {
    int sv = ei[base + k];
    int d = ei[E + base + k];
    int b = d >> 7;
    u32 val = (u32)sv | ((u32)(d & 127) << 17);
    int lpos = atomicAdd(&curx[b], 1);
    vals[lpos] = val;
    bkt[lpos] = (u16)b;
  }
  __syncthreads();

  for (int i = t; i < cnt; i += 512) {
    int b = bkt[i];
    staging[gbase[b] + (i - ofs[b])] = vals[i];
  }
}

// pass 2: per bucket — derive rowptr (LDS count+scan) and place edges
__global__ __launch_bounds__(256) void place(const u32* __restrict__ staging,
                                             const int* __restrict__ bucket_base,
                                             int* __restrict__ rowptr,
                                             int* __restrict__ csr, int N) {
  __shared__ int cnt[128], excl[128], cur[128], sc[128];
  const int t = threadIdx.x;
  const int node0 = blockIdx.x << 7;
  const int nn = min(128, N - node0);
  if (t < 128) { cnt[t] = 0; cur[t] = 0; }
  __syncthreads();
  const int rstart = bucket_base[blockIdx.x];
  const int rend = bucket_base[blockIdx.x + 1];
  for (int i = rstart + t; i < rend; i += 256)
    atomicAdd(&cnt[staging[i] >> 17], 1);
  __syncthreads();
  if (t < 128) sc[t] = cnt[t];
  __syncthreads();
  for (int off = 1; off < 128; off <<= 1) {
    int add = (t < 128 && t >= off) ? sc[t - off] : 0;
    __syncthreads();
    if (t < 128) sc[t] += add;
    __syncthreads();
  }
  if (t < 128) excl[t] = sc[t] - cnt[t];
  if (t < nn) rowptr[node0 + t] = rstart + excl[t];
  __syncthreads();
  for (int i = rstart + t; i < rend; i += 256) {
    u32 v = staging[i];
    int nl = v >> 17;
    int src = v & 0x1FFFF;
    int tk = atomicAdd(&cur[nl], 1);
    csr[rstart + excl[nl] + tk] = src;
  }
}

// ---------------- conversions (fused) ----------------
__global__ __launch_bounds__(256) void cvt_all(const float* __restrict__ x,
                                               u16* __restrict__ xb, int total4,
                                               const float* __restrict__ W1l,
                                               const float* __restrict__ W1r,
                                               const float* __restrict__ W2l,
                                               const float* __restrict__ W2r,
                                               u16* __restrict__ wt1,
                                               u16* __restrict__ wt2) {
  int i = blockIdx.x * 256 + threadIdx.x;
  if (i < total4) {
    float4 v = *(const float4*)(x + (size_t)i * 4);
    u32 lo = (u32)f2b(v.x) | ((u32)f2b(v.y) << 16);
    u32 hi = (u32)f2b(v.z) | ((u32)f2b(v.w) << 16);
    uint2 o; o.x = lo; o.y = hi;
    *(uint2*)(xb + (size_t)i * 4) = o;
    return;
  }
  int j = i - total4;
  if (j < 16384) {                 // Wt1: 128 x 128
    int jj = j >> 7, k = j & 127;
    float v = (k < 64) ? W1l[k * 128 + jj] : W1r[(k - 64) * 128 + jj];
    wt1[jj * 128 + k] = f2b(v);
  } else if (j < 16384 + 32768) {  // Wt2: 128 x 256
    int i2 = j - 16384;
    int jj = i2 >> 8, k = i2 & 255;
    float v = (k < 128) ? W2l[k * 128 + jj] : W2r[(k - 128) * 128 + jj];
    wt2[jj * 256 + k] = f2b(v);
  }
}

// ---------------- gather means (bf16, packed f32x2 accumulation) ----------------
#define PACC(v)                                                        \
  a0 += up2((v).x); a1 += up2((v).y); a2 += up2((v).z); a3 += up2((v).w);

__global__ __launch_bounds__(256) void gather_mean_64b(const u16* __restrict__ xb,
                                                       const int* __restrict__ rowptr,
                                                       const int* __restrict__ csr,
                                                       u16* __restrict__ mean, int N) {
  int n = (blockIdx.x * 256 + threadIdx.x) >> 6;
  int lane = threadIdx.x & 63;
  int sub = lane >> 3;
  int ln = lane & 7;
  if (n >= N) return;
  int s0 = rowptr[n], s1 = rowptr[n + 1];
  f32x2 a0 = (f32x2)(0.f), a1 = (f32x2)(0.f), a2 = (f32x2)(0.f), a3 = (f32x2)(0.f);
  int e = s0;
  for (; e + 16 <= s1; e += 16) {
    int i0 = csr[e + sub], i1 = csr[e + 8 + sub];
    uint4 v0 = *(const uint4*)(xb + (size_t)i0 * 64 + ln * 8);
    uint4 v1 = *(const uint4*)(xb + (size_t)i1 * 64 + ln * 8);
    PACC(v0); PACC(v1);
  }
  for (; e + 8 <= s1; e += 8) {
    int i0 = csr[e + sub];
    uint4 v0 = *(const uint4*)(xb + (size_t)i0 * 64 + ln * 8);
    PACC(v0);
  }
  int rem = s1 - e;
  if (sub < rem) {
    int i0 = csr[e + sub];
    uint4 v0 = *(const uint4*)(xb + (size_t)i0 * 64 + ln * 8);
    PACC(v0);
  }
#pragma unroll
  for (int off = 8; off < 64; off <<= 1) {
    a0.x += __shfl_xor(a0.x, off); a0.y += __shfl_xor(a0.y, off);
    a1.x += __shfl_xor(a1.x, off); a1.y += __shfl_xor(a1.y, off);
    a2.x += __shfl_xor(a2.x, off); a2.y += __shfl_xor(a2.y, off);
    a3.x += __shfl_xor(a3.x, off); a3.y += __shfl_xor(a3.y, off);
  }
  if (sub == 0) {
    int c = s1 - s0;
    float inv = c > 0 ? 1.f / (float)c : 0.f;
    uint4 o;
    o.x = (u32)f2b(a0.x * inv) | ((u32)f2b(a0.y * inv) << 16);
    o.y = (u32)f2b(a1.x * inv) | ((u32)f2b(a1.y * inv) << 16);
    o.z = (u32)f2b(a2.x * inv) | ((u32)f2b(a2.y * inv) << 16);
    o.w = (u32)f2b(a3.x * inv) | ((u32)f2b(a3.y * inv) << 16);
    *(uint4*)(mean + (size_t)n * 64 + ln * 8) = o;
  }
}

__global__ __launch_bounds__(256) void gather_mean_128b(const u16* __restrict__ hb,
                                                        const int* __restrict__ rowptr,
                                                        const int* __restrict__ csr,
                                                        u16* __restrict__ mean, int N) {
  int n = (blockIdx.x * 256 + threadIdx.x) >> 6;
  int lane = threadIdx.x & 63;
  int sub = lane >> 4;
  int ln = lane & 15;
  if (n >= N) return;
  int s0 = rowptr[n], s1 = rowptr[n + 1];
  f32x2 a0 = (f32x2)(0.f), a1 = (f32x2)(0.f), a2 = (f32x2)(0.f), a3 = (f32x2)(0.f);
  int e = s0;
  for (; e + 8 <= s1; e += 8) {
    int i0 = csr[e + sub], i1 = csr[e + 4 + sub];
    uint4 v0 = *(const uint4*)(hb + (size_t)i0 * 128 + ln * 8);
    uint4 v1 = *(const uint4*)(hb + (size_t)i1 * 128 + ln * 8);
    PACC(v0); PACC(v1);
  }
  for (; e + 4 <= s1; e += 4) {
    int i0 = csr[e + sub];
    uint4 v0 = *(const uint4*)(hb + (size_t)i0 * 128 + ln * 8);
    PACC(v0);
  }
  int rem = s1 - e;
  if (sub < rem) {
    int i0 = csr[e + sub];
    uint4 v0 = *(const uint4*)(hb + (size_t)i0 * 128 + ln * 8);
    PACC(v0);
  }
#pragma unroll
  for (int off = 16; off < 64; off <<= 1) {
    a0.x += __shfl_xor(a0.x, off); a0.y += __shfl_xor(a0.y, off);
    a1.x += __shfl_xor(a1.x, off); a1.y += __shfl_xor(a1.y, off);
    a2.x += __shfl_xor(a2.x, off); a2.y += __shfl_xor(a2.y, off);
    a3.x += __shfl_xor(a3.x, off); a3.y += __shfl_xor(a3.y, off);
  }
  if (sub == 0) {
    int c = s1 - s0;
    float inv = c > 0 ? 1.f / (float)c : 0.f;
    uint4 o;
    o.x = (u32)f2b(a0.x * inv) | ((u32)f2b(a0.y * inv) << 16);
    o.y = (u32)f2b(a1.x * inv) | ((u32)f2b(a1.y * inv) << 16);
    o.z = (u32)f2b(a2.x * inv) | ((u32)f2b(a2.y * inv) << 16);
    o.w = (u32)f2b(a3.x * inv) | ((u32)f2b(a3.y * inv) << 16);
    *(uint4*)(mean + (size_t)n * 128 + ln * 8) = o;
  }
}

// ---------------- MFMA GEMM (FINAL fuses p,q projection; h2 never stored) ------
template<int K2, bool FINAL>
__global__ __launch_bounds__(512) void mfma_gemm(
    const u16* __restrict__ meanb, const u16* __restrict__ prevb,
    const u16* __restrict__ wt,    // [128][K2] bf16 (pre-transposed)
    const float* __restrict__ bias,
    u16* __restrict__ hout,
    const float* __restrict__ W3l, const float* __restrict__ W3r,
    float* __restrict__ outp, float* __restrict__ outq, int N) {
  constexpr int KH = K2 / 2;
  constexpr int NC = K2 / 8;
  __shared__ __align__(16) u16 Albs[128 * K2];
  __shared__ __align__(16) u16 Wlds[128 * K2];

  const int t = threadIdx.x;
  const int tile = blockIdx.x * 128;

  for (int i = t; i < 128 * NC; i += 512) {
    int j = i / NC, c = i - j * NC;
    uint4 v = *(const uint4*)(wt + (size_t)j * K2 + c * 8);
    *(uint4*)(Wlds + j * K2 + ((c ^ (j & 7)) << 3)) = v;
  }
  for (int i = t; i < 128 * NC; i += 512) {
    int r = i / NC, c = i - r * NC;
    int node = tile + r;
    uint4 v; v.x = 0; v.y = 0; v.z = 0; v.w = 0;
    if (node < N) {
      int k0 = c * 8;
      v = (k0 < KH) ? *(const uint4*)(meanb + (size_t)node * KH + k0)
                    : *(const uint4*)(prevb + (size_t)node * KH + (k0 - KH));
    }
    *(uint4*)(Albs + r * K2 + ((c ^ (r & 7)) << 3)) = v;
  }
  __syncthreads();

  const int lane = t & 63;
  const int wid = t >> 6;
  const int wm = wid >> 1, wn = wid & 1;
  const int er = lane & 15;
  const int kg = lane >> 4;

  f32x4 acc[2][4];
#pragma unroll
  for (int mi = 0; mi < 2; ++mi)
#pragma unroll
    for (int ni = 0; ni < 4; ++ni) acc[mi][ni] = (f32x4)(0.f);

#pragma unroll
  for (int ks = 0; ks < K2 / 32; ++ks) {
    int cidx = ks * 4 + kg;
    s16x8 a[2], b[4];
#pragma unroll
    for (int mi = 0; mi < 2; ++mi) {
      int row = wm * 32 + mi * 16 + er;
      a[mi] = *(const s16x8*)(Albs + row * K2 + ((cidx ^ (row & 7)) << 3));
    }
#pragma unroll
    for (int ni = 0; ni < 4; ++ni) {
      int col = wn * 64 + ni * 16 + er;
      b[ni] = *(const s16x8*)(Wlds + col * K2 + ((cidx ^ (col & 7)) << 3));
    }
#pragma unroll
    for (int mi = 0; mi < 2; ++mi)
#pragma unroll
      for (int ni = 0; ni < 4; ++ni)
        acc[mi][ni] = __builtin_amdgcn_mfma_f32_16x16x32_bf16(a[mi], b[ni], acc[mi][ni], 0, 0, 0);
  }

  if constexpr (!FINAL) {
#pragma unroll
    for (int mi = 0; mi < 2; ++mi) {
#pragma unroll
      for (int ni = 0; ni < 4; ++ni) {
        int col = wn * 64 + ni * 16 + er;
        float bv = bias[col];
#pragma unroll
        for (int r = 0; r < 4; ++r) {
          int node = tile + wm * 32 + mi * 16 + kg * 4 + r;
          if (node < N) {
            float v = acc[mi][ni][r] + bv;
            v = v > 0.f ? v : 0.f;
            hout[(size_t)node * 128 + col] = f2b(v);
          }
        }
      }
    }
  } else {
    __shared__ float p_lds[128][2], q_lds[128][2];
    float wl[4], wr[4], bv[4];
#pragma unroll
    for (int ni = 0; ni < 4; ++ni) {
      int col = wn * 64 + ni * 16 + er;
      wl[ni] = W3l[col]; wr[ni] = W3r[col]; bv[ni] = bias[col];
    }
#pragma unroll
    for (int mi = 0; mi < 2; ++mi) {
#pragma unroll
      for (int r = 0; r < 4; ++r) {
        float pv = 0.f, qv = 0.f;
#pragma unroll
        for (int ni = 0; ni < 4; ++ni) {
          float v = acc[mi][ni][r] + bv[ni];
          v = v > 0.f ? v : 0.f;
          pv = fmaf(v, wl[ni], pv);
          qv = fmaf(v, wr[ni], qv);
        }
#pragma unroll
        for (int off = 1; off < 16; off <<= 1) {
          pv += __shfl_xor(pv, off);
          qv += __shfl_xor(qv, off);
        }
        if (er == 0) {
          int nl = wm * 32 + mi * 16 + kg * 4 + r;
          p_lds[nl][wn] = pv;
          q_lds[nl][wn] = qv;
        }
      }
    }
    __syncthreads();
    if (t < 128) {
      int node = tile + t;
      if (node < N) {
        outp[node] = p_lds[t][0] + p_lds[t][1];
        outq[node] = q_lds[t][0] + q_lds[t][1];
      }
    }
  }
}

// ---------------- layer 3 fused: h3 = mean_e(p) + q + b3 ; out_scalar ----------------
__global__ __launch_bounds__(256) void gather3_fused(const float* __restrict__ p,
                                                     const int* __restrict__ rowptr,
                                                     const int* __restrict__ csr,
                                                     const float* __restrict__ q,
                                                     const float* __restrict__ b3,
                                                     float* __restrict__ h3,
                                                     float* __restrict__ out_scalar, int N) {
  int n = blockIdx.x * 256 + threadIdx.x;
  if (n >= N) return;
  int s0 = rowptr[n], s1 = rowptr[n + 1];
  float a = 0.f;
  for (int e = s0; e < s1; ++e) a += p[csr[e]];
  int c = s1 - s0;
  float inv = c > 0 ? 1.f / (float)c : 0.f;
  float v = a * inv + q[n] + b3[0];
  h3[n] = v;
  out_scalar[n] = v;
}

// ---------------- layer 4 fused: mean_e(h3) -> logits -> log_softmax ----------------
__global__ __launch_bounds__(256) void gather4_fused(const float* __restrict__ h3,
                                                     const int* __restrict__ rowptr,
                                                     const int* __restrict__ csr,
                                                     const float* __restrict__ W4l,
                                                     const float* __restrict__ W4r,
                                                     const float* __restrict__ b4,
                                                     float* __restrict__ out, int N) {
  int n = blockIdx.x * 256 + threadIdx.x;
  if (n >= N) return;
  int s0 = rowptr[n], s1 = rowptr[n + 1];
  float a = 0.f;
  for (int e = s0; e < s1; ++e) a += h3[csr[e]];
  int c = s1 - s0;
  float inv = c > 0 ? 1.f / (float)c : 0.f;
  float m = a * inv;
  float hv = h3[n];
  float logits[8];
  float mx = -1e30f;
#pragma unroll
  for (int jj = 0; jj < 8; ++jj) {
    float v = m * W4l[jj] + hv * W4r[jj] + b4[jj];
    logits[jj] = v;
    mx = v > mx ? v : mx;
  }
  float s = 0.f;
#pragma unroll
  for (int jj = 0; jj < 8; ++jj) s += expf(logits[jj] - mx);
  float lse = mx + logf(s);
  float4 o0, o1;
  o0.x = logits[0] - lse; o0.y = logits[1] - lse; o0.z = logits[2] - lse; o0.w = logits[3] - lse;
  o1.x = logits[4] - lse; o1.y = logits[5] - lse; o1.z = logits[6] - lse; o1.w = logits[7] - lse;
  float4* o4 = (float4*)(out + (size_t)n * 8);
  o4[0] = o0; o4[1] = o1;
}

extern "C" void kernel_launch(void* const* d_in, const int* in_sizes, int n_in,
                              void* d_out, int out_size, void* d_ws, size_t ws_size,
                              hipStream_t stream) {
  const float* x   = (const float*)d_in[0];
  const int*   ei  = (const int*)d_in[1];
  const float* W1l = (const float*)d_in[2];
  const float* W1r = (const float*)d_in[3];
  const float* b1  = (const float*)d_in[4];
  const float* W2l = (const float*)d_in[5];
  const float* W2r = (const float*)d_in[6];
  const float* b2  = (const float*)d_in[7];
  const float* W3l = (const float*)d_in[8];
  const float* W3r = (const float*)d_in[9];
  const float* b3  = (const float*)d_in[10];
  const float* W4l = (const float*)d_in[11];
  const float* W4r = (const float*)d_in[12];
  const float* b4  = (const float*)d_in[13];

  const int N = in_sizes[0] / 64;   // 100000
  const int E = in_sizes[1] / 2;    // 1600000
  const size_t Ns = (size_t)N;
  const int B = (N + 127) >> 7;     // 782 buckets
  const int NBLK = (E + 8191) / 8192;  // 196

  // ---- workspace layout ----
  u16* ub      = (u16*)d_ws;
  u16* xb      = ub;                 // 64N
  u16* mean0b  = ub + 64 * Ns;       // 64N
  u16* h1b     = ub + 128 * Ns;      // 128N
  u16* mean1b  = ub + 256 * Ns;      // 128N
  u16* wt1     = ub + 384 * Ns;      // 16384
  u16* wt2     = wt1 + 16384;        // 32768
  float* fb    = (float*)(wt2 + 32768);
  float* p     = fb;                 // N
  float* q     = fb + Ns;            // N
  float* h3    = fb + 2 * Ns;        // N
  int* ib      = (int*)(fb + 3 * Ns);
  int* rowptr       = ib;                      // N+1
  int* gcur         = ib + (N + 1);            // 1024
  int* bucket_base  = gcur + 1024;             // 1025
  int* bucket_count = bucket_base + 1025;      // 1024
  int* gbh          = bucket_count + 1024;     // NBLK*1024
  int* csr          = gbh + NBLK * 1024;       // E
  u32* staging      = (u32*)(csr + E);         // E

  float* out_rock   = (float*)d_out;            // N x 8
  float* out_scalar = (float*)d_out + 8 * Ns;   // N

  const int GG = (N + 127) / 128;
  const int total4 = N * 16;

  // ---- CSR build ----
  hipMemsetAsync(bucket_count, 0, 1024 * sizeof(int), stream);
  bucket_hist<<<NBLK, 512, 0, stream>>>(ei, gbh, bucket_count, E);
  scan_tiny<<<1, 512, 0, stream>>>(bucket_count, bucket_base, gcur, rowptr, N, E);
  bucketize<<<NBLK, 512, 0, stream>>>(ei, gbh, gcur, staging, E, B);
  place<<<B, 256, 0, stream>>>(staging, bucket_base, rowptr, csr, N);

  // ---- conversions ----
  cvt_all<<<(total4 + 49152 + 255) / 256, 256, 0, stream>>>(
      x, xb, total4, W1l, W1r, W2l, W2r, wt1, wt2);

  // ---- layer 1 ----
  gather_mean_64b<<<(N + 3) / 4, 256, 0, stream>>>(xb, rowptr, csr, mean0b, N);
  mfma_gemm<128, false><<<GG, 512, 0, stream>>>(
      mean0b, xb, wt1, b1, h1b, nullptr, nullptr, nullptr, nullptr, N);

  // ---- layer 2 (+ fused p,q) ----
  gather_mean_128b<<<(N + 3) / 4, 256, 0, stream>>>(h1b, rowptr, csr, mean1b, N);
  mfma_gemm<256, true><<<GG, 512, 0, stream>>>(
      mean1b, h1b, wt2, b2, nullptr, W3l, W3r, p, q, N);

  // ---- layer 3 (scalar) ----
  gather3_fused<<<(N + 255) / 256, 256, 0, stream>>>(p, rowptr, csr, q, b3, h3, out_scalar, N);

  // ---- layer 4 (scalar in, 8 out) ----
  gather4_fused<<<(N + 255) / 256, 256, 0, stream>>>(h3, rowptr, csr, W4l, W4r, b4, out_rock, N);
}

// Round 10
// 231.196 us; speedup vs baseline: 22.3666x; 1.0382x over previous
//
#include <hip/hip_runtime.h>
#include <hip/hip_bf16.h>
#include <math.h>

// GraphSAGE: 4 layers on N=100000 nodes, E=1600000 edges.
// Round 10: drop bucket_hist pass (fixed-capacity staging, bucketize
// self-histograms), deepen gather-128 MLP to 16 edges/iter.

typedef unsigned short u16;
typedef unsigned int u32;
typedef __attribute__((ext_vector_type(2))) float f32x2;
typedef __attribute__((ext_vector_type(4))) float f32x4;
typedef __attribute__((ext_vector_type(8))) short s16x8;

#define BCAP 4096  // staging capacity per bucket (mean 2048, +45 sigma)

__device__ __forceinline__ float b2f(u16 u) {
  union { float f; u32 i; } v; v.i = ((u32)u) << 16; return v.f;
}
__device__ __forceinline__ u16 f2b(float f) {
  union { float f; u32 u; } v; v.f = f;
  u32 r = v.u + 0x7fffu + ((v.u >> 16) & 1u);   // RTN-even
  return (u16)(r >> 16);
}
__device__ __forceinline__ f32x2 up2(u32 v) {
  union { float f; u32 u; } lo, hi;
  lo.u = v << 16;
  hi.u = v & 0xFFFF0000u;
  f32x2 r; r.x = lo.f; r.y = hi.f; return r;
}

// ---------------- CSR build ----------------
// pass 1: bucketize edges by dst>>7 into fixed-capacity bucket slices.
__global__ __launch_bounds__(512) void bucketize(const int* __restrict__ ei,
                                                 int* __restrict__ gcur,
                                                 u32* __restrict__ staging,
                                                 int E, int B) {
  __shared__ u32 vals[8192];
  __shared__ u16 bkt[8192];
  __shared__ int hist[1024], ofs[1024], curx[1024], gbase[1024];
  __shared__ int wsum[512];

  const int t = threadIdx.x;
  const int base = blockIdx.x * 8192;
  const int cnt = min(8192, E - base);

  for (int b = t; b < 1024; b += 512) hist[b] = 0;
  __syncthreads();

  for (int k = t; k < cnt; k += 512) {
    int d = ei[E + base + k];
    atomicAdd(&hist[d >> 7], 1);
  }
  __syncthreads();

  int a0 = hist[2 * t], a1 = hist[2 * t + 1];
  int s = a0 + a1;
  wsum[t] = s;
  __syncthreads();
  for (int off = 1; off < 512; off <<= 1) {
    int add = (t >= off) ? wsum[t - off] : 0;
    __syncthreads();
    wsum[t] += add;
    __syncthreads();
  }
  int excl = wsum[t] - s;
  ofs[2 * t] = excl;
  ofs[2 * t + 1] = excl + a0;
  __syncthreads();

  // reserve bucket-local slices
  for (int b = t; b < B; b += 512) {
    int c = hist[b];
    gbase[b] = c ? atomicAdd(&gcur[b], c) : 0;
    curx[b] = ofs[b];
  }
  __syncthreads();

  // stage values bucket-sorted in LDS
  for (int k = t; k < cnt; k += 512) {
    int sv = ei[base + k];
    int d = ei[E + base + k];
    int b = d >> 7;
    u32 val = (u32)sv | ((u32)(d & 127) << 17);
    int lpos = atomicAdd(&curx[b], 1);
    vals[lpos] = val;
    bkt[lpos] = (u16)b;
  }
  __syncthreads();

  // write-out to fixed-capacity slices (runs of same bucket are consecutive)
  for (int i = t; i < cnt; i += 512) {
    int b = bkt[i];
    staging[(size_t)b * BCAP + gbase[b] + (i - ofs[b])] = vals[i];
  }
}

// pass 1b: exclusive scan over 1024 bucket counts -> bucket_base
__global__ __launch_bounds__(512) void scan_tiny(const int* __restrict__ gcur,
                                                 int* __restrict__ bucket_base,
                                                 int* __restrict__ rowptr,
                                                 int N, int E) {
  __shared__ int wsum[512];
  const int t = threadIdx.x;
  int c0 = gcur[2 * t];
  int c1 = gcur[2 * t + 1];
  int s = c0 + c1;
  wsum[t] = s;
  __syncthreads();
  for (int off = 1; off < 512; off <<= 1) {
    int add = (t >= off) ? wsum[t - off] : 0;
    __syncthreads();
    wsum[t] += add;
    __syncthreads();
  }
  int excl = wsum[t] - s;
  bucket_base[2 * t] = excl;
  bucket_base[2 * t + 1] = excl + c0;
  if (t == 511) bucket_base[1024] = wsum[511];
  if (t == 0) rowptr[N] = E;
}

// pass 2: per bucket — derive rowptr (LDS count+scan) and place edges
__global__ __launch_bounds__(256) void place(const u32* __restrict__ staging,
                                             const int* __restrict__ bucket_base,
                                             int* __restrict__ rowptr,
                                             int* __restrict__ csr, int N) {
  __shared__ int cnt[128], excl[128], cur[128], sc[128];
  const int t = threadIdx.x;
  const int node0 = blockIdx.x << 7;
  const int nn = min(128, N - node0);
  if (t < 128) { cnt[t] = 0; cur[t] = 0; }
  __syncthreads();
  const int rstart = bucket_base[blockIdx.x];
  const int ec = bucket_base[blockIdx.x + 1] - rstart;
  const u32* slice = staging + (size_t)blockIdx.x * BCAP;
  for (int i = t; i < ec; i += 256)
    atomicAdd(&cnt[slice[i] >> 17], 1);
  __syncthreads();
  if (t < 128) sc[t] = cnt[t];
  __syncthreads();
  for (int off = 1; off < 128; off <<= 1) {
    int add = (t < 128 && t >= off) ? sc[t - off] : 0;
    __syncthreads();
    if (t < 128) sc[t] += add;
    __syncthreads();
  }
  if (t < 128) excl[t] = sc[t] - cnt[t];
  if (t < nn) rowptr[node0 + t] = rstart + excl[t];
  __syncthreads();
  for (int i = t; i < ec; i += 256) {
    u32 v = slice[i];
    int nl = v >> 17;
    int src = v & 0x1FFFF;
    int tk = atomicAdd(&cur[nl], 1);
    csr[rstart + excl[nl] + tk] = src;
  }
}

// ---------------- conversions (fused) ----------------
__global__ __launch_bounds__(256) void cvt_all(const float* __restrict__ x,
                                               u16* __restrict__ xb, int total4,
                                               const float* __restrict__ W1l,
                                               const float* __restrict__ W1r,
                                               const float* __restrict__ W2l,
                                               const float* __restrict__ W2r,
                                               u16* __restrict__ wt1,
                                               u16* __restrict__ wt2) {
  int i = blockIdx.x * 256 + threadIdx.x;
  if (i < total4) {
    float4 v = *(const float4*)(x + (size_t)i * 4);
    u32 lo = (u32)f2b(v.x) | ((u32)f2b(v.y) << 16);
    u32 hi = (u32)f2b(v.z) | ((u32)f2b(v.w) << 16);
    uint2 o; o.x = lo; o.y = hi;
    *(uint2*)(xb + (size_t)i * 4) = o;
    return;
  }
  int j = i - total4;
  if (j < 16384) {                 // Wt1: 128 x 128
    int jj = j >> 7, k = j & 127;
    float v = (k < 64) ? W1l[k * 128 + jj] : W1r[(k - 64) * 128 + jj];
    wt1[jj * 128 + k] = f2b(v);
  } else if (j < 16384 + 32768) {  // Wt2: 128 x 256
    int i2 = j - 16384;
    int jj = i2 >> 8, k = i2 & 255;
    float v = (k < 128) ? W2l[k * 128 + jj] : W2r[(k - 128) * 128 + jj];
    wt2[jj * 256 + k] = f2b(v);
  }
}

// ---------------- gather means (bf16, packed f32x2 accumulation) ----------------
#define PACC(v)                                                        \
  a0 += up2((v).x); a1 += up2((v).y); a2 += up2((v).z); a3 += up2((v).w);

__global__ __launch_bounds__(256) void gather_mean_64b(const u16* __restrict__ xb,
                                                       const int* __restrict__ rowptr,
                                                       const int* __restrict__ csr,
                                                       u16* __restrict__ mean, int N) {
  int n = (blockIdx.x * 256 + threadIdx.x) >> 6;
  int lane = threadIdx.x & 63;
  int sub = lane >> 3;
  int ln = lane & 7;
  if (n >= N) return;
  int s0 = rowptr[n], s1 = rowptr[n + 1];
  f32x2 a0 = (f32x2)(0.f), a1 = (f32x2)(0.f), a2 = (f32x2)(0.f), a3 = (f32x2)(0.f);
  int e = s0;
  for (; e + 16 <= s1; e += 16) {
    int i0 = csr[e + sub], i1 = csr[e + 8 + sub];
    uint4 v0 = *(const uint4*)(xb + (size_t)i0 * 64 + ln * 8);
    uint4 v1 = *(const uint4*)(xb + (size_t)i1 * 64 + ln * 8);
    PACC(v0); PACC(v1);
  }
  for (; e + 8 <= s1; e += 8) {
    int i0 = csr[e + sub];
    uint4 v0 = *(const uint4*)(xb + (size_t)i0 * 64 + ln * 8);
    PACC(v0);
  }
  int rem = s1 - e;
  if (sub < rem) {
    int i0 = csr[e + sub];
    uint4 v0 = *(const uint4*)(xb + (size_t)i0 * 64 + ln * 8);
    PACC(v0);
  }
#pragma unroll
  for (int off = 8; off < 64; off <<= 1) {
    a0.x += __shfl_xor(a0.x, off); a0.y += __shfl_xor(a0.y, off);
    a1.x += __shfl_xor(a1.x, off); a1.y += __shfl_xor(a1.y, off);
    a2.x += __shfl_xor(a2.x, off); a2.y += __shfl_xor(a2.y, off);
    a3.x += __shfl_xor(a3.x, off); a3.y += __shfl_xor(a3.y, off);
  }
  if (sub == 0) {
    int c = s1 - s0;
    float inv = c > 0 ? 1.f / (float)c : 0.f;
    uint4 o;
    o.x = (u32)f2b(a0.x * inv) | ((u32)f2b(a0.y * inv) << 16);
    o.y = (u32)f2b(a1.x * inv) | ((u32)f2b(a1.y * inv) << 16);
    o.z = (u32)f2b(a2.x * inv) | ((u32)f2b(a2.y * inv) << 16);
    o.w = (u32)f2b(a3.x * inv) | ((u32)f2b(a3.y * inv) << 16);
    *(uint4*)(mean + (size_t)n * 64 + ln * 8) = o;
  }
}

__global__ __launch_bounds__(256) void gather_mean_128b(const u16* __restrict__ hb,
                                                        const int* __restrict__ rowptr,
                                                        const int* __restrict__ csr,
                                                        u16* __restrict__ mean, int N) {
  int n = (blockIdx.x * 256 + threadIdx.x) >> 6;
  int lane = threadIdx.x & 63;
  int sub = lane >> 4;
  int ln = lane & 15;
  if (n >= N) return;
  int s0 = rowptr[n], s1 = rowptr[n + 1];
  f32x2 a0 = (f32x2)(0.f), a1 = (f32x2)(0.f), a2 = (f32x2)(0.f), a3 = (f32x2)(0.f);
  int e = s0;
  for (; e + 16 <= s1; e += 16) {   // 16 edges in flight (4 loads/thread)
    int i0 = csr[e + sub], i1 = csr[e + 4 + sub];
    int i2 = csr[e + 8 + sub], i3 = csr[e + 12 + sub];
    uint4 v0 = *(const uint4*)(hb + (size_t)i0 * 128 + ln * 8);
    uint4 v1 = *(const uint4*)(hb + (size_t)i1 * 128 + ln * 8);
    uint4 v2 = *(const uint4*)(hb + (size_t)i2 * 128 + ln * 8);
    uint4 v3 = *(const uint4*)(hb + (size_t)i3 * 128 + ln * 8);
    PACC(v0); PACC(v1); PACC(v2); PACC(v3);
  }
  for (; e + 8 <= s1; e += 8) {
    int i0 = csr[e + sub], i1 = csr[e + 4 + sub];
    uint4 v0 = *(const uint4*)(hb + (size_t)i0 * 128 + ln * 8);
    uint4 v1 = *(const uint4*)(hb + (size_t)i1 * 128 + ln * 8);
    PACC(v0); PACC(v1);
  }
  for (; e + 4 <= s1; e += 4) {
    int i0 = csr[e + sub];
    uint4 v0 = *(const uint4*)(hb + (size_t)i0 * 128 + ln * 8);
    PACC(v0);
  }
  int rem = s1 - e;
  if (sub < rem) {
    int i0 = csr[e + sub];
    uint4 v0 = *(const uint4*)(hb + (size_t)i0 * 128 + ln * 8);
    PACC(v0);
  }
#pragma unroll
  for (int off = 16; off < 64; off <<= 1) {
    a0.x += __shfl_xor(a0.x, off); a0.y += __shfl_xor(a0.y, off);
    a1.x += __shfl_xor(a1.x, off); a1.y += __shfl_xor(a1.y, off);
    a2.x += __shfl_xor(a2.x, off); a2.y += __shfl_xor(a2.y, off);
    a3.x += __shfl_xor(a3.x, off); a3.y += __shfl_xor(a3.y, off);
  }
  if (sub == 0) {
    int c = s1 - s0;
    float inv = c > 0 ? 1.f / (float)c : 0.f;
    uint4 o;
    o.x = (u32)f2b(a0.x * inv) | ((u32)f2b(a0.y * inv) << 16);
    o.y = (u32)f2b(a1.x * inv) | ((u32)f2b(a1.y * inv) << 16);
    o.z = (u32)f2b(a2.x * inv) | ((u32)f2b(a2.y * inv) << 16);
    o.w = (u32)f2b(a3.x * inv) | ((u32)f2b(a3.y * inv) << 16);
    *(uint4*)(mean + (size_t)n * 128 + ln * 8) = o;
  }
}

// ---------------- MFMA GEMM (FINAL fuses p,q projection; h2 never stored) ------
template<int K2, bool FINAL>
__global__ __launch_bounds__(512) void mfma_gemm(
    const u16* __restrict__ meanb, const u16* __restrict__ prevb,
    const u16* __restrict__ wt,    // [128][K2] bf16 (pre-transposed)
    const float* __restrict__ bias,
    u16* __restrict__ hout,
    const float* __restrict__ W3l, const float* __restrict__ W3r,
    float* __restrict__ outp, float* __restrict__ outq, int N) {
  constexpr int KH = K2 / 2;
  constexpr int NC = K2 / 8;
  __shared__ __align__(16) u16 Albs[128 * K2];
  __shared__ __align__(16) u16 Wlds[128 * K2];

  const int t = threadIdx.x;
  const int tile = blockIdx.x * 128;

  for (int i = t; i < 128 * NC; i += 512) {
    int j = i / NC, c = i - j * NC;
    uint4 v = *(const uint4*)(wt + (size_t)j * K2 + c * 8);
    *(uint4*)(Wlds + j * K2 + ((c ^ (j & 7)) << 3)) = v;
  }
  for (int i = t; i < 128 * NC; i += 512) {
    int r = i / NC, c = i - r * NC;
    int node = tile + r;
    uint4 v; v.x = 0; v.y = 0; v.z = 0; v.w = 0;
    if (node < N) {
      int k0 = c * 8;
      v = (k0 < KH) ? *(const uint4*)(meanb + (size_t)node * KH + k0)
                    : *(const uint4*)(prevb + (size_t)node * KH + (k0 - KH));
    }
    *(uint4*)(Albs + r * K2 + ((c ^ (r & 7)) << 3)) = v;
  }
  __syncthreads();

  const int lane = t & 63;
  const int wid = t >> 6;
  const int wm = wid >> 1, wn = wid & 1;
  const int er = lane & 15;
  const int kg = lane >> 4;

  f32x4 acc[2][4];
#pragma unroll
  for (int mi = 0; mi < 2; ++mi)
#pragma unroll
    for (int ni = 0; ni < 4; ++ni) acc[mi][ni] = (f32x4)(0.f);

#pragma unroll
  for (int ks = 0; ks < K2 / 32; ++ks) {
    int cidx = ks * 4 + kg;
    s16x8 a[2], b[4];
#pragma unroll
    for (int mi = 0; mi < 2; ++mi) {
      int row = wm * 32 + mi * 16 + er;
      a[mi] = *(const s16x8*)(Albs + row * K2 + ((cidx ^ (row & 7)) << 3));
    }
#pragma unroll
    for (int ni = 0; ni < 4; ++ni) {
      int col = wn * 64 + ni * 16 + er;
      b[ni] = *(const s16x8*)(Wlds + col * K2 + ((cidx ^ (col & 7)) << 3));
    }
#pragma unroll
    for (int mi = 0; mi < 2; ++mi)
#pragma unroll
      for (int ni = 0; ni < 4; ++ni)
        acc[mi][ni] = __builtin_amdgcn_mfma_f32_16x16x32_bf16(a[mi], b[ni], acc[mi][ni], 0, 0, 0);
  }

  if constexpr (!FINAL) {
#pragma unroll
    for (int mi = 0; mi < 2; ++mi) {
#pragma unroll
      for (int ni = 0; ni < 4; ++ni) {
        int col = wn * 64 + ni * 16 + er;
        float bv = bias[col];
#pragma unroll
        for (int r = 0; r < 4; ++r) {
          int node = tile + wm * 32 + mi * 16 + kg * 4 + r;
          if (node < N) {
            float v = acc[mi][ni][r] + bv;
            v = v > 0.f ? v : 0.f;
            hout[(size_t)node * 128 + col] = f2b(v);
          }
        }
      }
    }
  } else {
    __shared__ float p_lds[128][2], q_lds[128][2];
    float wl[4], wr[4], bv[4];
#pragma unroll
    for (int ni = 0; ni < 4; ++ni) {
      int col = wn * 64 + ni * 16 + er;
      wl[ni] = W3l[col]; wr[ni] = W3r[col]; bv[ni] = bias[col];
    }
#pragma unroll
    for (int mi = 0; mi < 2; ++mi) {
#pragma unroll
      for (int r = 0; r < 4; ++r) {
        float pv = 0.f, qv = 0.f;
#pragma unroll
        for (int ni = 0; ni < 4; ++ni) {
          float v = acc[mi][ni][r] + bv[ni];
          v = v > 0.f ? v : 0.f;
          pv = fmaf(v, wl[ni], pv);
          qv = fmaf(v, wr[ni], qv);
        }
#pragma unroll
        for (int off = 1; off < 16; off <<= 1) {
          pv += __shfl_xor(pv, off);
          qv += __shfl_xor(qv, off);
        }
        if (er == 0) {
          int nl = wm * 32 + mi * 16 + kg * 4 + r;
          p_lds[nl][wn] = pv;
          q_lds[nl][wn] = qv;
        }
      }
    }
    __syncthreads();
    if (t < 128) {
      int node = tile + t;
      if (node < N) {
        outp[node] = p_lds[t][0] + p_lds[t][1];
        outq[node] = q_lds[t][0] + q_lds[t][1];
      }
    }
  }
}

// ---------------- layer 3 fused: h3 = mean_e(p) + q + b3 ; out_scalar ----------------
__global__ __launch_bounds__(256) void gather3_fused(const float* __restrict__ p,
                                                     const int* __restrict__ rowptr,
                                                     const int* __restrict__ csr,
                                                     const float* __restrict__ q,
                                                     const float* __restrict__ b3,
                                                     float* __restrict__ h3,
                                                     float* __restrict__ out_scalar, int N) {
  int n = blockIdx.x * 256 + threadIdx.x;
  if (n >= N) return;
  int s0 = rowptr[n], s1 = rowptr[n + 1];
  float a = 0.f;
  for (int e = s0; e < s1; ++e) a += p[csr[e]];
  int c = s1 - s0;
  float inv = c > 0 ? 1.f / (float)c : 0.f;
  float v = a * inv + q[n] + b3[0];
  h3[n] = v;
  out_scalar[n] = v;
}

// ---------------- layer 4 fused: mean_e(h3) -> logits -> log_softmax ----------------
__global__ __launch_bounds__(256) void gather4_fused(const float* __restrict__ h3,
                                                     const int* __restrict__ rowptr,
                                                     const int* __restrict__ csr,
                                                     const float* __restrict__ W4l,
                                                     const float* __restrict__ W4r,
                                                     const float* __restrict__ b4,
                                                     float* __restrict__ out, int N) {
  int n = blockIdx.x * 256 + threadIdx.x;
  if (n >= N) return;
  int s0 = rowptr[n], s1 = rowptr[n + 1];
  float a = 0.f;
  for (int e = s0; e < s1; ++e) a += h3[csr[e]];
  int c = s1 - s0;
  float inv = c > 0 ? 1.f / (float)c : 0.f;
  float m = a * inv;
  float hv = h3[n];
  float logits[8];
  float mx = -1e30f;
#pragma unroll
  for (int jj = 0; jj < 8; ++jj) {
    float v = m * W4l[jj] + hv * W4r[jj] + b4[jj];
    logits[jj] = v;
    mx = v > mx ? v : mx;
  }
  float s = 0.f;
#pragma unroll
  for (int jj = 0; jj < 8; ++jj) s += expf(logits[jj] - mx);
  float lse = mx + logf(s);
  float4 o0, o1;
  o0.x = logits[0] - lse; o0.y = logits[1] - lse; o0.z = logits[2] - lse; o0.w = logits[3] - lse;
  o1.x = logits[4] - lse; o1.y = logits[5] - lse; o1.z = logits[6] - lse; o1.w = logits[7] - lse;
  float4* o4 = (float4*)(out + (size_t)n * 8);
  o4[0] = o0; o4[1] = o1;
}

extern "C" void kernel_launch(void* const* d_in, const int* in_sizes, int n_in,
                              void* d_out, int out_size, void* d_ws, size_t ws_size,
                              hipStream_t stream) {
  const float* x   = (const float*)d_in[0];
  const int*   ei  = (const int*)d_in[1];
  const float* W1l = (const float*)d_in[2];
  const float* W1r = (const float*)d_in[3];
  const float* b1  = (const float*)d_in[4];
  const float* W2l = (const float*)d_in[5];
  const float* W2r = (const float*)d_in[6];
  const float* b2  = (const float*)d_in[7];
  const float* W3l = (const float*)d_in[8];
  const float* W3r = (const float*)d_in[9];
  const float* b3  = (const float*)d_in[10];
  const float* W4l = (const float*)d_in[11];
  const float* W4r = (const float*)d_in[12];
  const float* b4  = (const float*)d_in[13];

  const int N = in_sizes[0] / 64;   // 100000
  const int E = in_sizes[1] / 2;    // 1600000
  const size_t Ns = (size_t)N;
  const int B = (N + 127) >> 7;     // 782 buckets
  const int NBLK = (E + 8191) / 8192;  // 196

  // ---- workspace layout ----
  u16* ub      = (u16*)d_ws;
  u16* xb      = ub;                 // 64N
  u16* mean0b  = ub + 64 * Ns;       // 64N
  u16* h1b     = ub + 128 * Ns;      // 128N
  u16* mean1b  = ub + 256 * Ns;      // 128N
  u16* wt1     = ub + 384 * Ns;      // 16384
  u16* wt2     = wt1 + 16384;        // 32768
  float* fb    = (float*)(wt2 + 32768);
  float* p     = fb;                 // N
  float* q     = fb + Ns;            // N
  float* h3    = fb + 2 * Ns;        // N
  int* ib      = (int*)(fb + 3 * Ns);
  int* rowptr       = ib;                      // N+1
  int* gcur         = ib + (N + 1);            // 1024
  int* bucket_base  = gcur + 1024;             // 1025
  int* csr          = bucket_base + 1025;      // E
  u32* staging      = (u32*)(csr + E);         // 1024*BCAP = 16.8 MB

  float* out_rock   = (float*)d_out;            // N x 8
  float* out_scalar = (float*)d_out + 8 * Ns;   // N

  const int GG = (N + 127) / 128;
  const int total4 = N * 16;

  // ---- CSR build ----
  hipMemsetAsync(gcur, 0, 1024 * sizeof(int), stream);
  bucketize<<<NBLK, 512, 0, stream>>>(ei, gcur, staging, E, B);
  scan_tiny<<<1, 512, 0, stream>>>(gcur, bucket_base, rowptr, N, E);
  place<<<B, 256, 0, stream>>>(staging, bucket_base, rowptr, csr, N);

  // ---- conversions ----
  cvt_all<<<(total4 + 49152 + 255) / 256, 256, 0, stream>>>(
      x, xb, total4, W1l, W1r, W2l, W2r, wt1, wt2);

  // ---- layer 1 ----
  gather_mean_64b<<<(N + 3) / 4, 256, 0, stream>>>(xb, rowptr, csr, mean0b, N);
  mfma_gemm<128, false><<<GG, 512, 0, stream>>>(
      mean0b, xb, wt1, b1, h1b, nullptr, nullptr, nullptr, nullptr, N);

  // ---- layer 2 (+ fused p,q) ----
  gather_mean_128b<<<(N + 3) / 4, 256, 0, stream>>>(h1b, rowptr, csr, mean1b, N);
  mfma_gemm<256, true><<<GG, 512, 0, stream>>>(
      mean1b, h1b, wt2, b2, nullptr, W3l, W3r, p, q, N);

  // ---- layer 3 (scalar) ----
  gather3_fused<<<(N + 255) / 256, 256, 0, stream>>>(p, rowptr, csr, q, b3, h3, out_scalar, N);

  // ---- layer 4 (scalar in, 8 out) ----
  gather4_fused<<<(N + 255) / 256, 256, 0, stream>>>(h3, rowptr, csr, W4l, W4r, b4, out_rock, N);
}